// Round 1
// baseline (584.281 us; speedup 1.0000x reference)
//
#include <hip/hip_runtime.h>
#include <stdint.h>

// MBSeederSLFCAMS — exact replication of the JAX reference on MI355X.
// Key correctness requirement: bit-exact JAX threefry PRNG + stable-sort /
// stable-top_k tie semantics. PARTITIONABLE=1 assumes jax_threefry_partitionable
// default (JAX >= 0.5). If bench fails with absmax ~255, flip to 0 next round.
#define PARTITIONABLE 1

typedef unsigned int u32;
typedef unsigned long long u64;

static constexpr int BB  = 256;          // batch
static constexpr int HH  = 256;
static constexpr int WW  = 256;
static constexpr int HWN = HH * WW;      // 65536 pixels per image
static constexpr int WPI = HWN / 64;     // 1024 u64 words per image bitmask
static constexpr u32 K_BG = 6553;        // int(0.1*65536)
static constexpr u32 TOPK = 100;

__host__ __device__ inline u32 rotl32(u32 x, int d) { return (x << d) | (x >> (32 - d)); }

#define TF_ROUND(r) do { x0 += x1; x1 = rotl32(x1, r); x1 ^= x0; } while (0)

__host__ __device__ inline void threefry2x32(u32 k0, u32 k1, u32 x0, u32 x1, u32& o0, u32& o1) {
  u32 ks2 = k0 ^ k1 ^ 0x1BD11BDAu;
  x0 += k0; x1 += k1;
  TF_ROUND(13); TF_ROUND(15); TF_ROUND(26); TF_ROUND(6);
  x0 += k1;  x1 += ks2 + 1u;
  TF_ROUND(17); TF_ROUND(29); TF_ROUND(16); TF_ROUND(24);
  x0 += ks2; x1 += k0 + 2u;
  TF_ROUND(13); TF_ROUND(15); TF_ROUND(26); TF_ROUND(6);
  x0 += k0;  x1 += k1 + 3u;
  TF_ROUND(17); TF_ROUND(29); TF_ROUND(16); TF_ROUND(24);
  x0 += k1;  x1 += ks2 + 4u;
  TF_ROUND(13); TF_ROUND(15); TF_ROUND(26); TF_ROUND(6);
  x0 += ks2; x1 += k0 + 5u;
  o0 = x0; o1 = x1;
}

// 32 random bits for flat index i (i < 2^24) under key (k0,k1), matching
// jax.random's threefry_random_bits for shape of size 2^24.
__device__ inline u32 score_bits(u32 k0, u32 k1, u32 i) {
#if PARTITIONABLE
  u32 a, b;
  threefry2x32(k0, k1, 0u, i, a, b);   // 64-bit iota: hi=0, lo=i
  return a ^ b;
#else
  const u32 HALF = 1u << 23;           // n/2 for n = 2^24
  u32 a, b;
  if (i < HALF) { threefry2x32(k0, k1, i, i + HALF, a, b); return a; }
  threefry2x32(k0, k1, i - HALF, i, a, b); return b;
#endif
}

// ---------------------------------------------------------------- hist + otsu
__global__ __launch_bounds__(256) void k_hist_otsu(const float* __restrict__ x,
                                                   float* __restrict__ thOut,
                                                   u32* __restrict__ badOut) {
  int b = blockIdx.x, tid = threadIdx.x;
  __shared__ u32 hist[256];
  __shared__ float w1s[256], s1s[256];
  hist[tid] = 0;
  __syncthreads();
  const float* img = x + (size_t)b * HWN;
  for (int i = tid; i < HWN; i += 256) {
    float c = floorf(img[i] * 255.0f);
    c = fminf(fmaxf(c, 0.0f), 255.0f);
    atomicAdd(&hist[(int)c], 1u);
  }
  __syncthreads();
  if (tid == 0) {
    // Exact fp32 cumsums: every partial is an integer < 2^24 -> exact,
    // independent of XLA's scan association.
    float w = 0.f, s = 0.f;
    int nz = 0;
    for (int t = 0; t < 256; t++) {
      float h = (float)hist[t];
      if (hist[t]) nz++;
      w += h; w1s[t] = w;
      s += h * (float)t; s1s[t] = s;
    }
    float total = w1s[255], stot = s1s[255];
    float best = -1.0f; int bi = 0;
    for (int t = 0; t < 255; t++) {
      float h1 = (float)hist[t + 1];
      float w1 = w1s[t];
      float w2 = total - w1s[t + 1] + h1;          // w2[t+1]
      float s1 = s1s[t];
      float s2 = stot - s1s[t + 1] + h1 * (float)(t + 1);
      float m1 = s1 / fmaxf(w1, 1.0f);
      float m2 = s2 / fmaxf(w2, 1.0f);
      float d = m1 - m2;
      float v = (w1 * w2) * (d * d);               // mirrors (w1*w2)*(d**2)
      if (v > best) { best = v; bi = t; }          // first max == jnp.argmax
    }
    float th = (float)bi;
    th = (th <= 0.0f) ? 1.0f : ((th >= 255.0f) ? 254.0f : th);
    thOut[b] = th;
    badOut[b] = (nz <= 1) ? 1u : 0u;               // max(ci)==min(ci)
  }
}

// ---------------------------------------------------------------- roi erosion
__global__ __launch_bounds__(256) void k_roi(const float* __restrict__ x,
                                             const float* __restrict__ th,
                                             u64* __restrict__ roiBits,
                                             u32* __restrict__ roiCnt) {
  int b = blockIdx.x, r = threadIdx.x;   // thread = image row
  float t = th[b];
  const float* row = x + (size_t)b * HWN + (size_t)r * WW;
  u64 w[4] = {0, 0, 0, 0};
  for (int c = 0; c < WW; c++)
    if (floorf(row[c] * 255.0f) > t) w[c >> 6] |= (1ull << (c & 63));
  // horizontal 11-erosion; out-of-range = 1 (min-pool init = +inf)
  u64 h0[4] = {w[0], w[1], w[2], w[3]};
  for (int s = 1; s <= 5; s++) {
    for (int j = 0; j < 4; j++) {
      u64 hi = (j < 3) ? w[j + 1] : ~0ull;
      u64 lo = (j > 0) ? w[j - 1] : ~0ull;
      u64 A  = (w[j] >> s) | (hi << (64 - s));   // bit c <- bit c+s
      u64 Bv = (w[j] << s) | (lo >> (64 - s));   // bit c <- bit c-s
      h0[j] &= A & Bv;
    }
  }
  __shared__ u64 hb[256][4];
  for (int j = 0; j < 4; j++) hb[r][j] = h0[j];
  __syncthreads();
  u64 res[4] = {hb[r][0], hb[r][1], hb[r][2], hb[r][3]};
  for (int dr = -5; dr <= 5; dr++) {
    if (dr == 0) continue;
    int rr = r + dr;
    if (rr < 0 || rr >= HH) continue;            // OOB rows = 1 (skip)
    for (int j = 0; j < 4; j++) res[j] &= hb[rr][j];
  }
  u32 p = 0;
  for (int j = 0; j < 4; j++) { roiBits[(size_t)b * WPI + r * 4 + j] = res[j]; p += __popcll(res[j]); }
  __shared__ u32 tot;
  if (r == 0) tot = 0;
  __syncthreads();
  atomicAdd(&tot, p);
  __syncthreads();
  if (r == 0) roiCnt[b] = tot;
}

// ------------------------------------------- rank-6553 select on cam float bits
// cam >= 0, so raw IEEE bits are order-isomorphic to value; radix 11+11+10.
__global__ __launch_bounds__(256) void k_cam_select(const float* __restrict__ x,
                                                    u32* __restrict__ camT,
                                                    u32* __restrict__ camTie) {
  int b = blockIdx.x, tid = threadIdx.x;
  const float* img = x + (size_t)b * HWN;
  __shared__ u32 hist[2048];
  __shared__ u32 psum[256];
  __shared__ u32 s_bin, s_base;
  const u32 K = K_BG;

  // stage 1: bits [31:21]
  for (int t = tid; t < 2048; t += 256) hist[t] = 0;
  __syncthreads();
  for (int i = tid; i < HWN; i += 256) {
    u32 k = __float_as_uint(img[i]);
    atomicAdd(&hist[k >> 21], 1u);
  }
  __syncthreads();
  { u32 l = 0; for (int j = 0; j < 8; j++) l += hist[tid * 8 + j]; psum[tid] = l; }
  __syncthreads();
  if (tid == 0) {
    u32 cum = 0; int seg = 0;
    for (int t = 0; t < 256; t++) { if (cum + psum[t] >= K) { seg = t; break; } cum += psum[t]; }
    u32 bin = 0;
    for (int j = 0; j < 8; j++) { u32 h = hist[seg * 8 + j]; if (cum + h >= K) { bin = seg * 8 + j; break; } cum += h; }
    s_bin = bin; s_base = cum;   // count strictly below bin
  }
  __syncthreads();
  u32 b1 = s_bin; u32 K2 = K - s_base;
  __syncthreads();

  // stage 2: bits [20:10] where top bits == b1
  for (int t = tid; t < 2048; t += 256) hist[t] = 0;
  __syncthreads();
  for (int i = tid; i < HWN; i += 256) {
    u32 k = __float_as_uint(img[i]);
    if ((k >> 21) == b1) atomicAdd(&hist[(k >> 10) & 0x7FFu], 1u);
  }
  __syncthreads();
  { u32 l = 0; for (int j = 0; j < 8; j++) l += hist[tid * 8 + j]; psum[tid] = l; }
  __syncthreads();
  if (tid == 0) {
    u32 cum = 0; int seg = 0;
    for (int t = 0; t < 256; t++) { if (cum + psum[t] >= K2) { seg = t; break; } cum += psum[t]; }
    u32 bin = 0;
    for (int j = 0; j < 8; j++) { u32 h = hist[seg * 8 + j]; if (cum + h >= K2) { bin = seg * 8 + j; break; } cum += h; }
    s_bin = bin; s_base = cum;
  }
  __syncthreads();
  u32 b2 = s_bin; u32 K3 = K2 - s_base;
  __syncthreads();

  // stage 3: bits [9:0] where top 22 bits == (b1,b2)
  for (int t = tid; t < 1024; t += 256) hist[t] = 0;
  __syncthreads();
  u32 hi22 = (b1 << 11) | b2;
  for (int i = tid; i < HWN; i += 256) {
    u32 k = __float_as_uint(img[i]);
    if ((k >> 10) == hi22) atomicAdd(&hist[k & 0x3FFu], 1u);
  }
  __syncthreads();
  { u32 l = 0; for (int j = 0; j < 4; j++) l += hist[tid * 4 + j]; psum[tid] = l; }
  __syncthreads();
  if (tid == 0) {
    u32 cum = 0; int seg = 0;
    for (int t = 0; t < 256; t++) { if (cum + psum[t] >= K3) { seg = t; break; } cum += psum[t]; }
    u32 bin = 0;
    for (int j = 0; j < 4; j++) { u32 h = hist[seg * 4 + j]; if (cum + h >= K3) { bin = seg * 4 + j; break; } cum += h; }
    camT[b]  = (b1 << 21) | (b2 << 10) | bin;  // value of 6553rd smallest
    camTie[b] = K3 - cum;                       // #ties at T to take (lowest idx)
  }
}

// ------------------------------- mark bg candidate bitmask (stable argsort sem.)
__global__ __launch_bounds__(256) void k_mark_cand(const float* __restrict__ x,
                                                   const u32* __restrict__ camT,
                                                   const u32* __restrict__ camTie,
                                                   u64* __restrict__ cand) {
  int b = blockIdx.x, tid = threadIdx.x;
  u32 T = camT[b], ties = camTie[b];
  const float* img = x + (size_t)b * HWN + (size_t)tid * WW;  // chunk = image row tid
  u32 cntEq = 0;
  for (int c = 0; c < WW; c++) cntEq += (__float_as_uint(img[c]) == T);
  __shared__ u32 pc[256]; __shared__ u32 ps[256];
  pc[tid] = cntEq;
  __syncthreads();
  if (tid == 0) { u32 a = 0; for (int t = 0; t < 256; t++) { ps[t] = a; a += pc[t]; } }
  __syncthreads();
  u32 rank = ps[tid];
  u64 w[4] = {0, 0, 0, 0};
  for (int c = 0; c < WW; c++) {
    u32 k = __float_as_uint(img[c]);
    bool sel;
    if (k < T) sel = true;
    else if (k == T) { sel = (rank < ties); rank++; }
    else sel = false;
    if (sel) w[c >> 6] |= (1ull << (c & 63));
  }
  u64* crow = cand + (size_t)b * WPI + (size_t)tid * 4;
  for (int j = 0; j < 4; j++) crow[j] = w[j];
}

// ---------------- top-k (descending) select over masked positions' score bits
__global__ __launch_bounds__(256) void k_score_select(const u64* __restrict__ mask,
                                                      const u32* __restrict__ cntPtr,
                                                      u32 key0, u32 key1,
                                                      u32* __restrict__ Sout,
                                                      u32* __restrict__ tiesOut) {
  int b = blockIdx.x, tid = threadIdx.x;
  u32 cnt = cntPtr ? cntPtr[b] : K_BG;
  u32 keff = cnt < TOPK ? cnt : TOPK;
  if (keff == 0) { if (tid == 0) { Sout[b] = 0xFFFFFFFFu; tiesOut[b] = 0u; } return; }
  __shared__ u32 hist[4096];
  __shared__ u32 psum[256];
  __shared__ u32 s_bin, s_base;
  const u64* mrow = mask + (size_t)b * WPI;

  // stage 1: hi 11 bits of 23-bit score m, descending
  for (int t = tid; t < 2048; t += 256) hist[t] = 0;
  __syncthreads();
  for (int wi = tid; wi < WPI; wi += 256) {
    u64 w = mrow[wi];
    while (w) {
      int bit = __builtin_ctzll(w); w &= w - 1;
      u32 i = ((u32)b << 16) | (u32)(wi * 64 + bit);
      u32 m = score_bits(key0, key1, i) >> 9;
      atomicAdd(&hist[m >> 12], 1u);
    }
  }
  __syncthreads();
  { u32 l = 0; for (int j = 0; j < 8; j++) l += hist[tid * 8 + j]; psum[tid] = l; }
  __syncthreads();
  if (tid == 0) {
    u32 cum = 0; int seg = 0;
    for (int t = 255; t >= 0; t--) { if (cum + psum[t] >= keff) { seg = t; break; } cum += psum[t]; }
    u32 bin = 0;
    for (int j = 7; j >= 0; j--) { u32 h = hist[seg * 8 + j]; if (cum + h >= keff) { bin = seg * 8 + j; break; } cum += h; }
    s_bin = bin; s_base = cum;   // count strictly above bin
  }
  __syncthreads();
  u32 b1 = s_bin; u32 k2 = keff - s_base;
  __syncthreads();

  // stage 2: lo 12 bits among m>>12 == b1, descending
  for (int t = tid; t < 4096; t += 256) hist[t] = 0;
  __syncthreads();
  for (int wi = tid; wi < WPI; wi += 256) {
    u64 w = mrow[wi];
    while (w) {
      int bit = __builtin_ctzll(w); w &= w - 1;
      u32 i = ((u32)b << 16) | (u32)(wi * 64 + bit);
      u32 m = score_bits(key0, key1, i) >> 9;
      if ((m >> 12) == b1) atomicAdd(&hist[m & 0xFFFu], 1u);
    }
  }
  __syncthreads();
  { u32 l = 0; for (int j = 0; j < 16; j++) l += hist[tid * 16 + j]; psum[tid] = l; }
  __syncthreads();
  if (tid == 0) {
    u32 cum = 0; int seg = 0;
    for (int t = 255; t >= 0; t--) { if (cum + psum[t] >= k2) { seg = t; break; } cum += psum[t]; }
    u32 bin = 0;
    for (int j = 15; j >= 0; j--) { u32 h = hist[seg * 16 + j]; if (cum + h >= k2) { bin = seg * 16 + j; break; } cum += h; }
    Sout[b]   = (b1 << 12) | bin;   // score of k-th largest
    tiesOut[b] = k2 - cum;          // #ties at S to take (lowest idx)
  }
}

// ---------------------- mark seed bitmask: m > S, or m == S with rank < ties
__global__ __launch_bounds__(256) void k_mark_topk(const u64* __restrict__ mask,
                                                   u32 key0, u32 key1,
                                                   const u32* __restrict__ Sarr,
                                                   const u32* __restrict__ tiesArr,
                                                   const u32* __restrict__ bad,
                                                   u64* __restrict__ seed) {
  int b = blockIdx.x, tid = threadIdx.x;
  u32 S = Sarr[b], ties = tiesArr[b];
  bool dead = (bad[b] != 0u);
  const u64* mrow = mask + (size_t)b * WPI;
  u64* srow = seed + (size_t)b * WPI;
  u64 mw[4];
  u32 cntEq = 0;
  for (int j = 0; j < 4; j++) {
    mw[j] = mrow[tid * 4 + j];
    u64 w = mw[j];
    while (w) {
      int bit = __builtin_ctzll(w); w &= w - 1;
      u32 i = ((u32)b << 16) | (u32)((tid * 4 + j) * 64 + bit);
      u32 m = score_bits(key0, key1, i) >> 9;
      cntEq += (m == S);
    }
  }
  __shared__ u32 pc[256]; __shared__ u32 ps[256];
  pc[tid] = cntEq;
  __syncthreads();
  if (tid == 0) { u32 a = 0; for (int t = 0; t < 256; t++) { ps[t] = a; a += pc[t]; } }
  __syncthreads();
  u32 rank = ps[tid];
  for (int j = 0; j < 4; j++) {
    u64 w = mw[j]; u64 ow = 0;
    while (w) {
      int bit = __builtin_ctzll(w); w &= w - 1;
      u32 i = ((u32)b << 16) | (u32)((tid * 4 + j) * 64 + bit);
      u32 m = score_bits(key0, key1, i) >> 9;
      bool sel;
      if (m > S) sel = true;
      else if (m == S) { sel = (rank < ties); rank++; }
      else sel = false;
      if (sel && !dead) ow |= (1ull << bit);
    }
    srow[tid * 4 + j] = ow;
  }
}

// ------------------------------ dilate 3x3 (OOB=0), conflict-resolve, emit int32
__global__ __launch_bounds__(256) void k_out(const u64* __restrict__ fgSeed,
                                             const u64* __restrict__ bgSeed,
                                             int* __restrict__ out) {
  int blk = blockIdx.x;
  int b = blk >> 8, r = blk & 255, c = threadIdx.x;
  __shared__ u64 fv[4], bv[4], fh[4], bh[4];
  if (c < 4) {
    u64 vf = 0, vb = 0;
    for (int dr = -1; dr <= 1; dr++) {
      int rr = r + dr;
      if (rr < 0 || rr >= HH) continue;
      vf |= fgSeed[(size_t)b * WPI + rr * 4 + c];
      vb |= bgSeed[(size_t)b * WPI + rr * 4 + c];
    }
    fv[c] = vf; bv[c] = vb;
  }
  __syncthreads();
  if (c < 4) {
    u64 v = fv[c], L = (c > 0) ? fv[c - 1] : 0ull, R = (c < 3) ? fv[c + 1] : 0ull;
    fh[c] = v | (v << 1) | (L >> 63) | (v >> 1) | (R << 63);
    v = bv[c]; L = (c > 0) ? bv[c - 1] : 0ull; R = (c < 3) ? bv[c + 1] : 0ull;
    bh[c] = v | (v << 1) | (L >> 63) | (v >> 1) | (R << 63);
  }
  __syncthreads();
  int wi = c >> 6, bi = c & 63;
  bool fgd = (fh[wi] >> bi) & 1ull;
  bool bgd = (bh[wi] >> bi) & 1ull;
  int o = (fgd && bgd) ? -255 : (bgd ? 0 : (fgd ? 1 : -255));
  out[(size_t)blk * WW + c] = o;
}

extern "C" void kernel_launch(void* const* d_in, const int* in_sizes, int n_in,
                              void* d_out, int out_size, void* d_ws, size_t ws_size,
                              hipStream_t stream) {
  const float* x = (const float*)d_in[0];
  int* out = (int*)d_out;
  char* ws = (char*)d_ws;

  // workspace layout (~8.4 MB total)
  float* th     = (float*)(ws + 0);
  u32*   bad    = (u32*)(ws + 1024);
  u32*   roiCnt = (u32*)(ws + 2048);
  u32*   camT   = (u32*)(ws + 3072);
  u32*   camTie = (u32*)(ws + 4096);
  u32*   fgS    = (u32*)(ws + 5120);
  u32*   fgTie  = (u32*)(ws + 6144);
  u32*   bgS    = (u32*)(ws + 7168);
  u32*   bgTie  = (u32*)(ws + 8192);
  u64* roiBits  = (u64*)(ws + 16384);
  u64* candBits = (u64*)(ws + 16384 + 1 * 2097152);
  u64* fgSeed   = (u64*)(ws + 16384 + 2 * 2097152);
  u64* bgSeed   = (u64*)(ws + 16384 + 3 * 2097152);

  // Derive kf/kb from jax.random.split(jax.random.key(42)) on host (pure int math).
  u32 kf0, kf1, kb0, kb1;
#if PARTITIONABLE
  threefry2x32(0u, 42u, 0u, 0u, kf0, kf1);
  threefry2x32(0u, 42u, 0u, 1u, kb0, kb1);
#else
  u32 a0, a1, c0, c1;
  threefry2x32(0u, 42u, 0u, 2u, a0, a1);
  threefry2x32(0u, 42u, 1u, 3u, c0, c1);
  kf0 = a0; kf1 = c0; kb0 = a1; kb1 = c1;
#endif

  k_hist_otsu<<<BB, 256, 0, stream>>>(x, th, bad);
  k_roi<<<BB, 256, 0, stream>>>(x, th, roiBits, roiCnt);
  k_cam_select<<<BB, 256, 0, stream>>>(x, camT, camTie);
  k_mark_cand<<<BB, 256, 0, stream>>>(x, camT, camTie, candBits);
  // fg: top-100 kf-scores over (almost surely empty) eroded ROI
  k_score_select<<<BB, 256, 0, stream>>>(roiBits, roiCnt, kf0, kf1, fgS, fgTie);
  k_mark_topk<<<BB, 256, 0, stream>>>(roiBits, kf0, kf1, fgS, fgTie, bad, fgSeed);
  // bg: top-100 kb-scores over the 6553 lowest-cam candidates
  k_score_select<<<BB, 256, 0, stream>>>(candBits, (const u32*)nullptr, kb0, kb1, bgS, bgTie);
  k_mark_topk<<<BB, 256, 0, stream>>>(candBits, kb0, kb1, bgS, bgTie, bad, bgSeed);
  k_out<<<BB * HH, 256, 0, stream>>>(fgSeed, bgSeed, out);
}

// Round 2
// 223.878 us; speedup vs baseline: 2.6098x; 2.6098x over previous
//
#include <hip/hip_runtime.h>
#include <stdint.h>

// MBSeederSLFCAMS — exact JAX replication, restructured for occupancy/coalescing.
#define PARTITIONABLE 1

typedef unsigned int u32;
typedef unsigned long long u64;

static constexpr int BB  = 256;
static constexpr int HH  = 256;
static constexpr int WW  = 256;
static constexpr int HWN = HH * WW;     // 65536
static constexpr int WPI = HWN / 64;    // 1024 u64 words per image
static constexpr u32 K_BG = 6553;       // int(0.1*65536)
static constexpr u32 TOPK = 100;

__host__ __device__ inline u32 rotl32(u32 x, int d) { return (x << d) | (x >> (32 - d)); }

#define TF_ROUND(r) do { x0 += x1; x1 = rotl32(x1, r); x1 ^= x0; } while (0)

__host__ __device__ inline void threefry2x32(u32 k0, u32 k1, u32 x0, u32 x1, u32& o0, u32& o1) {
  u32 ks2 = k0 ^ k1 ^ 0x1BD11BDAu;
  x0 += k0; x1 += k1;
  TF_ROUND(13); TF_ROUND(15); TF_ROUND(26); TF_ROUND(6);
  x0 += k1;  x1 += ks2 + 1u;
  TF_ROUND(17); TF_ROUND(29); TF_ROUND(16); TF_ROUND(24);
  x0 += ks2; x1 += k0 + 2u;
  TF_ROUND(13); TF_ROUND(15); TF_ROUND(26); TF_ROUND(6);
  x0 += k0;  x1 += k1 + 3u;
  TF_ROUND(17); TF_ROUND(29); TF_ROUND(16); TF_ROUND(24);
  x0 += k1;  x1 += ks2 + 4u;
  TF_ROUND(13); TF_ROUND(15); TF_ROUND(26); TF_ROUND(6);
  x0 += ks2; x1 += k0 + 5u;
  o0 = x0; o1 = x1;
}

__device__ inline u32 score_bits(u32 k0, u32 k1, u32 i) {
#if PARTITIONABLE
  u32 a, b;
  threefry2x32(k0, k1, 0u, i, a, b);
  return a ^ b;
#else
  const u32 HALF = 1u << 23;
  u32 a, b;
  if (i < HALF) { threefry2x32(k0, k1, i, i + HALF, a, b); return a; }
  threefry2x32(k0, k1, i - HALF, i, a, b); return b;
#endif
}

// ---------------- K1: fused otsu-hist + cam-bits-hist partials, 2 blocks/image
__global__ __launch_bounds__(1024) void k1_hist(const float* __restrict__ x,
                                                u32* __restrict__ gPart) {
  int bid = blockIdx.x, b = bid >> 1, s = bid & 1, tid = threadIdx.x;
  __shared__ u32 hO[256];
  __shared__ u32 hC[2048];
  if (tid < 256) hO[tid] = 0;
  hC[tid] = 0; hC[tid + 1024] = 0;
  __syncthreads();
  const float4* img4 = (const float4*)(x + (size_t)b * HWN) + s * 8192;
  for (int it = 0; it < 8; ++it) {
    float4 v = img4[it * 1024 + tid];
    float a[4] = {v.x, v.y, v.z, v.w};
#pragma unroll
    for (int c = 0; c < 4; c++) {
      u32 kb = __float_as_uint(a[c]);
      atomicAdd(&hC[kb >> 21], 1u);
      float f = floorf(a[c] * 255.0f);
      f = fminf(fmaxf(f, 0.0f), 255.0f);
      atomicAdd(&hO[(int)f], 1u);
    }
  }
  __syncthreads();
  u32* dst = gPart + (size_t)bid * 2304;
  for (int j = tid; j < 2304; j += 1024) dst[j] = (j < 256) ? hO[j] : hC[j - 256];
}

// ---------------- K2: reduce partials; otsu scan; cam radix stage 1
__global__ __launch_bounds__(256) void k2_select1(const u32* __restrict__ gPart,
                                                  float* __restrict__ thArr,
                                                  u32* __restrict__ badArr,
                                                  u32* __restrict__ b1Arr,
                                                  u32* __restrict__ K2Arr) {
  int b = blockIdx.x, tid = threadIdx.x;
  __shared__ u32 hO[256];
  __shared__ u32 hC[2048];
  __shared__ u32 psum[256];
  __shared__ float w1s[256], s1s[256];
  const u32* p0 = gPart + (size_t)(2 * b) * 2304;
  const u32* p1 = p0 + 2304;
  for (int j = tid; j < 2304; j += 256) {
    u32 v = p0[j] + p1[j];
    if (j < 256) hO[j] = v; else hC[j - 256] = v;
  }
  __syncthreads();
  { u32 l = 0; for (int j = 0; j < 8; j++) l += hC[tid * 8 + j]; psum[tid] = l; }
  __syncthreads();
  if (tid == 0) {
    // Otsu (exact fp32: all partials are ints < 2^24)
    float w = 0.f, sv = 0.f; int nz = 0;
    for (int t = 0; t < 256; t++) {
      float h = (float)hO[t];
      if (hO[t]) nz++;
      w += h; w1s[t] = w;
      sv += h * (float)t; s1s[t] = sv;
    }
    float total = w1s[255], stot = s1s[255];
    float best = -1.0f; int bi = 0;
    for (int t = 0; t < 255; t++) {
      float h1 = (float)hO[t + 1];
      float w1 = w1s[t];
      float w2 = total - w1s[t + 1] + h1;
      float s1 = s1s[t];
      float s2 = stot - s1s[t + 1] + h1 * (float)(t + 1);
      float m1 = s1 / fmaxf(w1, 1.0f);
      float m2 = s2 / fmaxf(w2, 1.0f);
      float d = m1 - m2;
      float v = (w1 * w2) * (d * d);
      if (v > best) { best = v; bi = t; }
    }
    float th = (float)bi;
    th = (th <= 0.0f) ? 1.0f : ((th >= 255.0f) ? 254.0f : th);
    thArr[b] = th;
    badArr[b] = (nz <= 1) ? 1u : 0u;
    // cam radix stage 1 over top-11 float bits
    u32 cum = 0; int seg = 0;
    for (int t = 0; t < 256; t++) { if (cum + psum[t] >= K_BG) { seg = t; break; } cum += psum[t]; }
    u32 bin = 0;
    for (int j = 0; j < 8; j++) { u32 h = hC[seg * 8 + j]; if (cum + h >= K_BG) { bin = seg * 8 + j; break; } cum += h; }
    b1Arr[b] = bin;
    K2Arr[b] = K_BG - cum;
  }
}

// ---------------- K3: collect bin-b1 elements; in-LDS select of low 21 bits; tie idx
__global__ __launch_bounds__(1024) void k3_select2(const float* __restrict__ x,
                                                   const u32* __restrict__ b1Arr,
                                                   const u32* __restrict__ K2Arr,
                                                   u32* __restrict__ camT,
                                                   int* __restrict__ tieMaxArr) {
  int b = blockIdx.x, tid = threadIdx.x;
  u32 b1 = b1Arr[b], K2v = K2Arr[b];
  __shared__ u64 list[8192];
  __shared__ u32 hist[2048];
  __shared__ u32 psum[256];
  __shared__ u32 eq[256];
  __shared__ u32 cnt, eqc, sh_a, sh_b;
  if (tid == 0) { cnt = 0; eqc = 0; }
  __syncthreads();
  const float4* img4 = (const float4*)(x + (size_t)b * HWN);
  for (int f = tid; f < 16384; f += 1024) {
    float4 v = img4[f];
    float a[4] = {v.x, v.y, v.z, v.w};
#pragma unroll
    for (int c = 0; c < 4; c++) {
      u32 kb = __float_as_uint(a[c]);
      if ((kb >> 21) == b1) {
        u32 pos = atomicAdd(&cnt, 1u);
        if (pos < 8192) list[pos] = ((u64)(kb & 0x1FFFFFu) << 16) | (u32)(f * 4 + c);
      }
    }
  }
  __syncthreads();
  u32 cntC = cnt < 8192u ? cnt : 8192u;
  // stage A: bits [20:10]
  for (int j = tid; j < 2048; j += 1024) hist[j] = 0;
  __syncthreads();
  for (u32 e = tid; e < cntC; e += 1024) { u32 rem = (u32)(list[e] >> 16); atomicAdd(&hist[rem >> 10], 1u); }
  __syncthreads();
  if (tid < 256) { u32 l = 0; for (int j = 0; j < 8; j++) l += hist[tid * 8 + j]; psum[tid] = l; }
  __syncthreads();
  if (tid == 0) {
    u32 cum = 0; int seg = 0;
    for (int t = 0; t < 256; t++) { if (cum + psum[t] >= K2v) { seg = t; break; } cum += psum[t]; }
    u32 bin = 0;
    for (int j = 0; j < 8; j++) { u32 h = hist[seg * 8 + j]; if (cum + h >= K2v) { bin = seg * 8 + j; break; } cum += h; }
    sh_a = bin; sh_b = K2v - cum;
  }
  __syncthreads();
  u32 bA = sh_a, K3v = sh_b;
  __syncthreads();
  // stage B: bits [9:0] among rem>>10 == bA
  for (int j = tid; j < 1024; j += 1024) hist[j] = 0;
  __syncthreads();
  for (u32 e = tid; e < cntC; e += 1024) { u32 rem = (u32)(list[e] >> 16); if ((rem >> 10) == bA) atomicAdd(&hist[rem & 0x3FFu], 1u); }
  __syncthreads();
  if (tid < 256) { u32 l = 0; for (int j = 0; j < 4; j++) l += hist[tid * 4 + j]; psum[tid] = l; }
  __syncthreads();
  if (tid == 0) {
    u32 cum = 0; int seg = 0;
    for (int t = 0; t < 256; t++) { if (cum + psum[t] >= K3v) { seg = t; break; } cum += psum[t]; }
    u32 bin = 0;
    for (int j = 0; j < 4; j++) { u32 h = hist[seg * 4 + j]; if (cum + h >= K3v) { bin = seg * 4 + j; break; } cum += h; }
    sh_a = (bA << 10) | bin;   // low 21 bits of threshold
    sh_b = K3v - cum;          // ties to take (lowest index first)
  }
  __syncthreads();
  u32 low21 = sh_a, ties = sh_b;
  for (u32 e = tid; e < cntC; e += 1024) {
    u64 le = list[e];
    if ((u32)(le >> 16) == low21) { u32 p = atomicAdd(&eqc, 1u); if (p < 256) eq[p] = (u32)(le & 0xFFFFu); }
  }
  __syncthreads();
  if (tid == 0) {
    u32 n = eqc < 256u ? eqc : 256u;
    for (u32 i2 = 1; i2 < n; i2++) { u32 v = eq[i2]; int j = (int)i2 - 1; while (j >= 0 && eq[j] > v) { eq[j + 1] = eq[j]; j--; } eq[j + 1] = v; }
    camT[b] = (b1 << 21) | low21;
    tieMaxArr[b] = (ties > 0) ? (int)eq[ties - 1] : -1;
  }
}

// ---------------- K4: fused ROI (threshold+11x11 erosion) + bg-candidate bitmask
__global__ __launch_bounds__(1024) void k4_mark(const float* __restrict__ x,
                                                const float* __restrict__ thArr,
                                                const u32* __restrict__ camT,
                                                const int* __restrict__ tieMaxArr,
                                                u64* __restrict__ roiBits,
                                                u64* __restrict__ candBits) {
  int b = blockIdx.x, tid = threadIdx.x;
  float th = thArr[b];
  u32 T = camT[b];
  int tmax = tieMaxArr[b];
  __shared__ u64 rows[1024];
  __shared__ u64 hrows[1024];
  const float* img = x + (size_t)b * HWN;
  u64* crow = candBits + (size_t)b * WPI;
  int lane = tid & 63, w = tid >> 6;
  for (int c = 0; c < 64; c++) {
    int i = c * 1024 + tid;
    float v = img[i];
    u32 kb = __float_as_uint(v);
    bool roip = floorf(v * 255.0f) > th;
    bool candp = (kb < T) || (kb == T && i <= tmax);
    u64 br = __ballot(roip);
    u64 bc = __ballot(candp);
    if (lane == 0) { int wid = c * 16 + w; rows[wid] = br; crow[wid] = bc; }
  }
  __syncthreads();
  if (tid < 256) {
    int r = tid;
    u64 wv[4], h0[4];
    for (int j = 0; j < 4; j++) { wv[j] = rows[r * 4 + j]; h0[j] = wv[j]; }
    for (int s = 1; s <= 5; s++) {
      for (int j = 0; j < 4; j++) {
        u64 hi = (j < 3) ? wv[j + 1] : ~0ull;
        u64 lo = (j > 0) ? wv[j - 1] : ~0ull;
        u64 A  = (wv[j] >> s) | (hi << (64 - s));
        u64 Bv = (wv[j] << s) | (lo >> (64 - s));
        h0[j] &= A & Bv;
      }
    }
    for (int j = 0; j < 4; j++) hrows[r * 4 + j] = h0[j];
  }
  __syncthreads();
  if (tid < 256) {
    int r = tid;
    u64 res[4] = {hrows[r * 4], hrows[r * 4 + 1], hrows[r * 4 + 2], hrows[r * 4 + 3]};
    for (int dr = -5; dr <= 5; dr++) {
      if (dr == 0) continue;
      int rr = r + dr;
      if (rr < 0 || rr >= HH) continue;
      for (int j = 0; j < 4; j++) res[j] &= hrows[rr * 4 + j];
    }
    u64* orow = roiBits + (size_t)b * WPI + r * 4;
    for (int j = 0; j < 4; j++) orow[j] = res[j];
  }
}

// ---------------- K5: threefry per set bit -> LDS list; top-100 select; write seed bitmask
__global__ __launch_bounds__(512) void k5_seed(const u64* __restrict__ mask,
                                               u32 key0, u32 key1,
                                               const u32* __restrict__ badArr,
                                               u64* __restrict__ seedOut) {
  int b = blockIdx.x, tid = threadIdx.x;
  __shared__ u64 list[8192];
  __shared__ u64 seedRows[1024];
  __shared__ u32 hist[4096];
  __shared__ u32 psum[256];
  __shared__ u32 eq[256];
  __shared__ u32 cnt, eqc, sh_a, sh_b;
  if (tid == 0) { cnt = 0; eqc = 0; }
  for (int j = tid; j < 1024; j += 512) seedRows[j] = 0;
  __syncthreads();
  const u64* mrow = mask + (size_t)b * WPI;
  for (int wi = tid; wi < 1024; wi += 512) {
    u64 wv = mrow[wi];
    while (wv) {
      int bit = __ffsll((long long)wv) - 1; wv &= wv - 1;
      u32 idx = (u32)(wi * 64 + bit);
      u32 m = score_bits(key0, key1, ((u32)b << 16) | idx) >> 9;
      u32 pos = atomicAdd(&cnt, 1u);
      if (pos < 8192) list[pos] = ((u64)m << 16) | idx;
    }
  }
  __syncthreads();
  u32 cntC = cnt < 8192u ? cnt : 8192u;
  u32 keff = cntC < TOPK ? cntC : TOPK;
  if (keff > 0) {
    // stage 1: descending over m>>12 (11 bits)
    for (int j = tid; j < 2048; j += 512) hist[j] = 0;
    __syncthreads();
    for (u32 e = tid; e < cntC; e += 512) { u32 m = (u32)(list[e] >> 16); atomicAdd(&hist[m >> 12], 1u); }
    __syncthreads();
    if (tid < 256) { u32 l = 0; for (int j = 0; j < 8; j++) l += hist[tid * 8 + j]; psum[tid] = l; }
    __syncthreads();
    if (tid == 0) {
      u32 cum = 0; int seg = 0;
      for (int t = 255; t >= 0; t--) { if (cum + psum[t] >= keff) { seg = t; break; } cum += psum[t]; }
      u32 bin = 0;
      for (int j = 7; j >= 0; j--) { u32 h = hist[seg * 8 + j]; if (cum + h >= keff) { bin = seg * 8 + j; break; } cum += h; }
      sh_a = bin; sh_b = keff - cum;
    }
    __syncthreads();
    u32 b1s = sh_a, k2 = sh_b;
    __syncthreads();
    // stage 2: descending over m&0xFFF (12 bits) among m>>12==b1s
    for (int j = tid; j < 4096; j += 512) hist[j] = 0;
    __syncthreads();
    for (u32 e = tid; e < cntC; e += 512) { u32 m = (u32)(list[e] >> 16); if ((m >> 12) == b1s) atomicAdd(&hist[m & 0xFFFu], 1u); }
    __syncthreads();
    if (tid < 256) { u32 l = 0; for (int j = 0; j < 16; j++) l += hist[tid * 16 + j]; psum[tid] = l; }
    __syncthreads();
    if (tid == 0) {
      u32 cum = 0; int seg = 0;
      for (int t = 255; t >= 0; t--) { if (cum + psum[t] >= k2) { seg = t; break; } cum += psum[t]; }
      u32 bin = 0;
      for (int j = 15; j >= 0; j--) { u32 h = hist[seg * 16 + j]; if (cum + h >= k2) { bin = seg * 16 + j; break; } cum += h; }
      sh_a = (b1s << 12) | bin;  // S: score of keff-th largest
      sh_b = k2 - cum;           // ties at S to take (lowest index first)
    }
    __syncthreads();
    u32 S = sh_a, ties = sh_b;
    for (u32 e = tid; e < cntC; e += 512) {
      u64 le = list[e];
      if ((u32)(le >> 16) == S) { u32 p = atomicAdd(&eqc, 1u); if (p < 256) eq[p] = (u32)(le & 0xFFFFu); }
    }
    __syncthreads();
    if (tid == 0) {
      u32 n = eqc < 256u ? eqc : 256u;
      for (u32 i2 = 1; i2 < n; i2++) { u32 v = eq[i2]; int j = (int)i2 - 1; while (j >= 0 && eq[j] > v) { eq[j + 1] = eq[j]; j--; } eq[j + 1] = v; }
      sh_a = (ties > 0) ? eq[ties - 1] : 0xFFFFFFFFu;
    }
    __syncthreads();
    u32 tmaxU = sh_a;
    bool dead = badArr[b] != 0u;
    if (!dead) {
      for (u32 e = tid; e < cntC; e += 512) {
        u64 le = list[e];
        u32 m = (u32)(le >> 16);
        u32 idx = (u32)(le & 0xFFFFu);
        bool sel = (m > S) || (m == S && tmaxU != 0xFFFFFFFFu && idx <= tmaxU);
        if (sel) atomicOr(&seedRows[idx >> 6], 1ull << (idx & 63));
      }
    }
  }
  __syncthreads();
  u64* srow = seedOut + (size_t)b * WPI;
  for (int j = tid; j < 1024; j += 512) srow[j] = seedRows[j];
}

// ---------------- K6: dilate 3x3, conflict-resolve, emit int32
__global__ __launch_bounds__(256) void k_out(const u64* __restrict__ fgSeed,
                                             const u64* __restrict__ bgSeed,
                                             int* __restrict__ out) {
  int blk = blockIdx.x;
  int b = blk >> 8, r = blk & 255, c = threadIdx.x;
  __shared__ u64 fv[4], bv[4], fh[4], bh[4];
  if (c < 4) {
    u64 vf = 0, vb = 0;
    for (int dr = -1; dr <= 1; dr++) {
      int rr = r + dr;
      if (rr < 0 || rr >= HH) continue;
      vf |= fgSeed[(size_t)b * WPI + rr * 4 + c];
      vb |= bgSeed[(size_t)b * WPI + rr * 4 + c];
    }
    fv[c] = vf; bv[c] = vb;
  }
  __syncthreads();
  if (c < 4) {
    u64 v = fv[c], L = (c > 0) ? fv[c - 1] : 0ull, R = (c < 3) ? fv[c + 1] : 0ull;
    fh[c] = v | (v << 1) | (L >> 63) | (v >> 1) | (R << 63);
    v = bv[c]; L = (c > 0) ? bv[c - 1] : 0ull; R = (c < 3) ? bv[c + 1] : 0ull;
    bh[c] = v | (v << 1) | (L >> 63) | (v >> 1) | (R << 63);
  }
  __syncthreads();
  int wi = c >> 6, bi = c & 63;
  bool fgd = (fh[wi] >> bi) & 1ull;
  bool bgd = (bh[wi] >> bi) & 1ull;
  int o = (fgd && bgd) ? -255 : (bgd ? 0 : (fgd ? 1 : -255));
  out[(size_t)blk * WW + c] = o;
}

extern "C" void kernel_launch(void* const* d_in, const int* in_sizes, int n_in,
                              void* d_out, int out_size, void* d_ws, size_t ws_size,
                              hipStream_t stream) {
  const float* x = (const float*)d_in[0];
  int* out = (int*)d_out;
  char* ws = (char*)d_ws;

  // small arrays
  float* th      = (float*)(ws + 0);
  u32*   bad     = (u32*)(ws + 1024);
  u32*   b1Arr   = (u32*)(ws + 2048);
  u32*   K2Arr   = (u32*)(ws + 3072);
  u32*   camT    = (u32*)(ws + 4096);
  int*   tieMax  = (int*)(ws + 5120);
  // masks region (8 MB). gPart (4.7 MB) aliases it: gPart is only live
  // K1->K2, strictly before any mask write.
  char* big = ws + 8192;
  u32* gPart    = (u32*)big;                       // [512][2304] u32
  u64* roiBits  = (u64*)(big + 0 * 2097152);
  u64* candBits = (u64*)(big + 1 * 2097152);
  u64* fgSeed   = (u64*)(big + 2 * 2097152);
  u64* bgSeed   = (u64*)(big + 3 * 2097152);

  u32 kf0, kf1, kb0, kb1;
#if PARTITIONABLE
  threefry2x32(0u, 42u, 0u, 0u, kf0, kf1);
  threefry2x32(0u, 42u, 0u, 1u, kb0, kb1);
#else
  u32 a0, a1, c0, c1;
  threefry2x32(0u, 42u, 0u, 2u, a0, a1);
  threefry2x32(0u, 42u, 1u, 3u, c0, c1);
  kf0 = a0; kf1 = c0; kb0 = a1; kb1 = c1;
#endif

  k1_hist<<<512, 1024, 0, stream>>>(x, gPart);
  k2_select1<<<BB, 256, 0, stream>>>(gPart, th, bad, b1Arr, K2Arr);
  k3_select2<<<BB, 1024, 0, stream>>>(x, b1Arr, K2Arr, camT, tieMax);
  k4_mark<<<BB, 1024, 0, stream>>>(x, th, camT, tieMax, roiBits, candBits);
  k5_seed<<<BB, 512, 0, stream>>>(roiBits, kf0, kf1, bad, fgSeed);
  k5_seed<<<BB, 512, 0, stream>>>(candBits, kb0, kb1, bad, bgSeed);
  k_out<<<BB * HH, 256, 0, stream>>>(fgSeed, bgSeed, out);
}

// Round 3
// 161.161 us; speedup vs baseline: 3.6254x; 1.3892x over previous
//
#include <hip/hip_runtime.h>
#include <stdint.h>

// MBSeederSLFCAMS — exact JAX replication; fused single-pass restructure.
#define PARTITIONABLE 1

typedef unsigned int u32;
typedef unsigned long long u64;

static constexpr int BB  = 256;
static constexpr int HH  = 256;
static constexpr int WW  = 256;
static constexpr int HWN = HH * WW;     // 65536
static constexpr int WPI = HWN / 64;    // 1024 u64 words per image
static constexpr u32 K_BG = 6553;       // int(0.1*65536)
static constexpr u32 TOPK = 100;

__host__ __device__ inline u32 rotl32(u32 x, int d) { return (x << d) | (x >> (32 - d)); }

#define TF_ROUND(r) do { x0 += x1; x1 = rotl32(x1, r); x1 ^= x0; } while (0)

__host__ __device__ inline void threefry2x32(u32 k0, u32 k1, u32 x0, u32 x1, u32& o0, u32& o1) {
  u32 ks2 = k0 ^ k1 ^ 0x1BD11BDAu;
  x0 += k0; x1 += k1;
  TF_ROUND(13); TF_ROUND(15); TF_ROUND(26); TF_ROUND(6);
  x0 += k1;  x1 += ks2 + 1u;
  TF_ROUND(17); TF_ROUND(29); TF_ROUND(16); TF_ROUND(24);
  x0 += ks2; x1 += k0 + 2u;
  TF_ROUND(13); TF_ROUND(15); TF_ROUND(26); TF_ROUND(6);
  x0 += k0;  x1 += k1 + 3u;
  TF_ROUND(17); TF_ROUND(29); TF_ROUND(16); TF_ROUND(24);
  x0 += k1;  x1 += ks2 + 4u;
  TF_ROUND(13); TF_ROUND(15); TF_ROUND(26); TF_ROUND(6);
  x0 += ks2; x1 += k0 + 5u;
  o0 = x0; o1 = x1;
}

__device__ inline u32 score_bits(u32 k0, u32 k1, u32 i) {
#if PARTITIONABLE
  u32 a, b;
  threefry2x32(k0, k1, 0u, i, a, b);
  return a ^ b;
#else
  const u32 HALF = 1u << 23;
  u32 a, b;
  if (i < HALF) { threefry2x32(k0, k1, i, i + HALF, a, b); return a; }
  threefry2x32(k0, k1, i - HALF, i, a, b); return b;
#endif
}

// =============== K_fused: one block per image, x read once into registers ====
// hist(otsu)+hist(cam) -> otsu threshold (parallel, first-max argmax) ->
// 3-stage cam radix select over registers -> tie sort -> roi/cand ballots ->
// 11x11 erosion. Emits roiBits, candBits, badArr.
__global__ __launch_bounds__(1024) void k_fused(const float* __restrict__ x,
                                                u64* __restrict__ roiBits,
                                                u64* __restrict__ candBits,
                                                u32* __restrict__ badArr) {
  int b = blockIdx.x, tid = threadIdx.x;
  int lane = tid & 63, w = tid >> 6;

  __shared__ u32 hO[256];
  __shared__ u32 hC[2048];
  __shared__ u32 psum[256];
  __shared__ float w1s[256], s1s[256];
  __shared__ u64 amax;
  __shared__ u32 eq[256];
  __shared__ u32 eqc, sh_a, sh_b, sh_nz;
  __shared__ float sh_th;
  __shared__ u64 rows[1024], hrows[1024];

  // ---- load image into registers: pixel i = c*1024 + tid
  u32 kb[64];
  const float* img = x + (size_t)b * HWN;
#pragma unroll
  for (int c = 0; c < 64; c++) kb[c] = __float_as_uint(img[c * 1024 + tid]);

  // ---- phase 0: zero
  if (tid < 256) hO[tid] = 0;
  hC[tid] = 0; hC[tid + 1024] = 0;
  if (tid == 0) { eqc = 0; amax = 0ull; }
  __syncthreads();

  // ---- phase 1: both histograms
#pragma unroll
  for (int c = 0; c < 64; c++) {
    float v = __uint_as_float(kb[c]);
    float f = floorf(v * 255.0f);
    f = fminf(fmaxf(f, 0.0f), 255.0f);
    atomicAdd(&hO[(int)f], 1u);
    atomicAdd(&hC[kb[c] >> 21], 1u);
  }
  __syncthreads();

  // ---- phase 2: psum of hC; serial Otsu cumsums (exact fp32) in tid 0
  if (tid < 256) { u32 l = 0; for (int j = 0; j < 8; j++) l += hC[tid * 8 + j]; psum[tid] = l; }
  if (tid == 0) {
    float wc = 0.f, sv = 0.f; int nz = 0;
    for (int t = 0; t < 256; t++) {
      float h = (float)hO[t];
      if (hO[t]) nz++;
      wc += h; w1s[t] = wc;
      sv += h * (float)t; s1s[t] = sv;
    }
    sh_nz = (u32)nz;
  }
  __syncthreads();

  // ---- phase 3: parallel inter-class variance + packed first-max argmax
  if (tid < 255) {
    int t = tid;
    float total = w1s[255], stot = s1s[255];
    float h1 = (float)hO[t + 1];
    float w1 = w1s[t];
    float w2 = total - w1s[t + 1] + h1;
    float s1 = s1s[t];
    float s2 = stot - s1s[t + 1] + h1 * (float)(t + 1);
    float m1 = s1 / fmaxf(w1, 1.0f);
    float m2 = s2 / fmaxf(w2, 1.0f);
    float d = m1 - m2;
    float v = (w1 * w2) * (d * d);           // v >= 0, bits order-isomorphic
    u64 key = ((u64)__float_as_uint(v) << 32) | (u32)(255 - t); // tie -> smallest t
    atomicMax(&amax, key);
  }
  __syncthreads();

  // ---- phase 4: threshold + cam radix stage 1 (top-11 bits)
  if (tid == 0) {
    int bi = 255 - (int)(amax & 0xFFFFFFFFu);
    float th = (float)bi;
    th = (th <= 0.0f) ? 1.0f : ((th >= 255.0f) ? 254.0f : th);
    sh_th = th;
    badArr[b] = (sh_nz <= 1u) ? 1u : 0u;
    u32 cum = 0; int seg = 0;
    for (int t = 0; t < 256; t++) { if (cum + psum[t] >= K_BG) { seg = t; break; } cum += psum[t]; }
    u32 bin = 0;
    for (int j = 0; j < 8; j++) { u32 h = hC[seg * 8 + j]; if (cum + h >= K_BG) { bin = seg * 8 + j; break; } cum += h; }
    sh_a = bin; sh_b = K_BG - cum;
  }
  __syncthreads();
  u32 b1 = sh_a, K2v = sh_b;
  __syncthreads();

  // ---- phase 5/6: stage A over bits [20:10] (registers re-scan)
  hC[tid] = 0; hC[tid + 1024] = 0;
  __syncthreads();
#pragma unroll
  for (int c = 0; c < 64; c++)
    if ((kb[c] >> 21) == b1) atomicAdd(&hC[(kb[c] >> 10) & 0x7FFu], 1u);
  __syncthreads();
  if (tid < 256) { u32 l = 0; for (int j = 0; j < 8; j++) l += hC[tid * 8 + j]; psum[tid] = l; }
  __syncthreads();
  if (tid == 0) {
    u32 cum = 0; int seg = 0;
    for (int t = 0; t < 256; t++) { if (cum + psum[t] >= K2v) { seg = t; break; } cum += psum[t]; }
    u32 bin = 0;
    for (int j = 0; j < 8; j++) { u32 h = hC[seg * 8 + j]; if (cum + h >= K2v) { bin = seg * 8 + j; break; } cum += h; }
    sh_a = bin; sh_b = K2v - cum;
  }
  __syncthreads();
  u32 bA = sh_a, K3v = sh_b;
  u32 hi22 = (b1 << 11) | bA;
  __syncthreads();

  // ---- phase 9/10: stage B over bits [9:0]
  if (tid < 1024) hC[tid] = 0;
  __syncthreads();
#pragma unroll
  for (int c = 0; c < 64; c++)
    if ((kb[c] >> 10) == hi22) atomicAdd(&hC[kb[c] & 0x3FFu], 1u);
  __syncthreads();
  if (tid < 256) { u32 l = 0; for (int j = 0; j < 4; j++) l += hC[tid * 4 + j]; psum[tid] = l; }
  __syncthreads();
  if (tid == 0) {
    u32 cum = 0; int seg = 0;
    for (int t = 0; t < 256; t++) { if (cum + psum[t] >= K3v) { seg = t; break; } cum += psum[t]; }
    u32 bin = 0;
    for (int j = 0; j < 4; j++) { u32 h = hC[seg * 4 + j]; if (cum + h >= K3v) { bin = seg * 4 + j; break; } cum += h; }
    sh_a = (bA << 10) | bin;   // low 21 bits of threshold value
    sh_b = K3v - cum;          // ties to take (lowest index first)
  }
  __syncthreads();
  u32 T = (b1 << 21) | sh_a;
  u32 ties = sh_b;
  __syncthreads();

  // ---- phase 13: collect indices equal to T, sort, pick ties-th smallest
#pragma unroll
  for (int c = 0; c < 64; c++) {
    if (kb[c] == T) { u32 p = atomicAdd(&eqc, 1u); if (p < 256) eq[p] = (u32)(c * 1024 + tid); }
  }
  __syncthreads();
  if (tid == 0) {
    u32 n = eqc < 256u ? eqc : 256u;
    for (u32 i2 = 1; i2 < n; i2++) { u32 v = eq[i2]; int j = (int)i2 - 1; while (j >= 0 && eq[j] > v) { eq[j + 1] = eq[j]; j--; } eq[j + 1] = v; }
    sh_a = (ties > 0) ? eq[ties - 1] : 0xFFFFFFFFu;  // tieMax (as unsigned; none -> sentinel)
  }
  __syncthreads();
  int tmax = (sh_a == 0xFFFFFFFFu) ? -1 : (int)sh_a;
  float th = sh_th;

  // ---- phase 15: roi + cand ballots
  u64* crow = candBits + (size_t)b * WPI;
#pragma unroll
  for (int c = 0; c < 64; c++) {
    float v = __uint_as_float(kb[c]);
    int i = c * 1024 + tid;
    bool roip = floorf(v * 255.0f) > th;
    bool candp = (kb[c] < T) || (kb[c] == T && i <= tmax);
    u64 br = __ballot(roip);
    u64 bc = __ballot(candp);
    if (lane == 0) { int wid = c * 16 + w; rows[wid] = br; crow[wid] = bc; }
  }
  __syncthreads();

  // ---- phase 16: 11x11 erosion (OOB = 1)
  if (tid < 256) {
    int r = tid;
    u64 wv[4], h0[4];
    for (int j = 0; j < 4; j++) { wv[j] = rows[r * 4 + j]; h0[j] = wv[j]; }
    for (int s = 1; s <= 5; s++) {
      for (int j = 0; j < 4; j++) {
        u64 hi = (j < 3) ? wv[j + 1] : ~0ull;
        u64 lo = (j > 0) ? wv[j - 1] : ~0ull;
        u64 A  = (wv[j] >> s) | (hi << (64 - s));
        u64 Bv = (wv[j] << s) | (lo >> (64 - s));
        h0[j] &= A & Bv;
      }
    }
    for (int j = 0; j < 4; j++) hrows[r * 4 + j] = h0[j];
  }
  __syncthreads();
  if (tid < 256) {
    int r = tid;
    u64 res[4] = {hrows[r * 4], hrows[r * 4 + 1], hrows[r * 4 + 2], hrows[r * 4 + 3]};
    for (int dr = -5; dr <= 5; dr++) {
      if (dr == 0) continue;
      int rr = r + dr;
      if (rr < 0 || rr >= HH) continue;
      for (int j = 0; j < 4; j++) res[j] &= hrows[rr * 4 + j];
    }
    u64* orow = roiBits + (size_t)b * WPI + r * 4;
    for (int j = 0; j < 4; j++) orow[j] = res[j];
  }
}

// =============== K5: fg+bg in one dispatch; threefry per set bit; top-100 ====
__global__ __launch_bounds__(512) void k5_seed(const u64* __restrict__ roiBits,
                                               const u64* __restrict__ candBits,
                                               u32 kf0, u32 kf1, u32 kb0, u32 kb1,
                                               const u32* __restrict__ badArr,
                                               u64* __restrict__ fgSeed,
                                               u64* __restrict__ bgSeed) {
  int gb = blockIdx.x, tid = threadIdx.x;
  bool isFg = gb < BB;
  int b = gb & (BB - 1);
  const u64* mask = isFg ? roiBits : candBits;
  u64* seedOut = isFg ? fgSeed : bgSeed;
  u32 key0 = isFg ? kf0 : kb0;
  u32 key1 = isFg ? kf1 : kb1;

  __shared__ u64 list[8192];
  __shared__ u64 seedRows[1024];
  __shared__ u32 hist[4096];
  __shared__ u32 psum[256];
  __shared__ u32 eq[256];
  __shared__ u32 cnt, eqc, sh_a, sh_b;
  if (tid == 0) { cnt = 0; eqc = 0; }
  for (int j = tid; j < 1024; j += 512) seedRows[j] = 0;
  __syncthreads();
  const u64* mrow = mask + (size_t)b * WPI;
  for (int wi = tid; wi < 1024; wi += 512) {
    u64 wv = mrow[wi];
    while (wv) {
      int bit = __ffsll((long long)wv) - 1; wv &= wv - 1;
      u32 idx = (u32)(wi * 64 + bit);
      u32 m = score_bits(key0, key1, ((u32)b << 16) | idx) >> 9;
      u32 pos = atomicAdd(&cnt, 1u);
      if (pos < 8192) list[pos] = ((u64)m << 16) | idx;
    }
  }
  __syncthreads();
  u32 cntC = cnt < 8192u ? cnt : 8192u;
  u32 keff = cntC < TOPK ? cntC : TOPK;
  if (keff > 0) {
    for (int j = tid; j < 2048; j += 512) hist[j] = 0;
    __syncthreads();
    for (u32 e = tid; e < cntC; e += 512) { u32 m = (u32)(list[e] >> 16); atomicAdd(&hist[m >> 12], 1u); }
    __syncthreads();
    if (tid < 256) { u32 l = 0; for (int j = 0; j < 8; j++) l += hist[tid * 8 + j]; psum[tid] = l; }
    __syncthreads();
    if (tid == 0) {
      u32 cum = 0; int seg = 0;
      for (int t = 255; t >= 0; t--) { if (cum + psum[t] >= keff) { seg = t; break; } cum += psum[t]; }
      u32 bin = 0;
      for (int j = 7; j >= 0; j--) { u32 h = hist[seg * 8 + j]; if (cum + h >= keff) { bin = seg * 8 + j; break; } cum += h; }
      sh_a = bin; sh_b = keff - cum;
    }
    __syncthreads();
    u32 b1s = sh_a, k2 = sh_b;
    __syncthreads();
    for (int j = tid; j < 4096; j += 512) hist[j] = 0;
    __syncthreads();
    for (u32 e = tid; e < cntC; e += 512) { u32 m = (u32)(list[e] >> 16); if ((m >> 12) == b1s) atomicAdd(&hist[m & 0xFFFu], 1u); }
    __syncthreads();
    if (tid < 256) { u32 l = 0; for (int j = 0; j < 16; j++) l += hist[tid * 16 + j]; psum[tid] = l; }
    __syncthreads();
    if (tid == 0) {
      u32 cum = 0; int seg = 0;
      for (int t = 255; t >= 0; t--) { if (cum + psum[t] >= k2) { seg = t; break; } cum += psum[t]; }
      u32 bin = 0;
      for (int j = 15; j >= 0; j--) { u32 h = hist[seg * 16 + j]; if (cum + h >= k2) { bin = seg * 16 + j; break; } cum += h; }
      sh_a = (b1s << 12) | bin;
      sh_b = k2 - cum;
    }
    __syncthreads();
    u32 S = sh_a, tiesS = sh_b;
    for (u32 e = tid; e < cntC; e += 512) {
      u64 le = list[e];
      if ((u32)(le >> 16) == S) { u32 p = atomicAdd(&eqc, 1u); if (p < 256) eq[p] = (u32)(le & 0xFFFFu); }
    }
    __syncthreads();
    if (tid == 0) {
      u32 n = eqc < 256u ? eqc : 256u;
      for (u32 i2 = 1; i2 < n; i2++) { u32 v = eq[i2]; int j = (int)i2 - 1; while (j >= 0 && eq[j] > v) { eq[j + 1] = eq[j]; j--; } eq[j + 1] = v; }
      sh_a = (tiesS > 0) ? eq[tiesS - 1] : 0xFFFFFFFFu;
    }
    __syncthreads();
    u32 tmaxU = sh_a;
    bool dead = badArr[b] != 0u;
    if (!dead) {
      for (u32 e = tid; e < cntC; e += 512) {
        u64 le = list[e];
        u32 m = (u32)(le >> 16);
        u32 idx = (u32)(le & 0xFFFFu);
        bool sel = (m > S) || (m == S && tmaxU != 0xFFFFFFFFu && idx <= tmaxU);
        if (sel) atomicOr(&seedRows[idx >> 6], 1ull << (idx & 63));
      }
    }
  }
  __syncthreads();
  u64* srow = seedOut + (size_t)b * WPI;
  for (int j = tid; j < 1024; j += 512) srow[j] = seedRows[j];
}

// =============== K_out v2: one image per block, int4 coalesced emit ==========
__global__ __launch_bounds__(1024) void k_out2(const u64* __restrict__ fgSeed,
                                               const u64* __restrict__ bgSeed,
                                               int* __restrict__ out) {
  int b = blockIdx.x, tid = threadIdx.x;
  __shared__ u64 fgL[1024], bgL[1024];
  __shared__ u64 fvL[1024], bvL[1024];
  __shared__ u64 fhL[1024], bhL[1024];
  fgL[tid] = fgSeed[(size_t)b * WPI + tid];
  bgL[tid] = bgSeed[(size_t)b * WPI + tid];
  __syncthreads();
  {
    int r = tid >> 2, j = tid & 3;
    u64 vf = fgL[tid], vb = bgL[tid];
    if (r > 0)   { vf |= fgL[tid - 4]; vb |= bgL[tid - 4]; }
    if (r < 255) { vf |= fgL[tid + 4]; vb |= bgL[tid + 4]; }
    fvL[tid] = vf; bvL[tid] = vb;
  }
  __syncthreads();
  {
    int j = tid & 3;
    u64 v = fvL[tid];
    u64 L = (j > 0) ? fvL[tid - 1] : 0ull;
    u64 R = (j < 3) ? fvL[tid + 1] : 0ull;
    fhL[tid] = v | (v << 1) | (L >> 63) | (v >> 1) | (R << 63);
    v = bvL[tid];
    L = (j > 0) ? bvL[tid - 1] : 0ull;
    R = (j < 3) ? bvL[tid + 1] : 0ull;
    bhL[tid] = v | (v << 1) | (L >> 63) | (v >> 1) | (R << 63);
  }
  __syncthreads();
  int4* out4 = (int4*)(out + (size_t)b * HWN);
#define PIXV(f, g) (((f) && (g)) ? -255 : ((g) ? 0 : ((f) ? 1 : -255)))
  for (int it = 0; it < 16; it++) {
    int idx4 = it * 1024 + tid;
    int word = idx4 >> 4;
    int sh = (idx4 & 15) * 4;
    u32 fb = (u32)(fhL[word] >> sh) & 0xFu;
    u32 gb = (u32)(bhL[word] >> sh) & 0xFu;
    int4 o;
    o.x = PIXV(fb & 1u, gb & 1u);
    o.y = PIXV((fb >> 1) & 1u, (gb >> 1) & 1u);
    o.z = PIXV((fb >> 2) & 1u, (gb >> 2) & 1u);
    o.w = PIXV((fb >> 3) & 1u, (gb >> 3) & 1u);
    out4[idx4] = o;
  }
#undef PIXV
}

extern "C" void kernel_launch(void* const* d_in, const int* in_sizes, int n_in,
                              void* d_out, int out_size, void* d_ws, size_t ws_size,
                              hipStream_t stream) {
  const float* x = (const float*)d_in[0];
  int* out = (int*)d_out;
  char* ws = (char*)d_ws;

  u32* bad      = (u32*)(ws + 0);
  char* big     = ws + 8192;
  u64* roiBits  = (u64*)(big + 0 * 2097152);
  u64* candBits = (u64*)(big + 1 * 2097152);
  u64* fgSeed   = (u64*)(big + 2 * 2097152);
  u64* bgSeed   = (u64*)(big + 3 * 2097152);

  u32 kf0, kf1, kb0, kb1;
#if PARTITIONABLE
  threefry2x32(0u, 42u, 0u, 0u, kf0, kf1);
  threefry2x32(0u, 42u, 0u, 1u, kb0, kb1);
#else
  u32 a0, a1, c0, c1;
  threefry2x32(0u, 42u, 0u, 2u, a0, a1);
  threefry2x32(0u, 42u, 1u, 3u, c0, c1);
  kf0 = a0; kf1 = c0; kb0 = a1; kb1 = c1;
#endif

  k_fused<<<BB, 1024, 0, stream>>>(x, roiBits, candBits, bad);
  k5_seed<<<2 * BB, 512, 0, stream>>>(roiBits, candBits, kf0, kf1, kb0, kb1, bad, fgSeed, bgSeed);
  k_out2<<<BB, 1024, 0, stream>>>(fgSeed, bgSeed, out);
}

// Round 4
// 161.047 us; speedup vs baseline: 3.6280x; 1.0007x over previous
//
#include <hip/hip_runtime.h>
#include <stdint.h>

// MBSeederSLFCAMS — exact JAX replication; single fused kernel, x read once.
#define PARTITIONABLE 1

typedef unsigned int u32;
typedef unsigned long long u64;
typedef unsigned char u8;

static constexpr int BB  = 256;
static constexpr int HH  = 256;
static constexpr int WW  = 256;
static constexpr int HWN = 65536;
static constexpr int WPI = 1024;
static constexpr u32 K_BG = 6553;
static constexpr u32 TOPK = 100;
static constexpr u32 CAP  = 7936;     // list capacity (62 KB of u64)
static constexpr u32 FG_CAP = 1024;

// ---- shared arena layout (bytes). Live ranges verified phase by phase.
static constexpr int OFF_LIST   = 0;       // u64[7936]  ph1-ph5(bg seed)
static constexpr int OFF_CIMG   = 63488;   // u8[65536]  ph1-ph6
static constexpr int OFF_HROWS  = 63488;   // u64[1024]  ph7 (cImg dead)
static constexpr int OFF_FVL    = 63488;   // u64[1024]  ph10 (hrows dead)
static constexpr int OFF_FGLIST = 71680;   // u64[1024]  ph8-9
static constexpr int OFF_BVL    = 71680;   // u64[1024]  ph10 (fgList dead)
static constexpr int OFF_SEEDB  = 79872;   // u64[1024]  ph5-10
static constexpr int OFF_SEEDF  = 88064;   // u64[1024]  ph9-10
static constexpr int OFF_FHL    = 96256;   // u64[1024]  ph10
static constexpr int OFF_BHL    = 104448;  // u64[1024]  ph10
static constexpr int OFF_ROWS   = 129024;  // u64[1024]  ph6-8
static constexpr int OFF_HC     = 129024;  // u32[2048]  ph3 fallback only
static constexpr int OFF_HO     = 137216;  // u32[256]
static constexpr int OFF_HIST   = 138240;  // u32[256]
static constexpr int OFF_EQ     = 139264;  // u32[256]
static constexpr int OFF_W1S    = 140288;  // f32[256]
static constexpr int OFF_S1S    = 141312;  // f32[256]
static constexpr int OFF_AMAX   = 142336;  // u64
static constexpr int OFF_SCAL   = 142344;  // u32[14]
static constexpr int ARENA_BYTES = 142400; // < 160 KiB/CU

__host__ __device__ inline u32 rotl32(u32 x, int d) { return (x << d) | (x >> (32 - d)); }

#define TF_ROUND(r) do { x0 += x1; x1 = rotl32(x1, r); x1 ^= x0; } while (0)

__host__ __device__ inline void threefry2x32(u32 k0, u32 k1, u32 x0, u32 x1, u32& o0, u32& o1) {
  u32 ks2 = k0 ^ k1 ^ 0x1BD11BDAu;
  x0 += k0; x1 += k1;
  TF_ROUND(13); TF_ROUND(15); TF_ROUND(26); TF_ROUND(6);
  x0 += k1;  x1 += ks2 + 1u;
  TF_ROUND(17); TF_ROUND(29); TF_ROUND(16); TF_ROUND(24);
  x0 += ks2; x1 += k0 + 2u;
  TF_ROUND(13); TF_ROUND(15); TF_ROUND(26); TF_ROUND(6);
  x0 += k0;  x1 += k1 + 3u;
  TF_ROUND(17); TF_ROUND(29); TF_ROUND(16); TF_ROUND(24);
  x0 += k1;  x1 += ks2 + 4u;
  TF_ROUND(13); TF_ROUND(15); TF_ROUND(26); TF_ROUND(6);
  x0 += ks2; x1 += k0 + 5u;
  o0 = x0; o1 = x1;
}

__device__ inline u32 score_bits(u32 k0, u32 k1, u32 i) {
#if PARTITIONABLE
  u32 a, b;
  threefry2x32(k0, k1, 0u, i, a, b);
  return a ^ b;
#else
  const u32 HALF = 1u << 23;
  u32 a, b;
  if (i < HALF) { threefry2x32(k0, k1, i, i + HALF, a, b); return a; }
  threefry2x32(k0, k1, i - HALF, i, a, b); return b;
#endif
}

// ---- ascending rank-K radix select over key=(u32)(lst[e]>>16).
// Returns key of K-th smallest; *tiesOut = #to-take among ==key (lowest idx).
__device__ __forceinline__ u32 radix_asc(const u64* lst, u32 n, u32 K, int nst,
                                         const int* lo, const int* nb,
                                         u32* hist, u32* sc, u32 tid, u32* tiesOut) {
  u32 pref = 0, Krem = K;
  for (int st = 0; st < nst; ++st) {
    if (tid < 256) hist[tid] = 0;
    __syncthreads();
    int bins = 1 << nb[st];
    int hiSh = lo[st] + nb[st];
    for (u32 e = tid; e < n; e += 1024) {
      u32 key = (u32)(lst[e] >> 16);
      if (st == 0 || (key >> hiSh) == pref)
        atomicAdd(&hist[(key >> lo[st]) & (u32)(bins - 1)], 1u);
    }
    __syncthreads();
    if (tid == 0) {
      u32 cum = 0;
      for (int t = 0; t < bins; t++) {
        u32 h = hist[t];
        if (cum + h >= Krem) { sc[0] = (pref << nb[st]) | (u32)t; sc[1] = Krem - cum; break; }
        cum += h;
      }
    }
    __syncthreads();
    pref = sc[0]; Krem = sc[1];
    __syncthreads();
  }
  *tiesOut = Krem;
  return pref;
}

// ---- descending rank-K radix select (top-K), same conventions.
__device__ __forceinline__ u32 radix_desc(const u64* lst, u32 n, u32 K, int nst,
                                          const int* lo, const int* nb,
                                          u32* hist, u32* sc, u32 tid, u32* tiesOut) {
  u32 pref = 0, Krem = K;
  for (int st = 0; st < nst; ++st) {
    if (tid < 256) hist[tid] = 0;
    __syncthreads();
    int bins = 1 << nb[st];
    int hiSh = lo[st] + nb[st];
    for (u32 e = tid; e < n; e += 1024) {
      u32 key = (u32)(lst[e] >> 16);
      if (st == 0 || (key >> hiSh) == pref)
        atomicAdd(&hist[(key >> lo[st]) & (u32)(bins - 1)], 1u);
    }
    __syncthreads();
    if (tid == 0) {
      u32 cum = 0;
      for (int t = bins - 1; t >= 0; t--) {
        u32 h = hist[t];
        if (cum + h >= Krem) { sc[0] = (pref << nb[st]) | (u32)t; sc[1] = Krem - cum; break; }
        cum += h;
      }
    }
    __syncthreads();
    pref = sc[0]; Krem = sc[1];
    __syncthreads();
  }
  *tiesOut = Krem;
  return pref;
}

// ---- top-100-by-threefry seeding from an idx list (low16 of lst entries).
// Overwrites lst entries with (m<<16|idx); marks seedRows bits.
__device__ __forceinline__ void seed_from_idx(u64* lst, u32 n, u32 k0, u32 k1, u32 bimg,
                                              u64* seedRows, u32* hist, u32* eqA,
                                              u32* scal, bool dead, u32 tid) {
  seedRows[tid] = 0;
  for (u32 e = tid; e < n; e += 1024) {
    u32 idx = (u32)(lst[e] & 0xFFFFu);
    u32 m = score_bits(k0, k1, (bimg << 16) | idx) >> 9;   // 23-bit score
    lst[e] = ((u64)m << 16) | idx;
  }
  __syncthreads();
  u32 keff = n < TOPK ? n : TOPK;
  if (keff == 0) return;                                    // uniform branch
  const int lo3[3] = {15, 7, 0}; const int nb3[3] = {8, 8, 7};
  u32 tiesS;
  u32 S = radix_desc(lst, n, keff, 3, lo3, nb3, hist, scal + 2, tid, &tiesS);
  if (tid == 0) scal[1] = 0;
  __syncthreads();
  for (u32 e = tid; e < n; e += 1024) {
    u64 le = lst[e];
    if ((u32)(le >> 16) == S) { u32 p = atomicAdd(&scal[1], 1u); if (p < 256) eqA[p] = (u32)(le & 0xFFFFu); }
  }
  __syncthreads();
  if (tid == 0) {
    u32 ne = scal[1] < 256u ? scal[1] : 256u;
    for (u32 i2 = 1; i2 < ne; i2++) { u32 v = eqA[i2]; int j = (int)i2 - 1; while (j >= 0 && eqA[j] > v) { eqA[j + 1] = eqA[j]; j--; } eqA[j + 1] = v; }
    scal[2] = (tiesS > 0) ? eqA[tiesS - 1] : 0xFFFFFFFFu;
  }
  __syncthreads();
  u32 tmaxU = scal[2];
  if (!dead) {
    for (u32 e = tid; e < n; e += 1024) {
      u64 le = lst[e];
      u32 m = (u32)(le >> 16), idx = (u32)(le & 0xFFFFu);
      bool sel = (m > S) || (m == S && tmaxU != 0xFFFFFFFFu && idx <= tmaxU);
      if (sel) atomicOr(&seedRows[idx >> 6], 1ull << (idx & 63));
    }
  }
  __syncthreads();
}

__global__ __launch_bounds__(1024, 1) void k_all(const float* __restrict__ x,
                                                 u32 kf0, u32 kf1, u32 kb0, u32 kb1,
                                                 int* __restrict__ out) {
  __shared__ __align__(16) char arena[ARENA_BYTES];
  int b = blockIdx.x, tid = threadIdx.x;
  int lane = tid & 63, w = tid >> 6;

  u64* lst    = (u64*)(arena + OFF_LIST);
  u8*  cImg   = (u8*)(arena + OFF_CIMG);
  u32* hO     = (u32*)(arena + OFF_HO);
  u32* hist   = (u32*)(arena + OFF_HIST);
  u32* eqA    = (u32*)(arena + OFF_EQ);
  float* w1s  = (float*)(arena + OFF_W1S);
  float* s1s  = (float*)(arena + OFF_S1S);
  u64* amax   = (u64*)(arena + OFF_AMAX);
  u32* scal   = (u32*)(arena + OFF_SCAL);
  u64* rows   = (u64*)(arena + OFF_ROWS);
  u64* hrows  = (u64*)(arena + OFF_HROWS);
  u64* fgList = (u64*)(arena + OFF_FGLIST);
  u64* seedB  = (u64*)(arena + OFF_SEEDB);
  u64* seedF  = (u64*)(arena + OFF_SEEDF);

  const u32 BOUND_BITS = __float_as_uint(0.110f);
  const float* img = x + (size_t)b * HWN;

  // ---- phase 0: zero
  if (tid < 256) hO[tid] = 0;
  if (tid < 14) scal[tid] = 0;
  if (tid == 14) *amax = 0ull;
  __syncthreads();

  // ---- phase 1: single scan: cImg byte, otsu hist, bounded-list push
#pragma unroll 4
  for (int c = 0; c < 64; c++) {
    int i = (c << 10) + tid;
    float v = img[i];
    u32 kbv = __float_as_uint(v);
    float f = floorf(v * 255.0f);
    f = fminf(fmaxf(f, 0.0f), 255.0f);
    int cb = (int)f;
    cImg[i] = (u8)cb;
    atomicAdd(&hO[cb], 1u);
    bool q = kbv < BOUND_BITS;
    u64 bal = __ballot(q);
    u32 nq = (u32)__popcll(bal);
    u32 base = 0;
    if (lane == 0 && nq) base = atomicAdd(&scal[0], nq);
    base = __shfl(base, 0);
    if (q) {
      u32 pos = base + (u32)__popcll(bal & ((1ull << lane) - 1ull));
      if (pos < CAP) lst[pos] = ((u64)kbv << 16) | (u32)i;
    }
  }
  __syncthreads();
  u32 cntBelow = scal[0];

  // ---- phase 2: Otsu (exact fp32 cumsums; first-max argmax via packed key)
  if (tid == 0) {
    float wc = 0.f, sv = 0.f; int nz = 0;
    for (int t = 0; t < 256; t++) {
      float h = (float)hO[t];
      if (hO[t]) nz++;
      wc += h; w1s[t] = wc;
      sv += h * (float)t; s1s[t] = sv;
    }
    scal[4] = (u32)nz;
  }
  __syncthreads();
  if (tid < 255) {
    int t = tid;
    float total = w1s[255], stot = s1s[255];
    float h1 = (float)hO[t + 1];
    float w1 = w1s[t];
    float w2 = total - w1s[t + 1] + h1;
    float s1 = s1s[t];
    float s2 = stot - s1s[t + 1] + h1 * (float)(t + 1);
    float m1 = s1 / fmaxf(w1, 1.0f);
    float m2 = s2 / fmaxf(w2, 1.0f);
    float d = m1 - m2;
    float v = (w1 * w2) * (d * d);
    u64 key = ((u64)__float_as_uint(v) << 32) | (u32)(255 - t);
    atomicMax((unsigned long long*)amax, (unsigned long long)key);
  }
  __syncthreads();
  if (tid == 0) {
    int bi = 255 - (int)(*amax & 0xFFFFFFFFu);
    float th = (float)bi;
    th = (th <= 0.0f) ? 1.0f : ((th >= 255.0f) ? 254.0f : th);
    scal[8] = (u32)(int)th;
    scal[5] = (scal[4] <= 1u) ? 1u : 0u;   // bad
  }
  __syncthreads();
  int thi = (int)scal[8];
  bool dead = scal[5] != 0u;

  // ---- phase 3: cam rank-K_BG select
  bool fastOK = (cntBelow >= K_BG && cntBelow <= CAP);
  u32 T, ties, keyeq, listN;
  if (fastOK) {
    listN = cntBelow;
    const int lo4[4] = {24, 16, 8, 0}; const int nb4[4] = {8, 8, 8, 8};
    T = radix_asc(lst, listN, K_BG, 4, lo4, nb4, hist, scal + 2, tid, &ties);
    keyeq = T;
  } else {
    // exact fallback: 11-bit histogram + bin collect + 21-bit select (rescans x)
    u32* hC = (u32*)(arena + OFF_HC);
    for (int j = tid; j < 2048; j += 1024) hC[j] = 0;
    __syncthreads();
    for (int c = 0; c < 64; c++) {
      u32 kbv = __float_as_uint(img[(c << 10) + tid]);
      atomicAdd(&hC[kbv >> 21], 1u);
    }
    __syncthreads();
    if (tid == 0) {
      u32 cum = 0;
      for (int t = 0; t < 2048; t++) { u32 h = hC[t]; if (cum + h >= K_BG) { scal[2] = (u32)t; scal[3] = K_BG - cum; break; } cum += h; }
    }
    __syncthreads();
    u32 b1 = scal[2], K2v = scal[3];
    if (tid == 0) scal[0] = 0;
    __syncthreads();
    for (int c = 0; c < 64; c++) {
      int i = (c << 10) + tid;
      u32 kbv = __float_as_uint(img[i]);
      if ((kbv >> 21) == b1) { u32 p = atomicAdd(&scal[0], 1u); if (p < CAP) lst[p] = ((u64)(kbv & 0x1FFFFFu) << 16) | (u32)i; }
    }
    __syncthreads();
    listN = scal[0] < CAP ? scal[0] : CAP;
    const int lo3[3] = {16, 8, 0}; const int nb3[3] = {5, 8, 8};
    u32 low21 = radix_asc(lst, listN, K2v, 3, lo3, nb3, hist, scal + 2, tid, &ties);
    T = (b1 << 21) | low21;
    keyeq = low21;
  }
  // eq collect + tie index sort (ties <= K_BG but taken count <= ties <= keff bounds; eq cap 256)
  if (tid == 0) scal[1] = 0;
  __syncthreads();
  for (u32 e = tid; e < listN; e += 1024) {
    u64 le = lst[e];
    if ((u32)(le >> 16) == keyeq) { u32 p = atomicAdd(&scal[1], 1u); if (p < 256) eqA[p] = (u32)(le & 0xFFFFu); }
  }
  __syncthreads();
  if (tid == 0) {
    u32 ne = scal[1] < 256u ? scal[1] : 256u;
    for (u32 i2 = 1; i2 < ne; i2++) { u32 v = eqA[i2]; int j = (int)i2 - 1; while (j >= 0 && eqA[j] > v) { eqA[j + 1] = eqA[j]; j--; } eqA[j + 1] = v; }
    scal[2] = (ties > 0) ? eqA[ties - 1] : 0xFFFFFFFFu;
  }
  __syncthreads();
  int tmax = (scal[2] == 0xFFFFFFFFu) ? -1 : (int)scal[2];
  __syncthreads();

  // ---- phase 4: build candidate idx list (exactly K_BG entries) in lst
  if (fastOK) {
    u64 mine[8]; int nm = 0;
    for (u32 e = tid; e < listN; e += 1024) mine[nm++] = lst[e];
    __syncthreads();
    if (tid == 0) scal[6] = 0;
    __syncthreads();
    for (int k = 0; k < nm; k++) {
      u32 key = (u32)(mine[k] >> 16);
      int idx = (int)(mine[k] & 0xFFFFu);
      bool sel = (key < T) || (key == T && idx <= tmax);
      if (sel) { u32 p = atomicAdd(&scal[6], 1u); lst[p] = mine[k]; }
    }
    __syncthreads();
  } else {
    if (tid == 0) scal[6] = 0;
    __syncthreads();
    for (int c = 0; c < 64; c++) {
      int i = (c << 10) + tid;
      u32 kbv = __float_as_uint(img[i]);
      bool sel = (kbv < T) || (kbv == T && i <= tmax);
      if (sel) { u32 p = atomicAdd(&scal[6], 1u); if (p < CAP) lst[p] = (u64)(u32)i; }
    }
    __syncthreads();
  }
  u32 candN = scal[6] < CAP ? scal[6] : CAP;

  // ---- phase 6: ROI ballots from cImg
#pragma unroll 4
  for (int c = 0; c < 64; c++) {
    int i = (c << 10) + tid;
    bool roip = (int)cImg[i] > thi;
    u64 br = __ballot(roip);
    if (lane == 0) rows[c * 16 + w] = br;
  }
  __syncthreads();

  // ---- phase 7: 11x11 erosion (OOB = 1); result back into rows
  if (tid < 256) {
    int r = tid;
    u64 wv[4], h0[4];
    for (int j = 0; j < 4; j++) { wv[j] = rows[r * 4 + j]; h0[j] = wv[j]; }
    for (int s = 1; s <= 5; s++) {
      for (int j = 0; j < 4; j++) {
        u64 hi = (j < 3) ? wv[j + 1] : ~0ull;
        u64 lo = (j > 0) ? wv[j - 1] : ~0ull;
        u64 A  = (wv[j] >> s) | (hi << (64 - s));
        u64 Bv = (wv[j] << s) | (lo >> (64 - s));
        h0[j] &= A & Bv;
      }
    }
    for (int j = 0; j < 4; j++) hrows[r * 4 + j] = h0[j];
  }
  __syncthreads();
  if (tid < 256) {
    int r = tid;
    u64 res[4] = {hrows[r * 4], hrows[r * 4 + 1], hrows[r * 4 + 2], hrows[r * 4 + 3]};
    for (int dr = -5; dr <= 5; dr++) {
      if (dr == 0) continue;
      int rr = r + dr;
      if (rr < 0 || rr >= HH) continue;
      for (int j = 0; j < 4; j++) res[j] &= hrows[rr * 4 + j];
    }
    for (int j = 0; j < 4; j++) rows[r * 4 + j] = res[j];
  }
  __syncthreads();

  // ---- phase 8: extract fg (roi) indices
  if (tid == 0) scal[7] = 0;
  __syncthreads();
  {
    u64 wv = rows[tid];
    while (wv) {
      int bit = __ffsll((long long)wv) - 1; wv &= wv - 1;
      u32 p = atomicAdd(&scal[7], 1u);
      if (p < FG_CAP) fgList[p] = (u64)(u32)(tid * 64 + bit);
    }
  }
  __syncthreads();
  u32 fgN = scal[7] < FG_CAP ? scal[7] : FG_CAP;

  // ---- phase 5: bg seeds (top-100 kb-scores over candidates)
  seed_from_idx(lst, candN, kb0, kb1, (u32)b, seedB, hist, eqA, scal, dead, tid);
  // ---- phase 9: fg seeds (top-100 kf-scores over eroded roi)
  seed_from_idx(fgList, fgN, kf0, kf1, (u32)b, seedF, hist, eqA, scal, dead, tid);

  // ---- phase 10: 3x3 dilation + conflict resolve + int4 emit
  u64* fvL = (u64*)(arena + OFF_FVL);
  u64* bvL = (u64*)(arena + OFF_BVL);
  u64* fhL = (u64*)(arena + OFF_FHL);
  u64* bhL = (u64*)(arena + OFF_BHL);
  {
    int r = tid >> 2;
    u64 vf = seedF[tid], vb = seedB[tid];
    if (r > 0)   { vf |= seedF[tid - 4]; vb |= seedB[tid - 4]; }
    if (r < 255) { vf |= seedF[tid + 4]; vb |= seedB[tid + 4]; }
    fvL[tid] = vf; bvL[tid] = vb;
  }
  __syncthreads();
  {
    int j = tid & 3;
    u64 v = fvL[tid];
    u64 L = (j > 0) ? fvL[tid - 1] : 0ull;
    u64 R = (j < 3) ? fvL[tid + 1] : 0ull;
    fhL[tid] = v | (v << 1) | (L >> 63) | (v >> 1) | (R << 63);
    v = bvL[tid];
    L = (j > 0) ? bvL[tid - 1] : 0ull;
    R = (j < 3) ? bvL[tid + 1] : 0ull;
    bhL[tid] = v | (v << 1) | (L >> 63) | (v >> 1) | (R << 63);
  }
  __syncthreads();
  int4* out4 = (int4*)(out + (size_t)b * HWN);
#define PIXV(f, g) (((f) && (g)) ? -255 : ((g) ? 0 : ((f) ? 1 : -255)))
  for (int it = 0; it < 16; it++) {
    int idx4 = it * 1024 + tid;
    int word = idx4 >> 4;
    int sh = (idx4 & 15) * 4;
    u32 fb = (u32)(fhL[word] >> sh) & 0xFu;
    u32 gb = (u32)(bhL[word] >> sh) & 0xFu;
    int4 o;
    o.x = PIXV(fb & 1u, gb & 1u);
    o.y = PIXV((fb >> 1) & 1u, (gb >> 1) & 1u);
    o.z = PIXV((fb >> 2) & 1u, (gb >> 2) & 1u);
    o.w = PIXV((fb >> 3) & 1u, (gb >> 3) & 1u);
    out4[idx4] = o;
  }
#undef PIXV
}

extern "C" void kernel_launch(void* const* d_in, const int* in_sizes, int n_in,
                              void* d_out, int out_size, void* d_ws, size_t ws_size,
                              hipStream_t stream) {
  const float* x = (const float*)d_in[0];
  int* out = (int*)d_out;

  u32 kf0, kf1, kb0, kb1;
#if PARTITIONABLE
  threefry2x32(0u, 42u, 0u, 0u, kf0, kf1);
  threefry2x32(0u, 42u, 0u, 1u, kb0, kb1);
#else
  u32 a0, a1, c0, c1;
  threefry2x32(0u, 42u, 0u, 2u, a0, a1);
  threefry2x32(0u, 42u, 1u, 3u, c0, c1);
  kf0 = a0; kf1 = c0; kb0 = a1; kb1 = c1;
#endif

  k_all<<<BB, 1024, 0, stream>>>(x, kf0, kf1, kb0, kb1, out);
}

// Round 5
// 84.695 us; speedup vs baseline: 6.8986x; 1.9015x over previous
//
#include <hip/hip_runtime.h>
#include <stdint.h>

// MBSeederSLFCAMS — exact JAX replication; single fused kernel, parallel selects.
#define PARTITIONABLE 1

typedef unsigned int u32;
typedef unsigned long long u64;
typedef unsigned char u8;

static constexpr int BB  = 256;
static constexpr int HH  = 256;
static constexpr int HWN = 65536;
static constexpr u32 K_BG = 6553;
static constexpr u32 TOPK = 100;
static constexpr u32 CAP  = 7936;
static constexpr u32 FG_CAP = 1024;

// ---- shared arena layout (bytes); live ranges as in round 4 (verified).
static constexpr int OFF_LIST   = 0;       // u64[7936]  ph1..bg-seed
static constexpr int OFF_CIMG   = 63488;   // u8[65536]  ph1-ph6
static constexpr int OFF_HROWS  = 63488;   // u64[1024]  ph7 (cImg dead)
static constexpr int OFF_FVL    = 63488;   // u64[1024]  ph10 (hrows dead)
static constexpr int OFF_FGLIST = 71680;   // u64[1024]  ph8-9
static constexpr int OFF_BVL    = 71680;   // u64[1024]  ph10 (fgList dead)
static constexpr int OFF_SEEDB  = 79872;   // u64[1024]  ph5-10
static constexpr int OFF_SEEDF  = 88064;   // u64[1024]  ph9-10
static constexpr int OFF_FHL    = 96256;   // u64[1024]  ph10
static constexpr int OFF_BHL    = 104448;  // u64[1024]  ph10
static constexpr int OFF_ROWS   = 129024;  // u64[1024]  ph6-8
static constexpr int OFF_HC     = 129024;  // u32[2048]  fallback only
static constexpr int OFF_HO     = 137216;  // u32[256]
static constexpr int OFF_HIST   = 138240;  // u32[256]
static constexpr int OFF_EQ     = 139264;  // u32[256]
static constexpr int OFF_W1S    = 140288;  // f32[256]
static constexpr int OFF_S1S    = 141312;  // f32[256]
static constexpr int OFF_AMAX   = 142336;  // u64
static constexpr int OFF_SCAL   = 142344;  // u32[20]
static constexpr int ARENA_BYTES = 142432; // < 160 KiB

__host__ __device__ inline u32 rotl32(u32 x, int d) { return (x << d) | (x >> (32 - d)); }

#define TF_ROUND(r) do { x0 += x1; x1 = rotl32(x1, r); x1 ^= x0; } while (0)

__host__ __device__ inline void threefry2x32(u32 k0, u32 k1, u32 x0, u32 x1, u32& o0, u32& o1) {
  u32 ks2 = k0 ^ k1 ^ 0x1BD11BDAu;
  x0 += k0; x1 += k1;
  TF_ROUND(13); TF_ROUND(15); TF_ROUND(26); TF_ROUND(6);
  x0 += k1;  x1 += ks2 + 1u;
  TF_ROUND(17); TF_ROUND(29); TF_ROUND(16); TF_ROUND(24);
  x0 += ks2; x1 += k0 + 2u;
  TF_ROUND(13); TF_ROUND(15); TF_ROUND(26); TF_ROUND(6);
  x0 += k0;  x1 += k1 + 3u;
  TF_ROUND(17); TF_ROUND(29); TF_ROUND(16); TF_ROUND(24);
  x0 += k1;  x1 += ks2 + 4u;
  TF_ROUND(13); TF_ROUND(15); TF_ROUND(26); TF_ROUND(6);
  x0 += ks2; x1 += k0 + 5u;
  o0 = x0; o1 = x1;
}

__device__ inline u32 score_bits(u32 k0, u32 k1, u32 i) {
#if PARTITIONABLE
  u32 a, b;
  threefry2x32(k0, k1, 0u, i, a, b);
  return a ^ b;
#else
  const u32 HALF = 1u << 23;
  u32 a, b;
  if (i < HALF) { threefry2x32(k0, k1, i, i + HALF, a, b); return a; }
  threefry2x32(k0, k1, i - HALF, i, a, b); return b;
#endif
}

// ---- parallel 256-bin rank select. All 1024 threads enter (barriers inside).
// hist[0..255] populated; finds bin with ex < K <= ex+h where ex = #keys
// strictly below (asc) / strictly above (desc). Writes sc[0]=bin, sc[1]=K-ex.
__device__ __forceinline__ void psel256(const u32* hist, u32 K, bool desc,
                                        u32* ws, u32* sc, u32 tid) {
  int lane = tid & 63;
  u32 h = 0, inc = 0;
  if (tid < 256) {
    h = hist[tid];
    inc = h;
#pragma unroll
    for (int d = 1; d < 64; d <<= 1) { u32 t2 = __shfl_up(inc, d, 64); if (lane >= d) inc += t2; }
    if (lane == 63) ws[tid >> 6] = inc;
  }
  __syncthreads();
  if (tid < 256) {
    int wv = tid >> 6;
    u32 off = 0;
    for (int k = 0; k < wv; k++) off += ws[k];
    inc += off;
    u32 total = ws[0] + ws[1] + ws[2] + ws[3];
    u32 ex = desc ? (total - inc) : (inc - h);
    if (ex < K && ex + h >= K) { sc[0] = tid; sc[1] = K - ex; }
  }
  __syncthreads();
}

// ---- multi-stage radix rank-select over key=(u32)(lst[e]>>16).
__device__ __forceinline__ u32 radix_sel(const u64* lst, u32 n, u32 K, int nst,
                                         const int* lo, const int* nb, bool desc,
                                         u32* hist, u32* ws, u32* sc, u32 tid,
                                         u32* tiesOut) {
  u32 pref = 0, Krem = K;
  for (int st = 0; st < nst; ++st) {
    if (tid < 256) hist[tid] = 0;
    __syncthreads();
    int bins = 1 << nb[st];
    int hiSh = lo[st] + nb[st];
    for (u32 e = tid; e < n; e += 1024) {
      u32 key = (u32)(lst[e] >> 16);
      if (st == 0 || (key >> hiSh) == pref)
        atomicAdd(&hist[(key >> lo[st]) & (u32)(bins - 1)], 1u);
    }
    __syncthreads();
    psel256(hist, Krem, desc, ws, sc, tid);
    pref = (pref << nb[st]) | sc[0];
    Krem = sc[1];
  }
  *tiesOut = Krem;
  return pref;
}

// ---- top-100-by-threefry seeding from an idx list (low16 of lst entries).
__device__ __forceinline__ void seed_from_idx(u64* lst, u32 n, u32 k0, u32 k1, u32 bimg,
                                              u64* seedRows, u32* hist, u32* eqA,
                                              u32* scal, bool dead, u32 tid) {
  seedRows[tid] = 0;
  for (u32 e = tid; e < n; e += 1024) {
    u32 idx = (u32)(lst[e] & 0xFFFFu);
    u32 m = score_bits(k0, k1, (bimg << 16) | idx) >> 9;   // 23-bit score
    lst[e] = ((u64)m << 16) | idx;
  }
  __syncthreads();
  u32 keff = n < TOPK ? n : TOPK;
  if (keff == 0) return;                                    // uniform
  const int lo3[3] = {15, 7, 0}; const int nb3[3] = {8, 8, 7};
  u32 tiesS;
  u32 S = radix_sel(lst, n, keff, 3, lo3, nb3, true, hist, scal + 10, scal + 2, tid, &tiesS);
  if (tid == 0) scal[1] = 0;
  __syncthreads();
  for (u32 e = tid; e < n; e += 1024) {
    u64 le = lst[e];
    if ((u32)(le >> 16) == S) { u32 p = atomicAdd(&scal[1], 1u); if (p < 256) eqA[p] = (u32)(le & 0xFFFFu); }
  }
  __syncthreads();
  if (tid == 0) {
    u32 ne = scal[1] < 256u ? scal[1] : 256u;
    for (u32 i2 = 1; i2 < ne; i2++) { u32 v = eqA[i2]; int j = (int)i2 - 1; while (j >= 0 && eqA[j] > v) { eqA[j + 1] = eqA[j]; j--; } eqA[j + 1] = v; }
    scal[2] = (tiesS > 0) ? eqA[tiesS - 1] : 0xFFFFFFFFu;
  }
  __syncthreads();
  u32 tmaxU = scal[2];
  if (!dead) {
    for (u32 e = tid; e < n; e += 1024) {
      u64 le = lst[e];
      u32 m = (u32)(le >> 16), idx = (u32)(le & 0xFFFFu);
      bool sel = (m > S) || (m == S && tmaxU != 0xFFFFFFFFu && idx <= tmaxU);
      if (sel) atomicOr(&seedRows[idx >> 6], 1ull << (idx & 63));
    }
  }
  __syncthreads();
}

__global__ __launch_bounds__(1024, 1) void k_all(const float* __restrict__ x,
                                                 u32 kf0, u32 kf1, u32 kb0, u32 kb1,
                                                 int* __restrict__ out) {
  __shared__ __align__(16) char arena[ARENA_BYTES];
  int b = blockIdx.x, tid = threadIdx.x;
  int lane = tid & 63;

  u64* lst    = (u64*)(arena + OFF_LIST);
  u8*  cImg   = (u8*)(arena + OFF_CIMG);
  u32* cImgW  = (u32*)(arena + OFF_CIMG);
  u32* hO     = (u32*)(arena + OFF_HO);
  u32* hist   = (u32*)(arena + OFF_HIST);
  u32* eqA    = (u32*)(arena + OFF_EQ);
  float* w1s  = (float*)(arena + OFF_W1S);
  float* s1s  = (float*)(arena + OFF_S1S);
  u64* amax   = (u64*)(arena + OFF_AMAX);
  u32* scal   = (u32*)(arena + OFF_SCAL);
  u64* rows   = (u64*)(arena + OFF_ROWS);
  u64* hrows  = (u64*)(arena + OFF_HROWS);
  u64* fgList = (u64*)(arena + OFF_FGLIST);
  u64* seedB  = (u64*)(arena + OFF_SEEDB);
  u64* seedF  = (u64*)(arena + OFF_SEEDF);

  const u32 BOUND_BITS = __float_as_uint(0.110f);
  const float4* img4 = (const float4*)(x + (size_t)b * HWN);

  // ---- phase 0: zero
  if (tid < 256) hO[tid] = 0;
  if (tid < 20) scal[tid] = 0;
  if (tid == 20) *amax = 0ull;
  __syncthreads();

  // ---- phase 1: single scan (float4): packed cImg, otsu hist, candidate push
#pragma unroll 4
  for (int it = 0; it < 16; ++it) {
    int f = (it << 10) + tid;                 // float4 chunk; pixels 4f..4f+3
    float4 v = img4[f];
    float a[4] = {v.x, v.y, v.z, v.w};
    u32 packed = 0;
#pragma unroll
    for (int c = 0; c < 4; c++) {
      float fl = floorf(a[c] * 255.0f);
      fl = fminf(fmaxf(fl, 0.0f), 255.0f);
      u32 cb = (u32)(int)fl;
      packed |= cb << (8 * c);
      atomicAdd(&hO[cb], 1u);
    }
    cImgW[f] = packed;
#pragma unroll
    for (int c = 0; c < 4; c++) {
      u32 kbv = __float_as_uint(a[c]);
      bool q = kbv < BOUND_BITS;
      u64 bal = __ballot(q);
      u32 nq = (u32)__popcll(bal);
      u32 base = 0;
      if (lane == 0 && nq) base = atomicAdd(&scal[0], nq);
      base = __shfl(base, 0);
      if (q) {
        u32 pos = base + (u32)__popcll(bal & ((1ull << lane) - 1ull));
        if (pos < CAP) lst[pos] = ((u64)kbv << 16) | (u32)(4 * f + c);
      }
    }
  }
  __syncthreads();
  u32 cntBelow = scal[0];

  // ---- phase 2: Otsu — parallel u32 cumsums (exact), variance, argmax
  {
    u32 h = 0, incW = 0, incS = 0;
    if (tid < 256) {
      h = hO[tid];
      incW = h; incS = h * tid;
#pragma unroll
      for (int d = 1; d < 64; d <<= 1) {
        u32 tw = __shfl_up(incW, d, 64);
        u32 ts = __shfl_up(incS, d, 64);
        if (lane >= d) { incW += tw; incS += ts; }
      }
      if (lane == 63) { scal[10 + (tid >> 6)] = incW; scal[14 + (tid >> 6)] = incS; }
      u64 nb = __ballot(h != 0);
      if (lane == 0) atomicAdd(&scal[4], (u32)__popcll(nb));
    }
    __syncthreads();
    if (tid < 256) {
      int wv = tid >> 6;
      u32 offW = 0, offS = 0;
      for (int k = 0; k < wv; k++) { offW += scal[10 + k]; offS += scal[14 + k]; }
      w1s[tid] = (float)(incW + offW);
      s1s[tid] = (float)(incS + offS);
    }
    __syncthreads();
    if (tid < 255) {
      int t = tid;
      float total = w1s[255], stot = s1s[255];
      float h1 = (float)hO[t + 1];
      float w1 = w1s[t];
      float w2 = total - w1s[t + 1] + h1;
      float s1 = s1s[t];
      float s2 = stot - s1s[t + 1] + h1 * (float)(t + 1);
      float m1 = s1 / fmaxf(w1, 1.0f);
      float m2 = s2 / fmaxf(w2, 1.0f);
      float d = m1 - m2;
      float v = (w1 * w2) * (d * d);
      u64 key = ((u64)__float_as_uint(v) << 32) | (u32)(255 - t);
      atomicMax((unsigned long long*)amax, (unsigned long long)key);
    }
    __syncthreads();
    if (tid == 0) {
      int bi = 255 - (int)(*amax & 0xFFFFFFFFu);
      float th = (float)bi;
      th = (th <= 0.0f) ? 1.0f : ((th >= 255.0f) ? 254.0f : th);
      scal[8] = (u32)(int)th;
      scal[5] = (scal[4] <= 1u) ? 1u : 0u;
    }
    __syncthreads();
  }
  u32 thiU = scal[8];
  bool dead = scal[5] != 0u;

  // ---- phase 3: cam rank-K_BG select
  bool fastOK = (cntBelow >= K_BG && cntBelow <= CAP);
  u32 T, ties, keyeq, listN;
  if (fastOK) {
    listN = cntBelow;
    const int lo4[4] = {24, 16, 8, 0}; const int nb4[4] = {8, 8, 8, 8};
    T = radix_sel(lst, listN, K_BG, 4, lo4, nb4, false, hist, scal + 10, scal + 2, tid, &ties);
    keyeq = T;
  } else {
    // exact fallback (rescans x); essentially never taken for this input
    u32* hC = (u32*)(arena + OFF_HC);
    for (int j = tid; j < 2048; j += 1024) hC[j] = 0;
    __syncthreads();
    const float* img = x + (size_t)b * HWN;
    for (int c = 0; c < 64; c++) {
      u32 kbv = __float_as_uint(img[(c << 10) + tid]);
      atomicAdd(&hC[kbv >> 21], 1u);
    }
    __syncthreads();
    if (tid == 0) {
      u32 cum = 0;
      for (int t = 0; t < 2048; t++) { u32 h = hC[t]; if (cum + h >= K_BG) { scal[2] = (u32)t; scal[3] = K_BG - cum; break; } cum += h; }
    }
    __syncthreads();
    u32 b1 = scal[2], K2v = scal[3];
    if (tid == 0) scal[0] = 0;
    __syncthreads();
    for (int c = 0; c < 64; c++) {
      int i = (c << 10) + tid;
      u32 kbv = __float_as_uint(img[i]);
      if ((kbv >> 21) == b1) { u32 p = atomicAdd(&scal[0], 1u); if (p < CAP) lst[p] = ((u64)(kbv & 0x1FFFFFu) << 16) | (u32)i; }
    }
    __syncthreads();
    listN = scal[0] < CAP ? scal[0] : CAP;
    const int lo3[3] = {16, 8, 0}; const int nb3[3] = {5, 8, 8};
    u32 low21 = radix_sel(lst, listN, K2v, 3, lo3, nb3, false, hist, scal + 10, scal + 2, tid, &ties);
    T = (b1 << 21) | low21;
    keyeq = low21;
  }
  // tie collection + index sort
  if (tid == 0) scal[1] = 0;
  __syncthreads();
  for (u32 e = tid; e < listN; e += 1024) {
    u64 le = lst[e];
    if ((u32)(le >> 16) == keyeq) { u32 p = atomicAdd(&scal[1], 1u); if (p < 256) eqA[p] = (u32)(le & 0xFFFFu); }
  }
  __syncthreads();
  if (tid == 0) {
    u32 ne = scal[1] < 256u ? scal[1] : 256u;
    for (u32 i2 = 1; i2 < ne; i2++) { u32 v = eqA[i2]; int j = (int)i2 - 1; while (j >= 0 && eqA[j] > v) { eqA[j + 1] = eqA[j]; j--; } eqA[j + 1] = v; }
    scal[2] = (ties > 0) ? eqA[ties - 1] : 0xFFFFFFFFu;
  }
  __syncthreads();
  int tmax = (scal[2] == 0xFFFFFFFFu) ? -1 : (int)scal[2];
  __syncthreads();

  // ---- phase 4: compact candidates (<T, or ==T with idx<=tmax) into lst head
  {
    u64 mine[8]; int nm = 0;
    if (fastOK) {
      for (u32 e = tid; e < listN; e += 1024) mine[nm++] = lst[e];
    } else {
      const float* img = x + (size_t)b * HWN;
      for (int c = 0; c < 64; c++) {
        int i = (c << 10) + tid;
        u32 kbv = __float_as_uint(img[i]);
        bool sel = (kbv < T) || (kbv == T && i <= tmax);
        if (sel && nm < 8) mine[nm++] = ((u64)kbv << 16) | (u32)i;
      }
    }
    __syncthreads();
    if (tid == 0) scal[6] = 0;
    __syncthreads();
    for (int k = 0; k < 8; k++) {
      bool have = k < nm;
      u64 le = have ? mine[k] : 0;
      u32 key = (u32)(le >> 16);
      int idx = (int)(le & 0xFFFFu);
      bool sel = have && (!fastOK || (key < T) || (key == T && idx <= tmax));
      u64 bal = __ballot(sel);
      u32 nq = (u32)__popcll(bal);
      u32 base = 0;
      if (lane == 0 && nq) base = atomicAdd(&scal[6], nq);
      base = __shfl(base, 0);
      if (sel) {
        u32 pos = base + (u32)__popcll(bal & ((1ull << lane) - 1ull));
        if (pos < CAP) lst[pos] = le;
      }
    }
    __syncthreads();
  }
  u32 candN = scal[6] < CAP ? scal[6] : CAP;

  // ---- phase 6: ROI bits, one 64-pixel word per thread (swizzled reads)
  {
    u64 bits = 0;
#pragma unroll
    for (int k2 = 0; k2 < 16; k2++) {
      int k = (k2 + (tid >> 1)) & 15;
      u32 v4 = cImgW[tid * 16 + k];
      u32 m = 0;
      if ((v4 & 0xFFu) > thiU)         m |= 1u;
      if (((v4 >> 8) & 0xFFu) > thiU)  m |= 2u;
      if (((v4 >> 16) & 0xFFu) > thiU) m |= 4u;
      if ((v4 >> 24) > thiU)           m |= 8u;
      bits |= (u64)m << (4 * k);
    }
    rows[tid] = bits;
  }
  __syncthreads();

  // ---- phase 7: 11x11 erosion (OOB = 1); eroded result back into rows
  if (tid < 256) {
    int r = tid;
    u64 wv[4], h0[4];
    for (int j = 0; j < 4; j++) { wv[j] = rows[r * 4 + j]; h0[j] = wv[j]; }
    for (int s = 1; s <= 5; s++) {
      for (int j = 0; j < 4; j++) {
        u64 hi = (j < 3) ? wv[j + 1] : ~0ull;
        u64 lo = (j > 0) ? wv[j - 1] : ~0ull;
        u64 A  = (wv[j] >> s) | (hi << (64 - s));
        u64 Bv = (wv[j] << s) | (lo >> (64 - s));
        h0[j] &= A & Bv;
      }
    }
    for (int j = 0; j < 4; j++) hrows[r * 4 + j] = h0[j];
  }
  __syncthreads();
  if (tid < 256) {
    int r = tid;
    u64 res[4] = {hrows[r * 4], hrows[r * 4 + 1], hrows[r * 4 + 2], hrows[r * 4 + 3]};
    for (int dr = -5; dr <= 5; dr++) {
      if (dr == 0) continue;
      int rr = r + dr;
      if (rr < 0 || rr >= HH) continue;
      for (int j = 0; j < 4; j++) res[j] &= hrows[rr * 4 + j];
    }
    for (int j = 0; j < 4; j++) rows[r * 4 + j] = res[j];
  }
  __syncthreads();

  // ---- phase 8: extract fg (roi) indices (almost surely none)
  {
    u64 wv = rows[tid];
    while (wv) {
      int bit = __ffsll((long long)wv) - 1; wv &= wv - 1;
      u32 p = atomicAdd(&scal[7], 1u);
      if (p < FG_CAP) fgList[p] = (u64)(u32)(tid * 64 + bit);
    }
  }
  __syncthreads();
  u32 fgN = scal[7] < FG_CAP ? scal[7] : FG_CAP;

  // ---- phase 5: bg seeds; phase 9: fg seeds
  seed_from_idx(lst, candN, kb0, kb1, (u32)b, seedB, hist, eqA, scal, dead, tid);
  seed_from_idx(fgList, fgN, kf0, kf1, (u32)b, seedF, hist, eqA, scal, dead, tid);

  // ---- phase 10: 3x3 dilation + conflict resolve + int4 emit
  u64* fvL = (u64*)(arena + OFF_FVL);
  u64* bvL = (u64*)(arena + OFF_BVL);
  u64* fhL = (u64*)(arena + OFF_FHL);
  u64* bhL = (u64*)(arena + OFF_BHL);
  {
    int r = tid >> 2;
    u64 vf = seedF[tid], vb = seedB[tid];
    if (r > 0)   { vf |= seedF[tid - 4]; vb |= seedB[tid - 4]; }
    if (r < 255) { vf |= seedF[tid + 4]; vb |= seedB[tid + 4]; }
    fvL[tid] = vf; bvL[tid] = vb;
  }
  __syncthreads();
  {
    int j = tid & 3;
    u64 v = fvL[tid];
    u64 L = (j > 0) ? fvL[tid - 1] : 0ull;
    u64 R = (j < 3) ? fvL[tid + 1] : 0ull;
    fhL[tid] = v | (v << 1) | (L >> 63) | (v >> 1) | (R << 63);
    v = bvL[tid];
    L = (j > 0) ? bvL[tid - 1] : 0ull;
    R = (j < 3) ? bvL[tid + 1] : 0ull;
    bhL[tid] = v | (v << 1) | (L >> 63) | (v >> 1) | (R << 63);
  }
  __syncthreads();
  int4* out4 = (int4*)(out + (size_t)b * HWN);
#define PIXV(f, g) (((f) && (g)) ? -255 : ((g) ? 0 : ((f) ? 1 : -255)))
  for (int it = 0; it < 16; it++) {
    int idx4 = it * 1024 + tid;
    int word = idx4 >> 4;
    int sh = (idx4 & 15) * 4;
    u32 fb = (u32)(fhL[word] >> sh) & 0xFu;
    u32 gb = (u32)(bhL[word] >> sh) & 0xFu;
    int4 o;
    o.x = PIXV(fb & 1u, gb & 1u);
    o.y = PIXV((fb >> 1) & 1u, (gb >> 1) & 1u);
    o.z = PIXV((fb >> 2) & 1u, (gb >> 2) & 1u);
    o.w = PIXV((fb >> 3) & 1u, (gb >> 3) & 1u);
    out4[idx4] = o;
  }
#undef PIXV
}

extern "C" void kernel_launch(void* const* d_in, const int* in_sizes, int n_in,
                              void* d_out, int out_size, void* d_ws, size_t ws_size,
                              hipStream_t stream) {
  const float* x = (const float*)d_in[0];
  int* out = (int*)d_out;

  u32 kf0, kf1, kb0, kb1;
#if PARTITIONABLE
  threefry2x32(0u, 42u, 0u, 0u, kf0, kf1);
  threefry2x32(0u, 42u, 0u, 1u, kb0, kb1);
#else
  u32 a0, a1, c0, c1;
  threefry2x32(0u, 42u, 0u, 2u, a0, a1);
  threefry2x32(0u, 42u, 1u, 3u, c0, c1);
  kf0 = a0; kf1 = c0; kb0 = a1; kb1 = c1;
#endif

  k_all<<<BB, 1024, 0, stream>>>(x, kf0, kf1, kb0, kb1, out);
}

// Round 6
// 61.950 us; speedup vs baseline: 9.4315x; 1.3672x over previous
//
#include <hip/hip_runtime.h>
#include <stdint.h>

// MBSeederSLFCAMS — exact JAX replication; single fused kernel, lean phases.
#define PARTITIONABLE 1

typedef unsigned int u32;
typedef unsigned long long u64;
typedef unsigned char u8;

static constexpr int BB  = 256;
static constexpr int HH  = 256;
static constexpr int HWN = 65536;
static constexpr u32 K_BG = 6553;
static constexpr u32 TOPK = 100;
static constexpr u32 CAP  = 7936;
static constexpr u32 FG_CAP = 1024;

// ---- arena (bytes); aliasing validated phase-by-phase (sequential barriers)
static constexpr int OFF_LST    = 0;       // u64[7936]   ph1..bg-seed
static constexpr int OFF_FVL    = 0;       // u64[1024]   ph10 (lst dead)
static constexpr int OFF_BVL    = 8192;    // u64[1024]   ph10
static constexpr int OFF_FHL    = 16384;   // u64[1024]   ph10
static constexpr int OFF_BHL    = 24576;   // u64[1024]   ph10
static constexpr int OFF_CIMG   = 63488;   // u32[16384]  ph1-ph6
static constexpr int OFF_SEEDB  = 63488;   // u64[1024]   ph9a+ (cImg dead)
static constexpr int OFF_SEEDF  = 71680;   // u64[1024]   ph9b+
static constexpr int OFF_HIST   = 129024;  // u32[4096]   ph3, ph9 (16 KB)
static constexpr int OFF_ROWS   = 129024;  // u64[1024]   ph6-8 (aliases hist)
static constexpr int OFF_HROWS  = 137216;  // u64[1024]   ph7
static constexpr int OFF_FGL    = 145408;  // u64[1024]   ph8-9b
static constexpr int OFF_HO     = 153600;  // u32[256]
static constexpr int OFF_EQ     = 154624;  // u32[256]
static constexpr int OFF_W1S    = 155648;  // f32[256]
static constexpr int OFF_S1S    = 156672;  // f32[256]
static constexpr int OFF_AMAX   = 157696;  // u64
static constexpr int OFF_SCAL   = 157704;  // u32[28]
static constexpr int ARENA_BYTES = 157824; // < 160 KiB

__host__ __device__ inline u32 rotl32(u32 x, int d) { return (x << d) | (x >> (32 - d)); }

#define TF_ROUND(r) do { x0 += x1; x1 = rotl32(x1, r); x1 ^= x0; } while (0)

__host__ __device__ inline void threefry2x32(u32 k0, u32 k1, u32 x0, u32 x1, u32& o0, u32& o1) {
  u32 ks2 = k0 ^ k1 ^ 0x1BD11BDAu;
  x0 += k0; x1 += k1;
  TF_ROUND(13); TF_ROUND(15); TF_ROUND(26); TF_ROUND(6);
  x0 += k1;  x1 += ks2 + 1u;
  TF_ROUND(17); TF_ROUND(29); TF_ROUND(16); TF_ROUND(24);
  x0 += ks2; x1 += k0 + 2u;
  TF_ROUND(13); TF_ROUND(15); TF_ROUND(26); TF_ROUND(6);
  x0 += k0;  x1 += k1 + 3u;
  TF_ROUND(17); TF_ROUND(29); TF_ROUND(16); TF_ROUND(24);
  x0 += k1;  x1 += ks2 + 4u;
  TF_ROUND(13); TF_ROUND(15); TF_ROUND(26); TF_ROUND(6);
  x0 += ks2; x1 += k0 + 5u;
  o0 = x0; o1 = x1;
}

__device__ inline u32 score_bits(u32 k0, u32 k1, u32 i) {
#if PARTITIONABLE
  u32 a, b;
  threefry2x32(k0, k1, 0u, i, a, b);
  return a ^ b;
#else
  const u32 HALF = 1u << 23;
  u32 a, b;
  if (i < HALF) { threefry2x32(k0, k1, i, i + HALF, a, b); return a; }
  threefry2x32(k0, k1, i - HALF, i, a, b); return b;
#endif
}

// ---- parallel rank select over BPT*1024 bins (BPT bins per thread).
// Finds unique bin with ex < K <= ex+h (ex = #keys strictly below for asc,
// strictly above for desc). sc[0]=bin, sc[1]=K-ex. Zeroes hist[0..zeroN) for
// the next stage inside the same barrier window.
template<int BPT>
__device__ __forceinline__ void pselT(u32* hist, u32 K, bool desc, u32* ws, u32* sc,
                                      int zeroN, u32 tid) {
  int lane = (int)tid & 63, wid = (int)tid >> 6;
  u32 h[BPT]; u32 loc = 0;
#pragma unroll
  for (int j = 0; j < BPT; j++) { h[j] = hist[BPT * tid + j]; loc += h[j]; }
  u32 inc = loc;
#pragma unroll
  for (int d = 1; d < 64; d <<= 1) { u32 t2 = __shfl_up(inc, d, 64); if (lane >= d) inc += t2; }
  if (lane == 63) ws[wid] = inc;
  __syncthreads();
  u32 off = 0, total = 0;
  for (int k = 0; k < 16; k++) { u32 wv = ws[k]; total += wv; if (k < wid) off += wv; }
  inc += off;
  if (!desc) {
    u32 ex = inc - loc;
#pragma unroll
    for (int j = 0; j < BPT; j++) { if (ex < K && K <= ex + h[j]) { sc[0] = BPT * tid + j; sc[1] = K - ex; } ex += h[j]; }
  } else {
    u32 ex = total - inc;
#pragma unroll
    for (int j = BPT - 1; j >= 0; j--) { if (ex < K && K <= ex + h[j]) { sc[0] = BPT * tid + j; sc[1] = K - ex; } ex += h[j]; }
  }
  for (int k = (int)tid; k < zeroN; k += 1024) hist[k] = 0;
  __syncthreads();
}

// ---- 256-bin variant (waves 0-3 compute, all threads barrier)
__device__ __forceinline__ void psel256(u32* hist, u32 K, bool desc, u32* ws, u32* sc,
                                        int zeroN, u32 tid) {
  int lane = (int)tid & 63;
  u32 h = 0, inc = 0;
  if (tid < 256) {
    h = hist[tid]; inc = h;
#pragma unroll
    for (int d = 1; d < 64; d <<= 1) { u32 t2 = __shfl_up(inc, d, 64); if (lane >= d) inc += t2; }
    if (lane == 63) ws[tid >> 6] = inc;
  }
  __syncthreads();
  if (tid < 256) {
    int wid = (int)tid >> 6;
    u32 off = 0; for (int k = 0; k < wid; k++) off += ws[k];
    inc += off;
    u32 total = ws[0] + ws[1] + ws[2] + ws[3];
    u32 ex = desc ? (total - inc) : (inc - h);
    if (ex < K && ex + h >= K) { sc[0] = tid; sc[1] = K - ex; }
  }
  for (int k = (int)tid; k < zeroN; k += 1024) hist[k] = 0;
  __syncthreads();
}

// ---- top-100-by-threefry seeding from idx list (low16 of lst entries).
__device__ __forceinline__ void seed_from_idx(u64* lst, u32 n, u32 k0, u32 k1, u32 bimg,
                                              u64* seedRows, u32* hist, u32* eqA,
                                              u32* scal, u32* ws, bool dead, u32 tid) {
  seedRows[tid] = 0;
  hist[tid] = 0; hist[tid + 1024] = 0;
  for (u32 e = tid; e < n; e += 1024) {
    u32 idx = (u32)(lst[e] & 0xFFFFu);
    u32 m = score_bits(k0, k1, (bimg << 16) | idx) >> 9;   // 23-bit score
    lst[e] = ((u64)m << 16) | idx;
  }
  __syncthreads();
  u32 keff = n < TOPK ? n : TOPK;
  if (keff == 0) return;                                    // block-uniform
  u32* sc = scal + 2;
  for (u32 e = tid; e < n; e += 1024) atomicAdd(&hist[(u32)(lst[e] >> 16) >> 12], 1u);
  __syncthreads();
  pselT<2>(hist, keff, true, ws, sc, 4096, tid);            // bits 22..12
  u32 s0 = sc[0], Kr = sc[1];
  for (u32 e = tid; e < n; e += 1024) { u32 m = (u32)(lst[e] >> 16); if ((m >> 12) == s0) atomicAdd(&hist[m & 0xFFFu], 1u); }
  __syncthreads();
  pselT<4>(hist, Kr, true, ws, sc, 0, tid);                 // bits 11..0
  u32 S = (s0 << 12) | sc[0];
  u32 tiesS = sc[1];
  if (tid == 0) scal[1] = 0;
  __syncthreads();
  for (u32 e = tid; e < n; e += 1024) {
    u64 le = lst[e];
    if ((u32)(le >> 16) == S) { u32 p = atomicAdd(&scal[1], 1u); if (p < 256) eqA[p] = (u32)(le & 0xFFFFu); }
  }
  __syncthreads();
  if (tid == 0) {
    u32 ne = scal[1] < 256u ? scal[1] : 256u;
    for (u32 i2 = 1; i2 < ne; i2++) { u32 v = eqA[i2]; int j = (int)i2 - 1; while (j >= 0 && eqA[j] > v) { eqA[j + 1] = eqA[j]; j--; } eqA[j + 1] = v; }
    scal[9] = (tiesS > 0) ? eqA[tiesS - 1] : 0xFFFFFFFFu;
  }
  __syncthreads();
  u32 tmaxU = scal[9];
  if (!dead) {
    for (u32 e = tid; e < n; e += 1024) {
      u64 le = lst[e];
      u32 m = (u32)(le >> 16), idx = (u32)(le & 0xFFFFu);
      bool sel = (m > S) || (m == S && tmaxU != 0xFFFFFFFFu && idx <= tmaxU);
      if (sel) atomicOr(&seedRows[idx >> 6], 1ull << (idx & 63));
    }
  }
  __syncthreads();
}

__global__ __launch_bounds__(1024) void k_all(const float* __restrict__ x,
                                              u32 kf0, u32 kf1, u32 kb0, u32 kb1,
                                              int* __restrict__ out) {
  __shared__ __align__(16) char arena[ARENA_BYTES];
  const int b = blockIdx.x, tid = threadIdx.x;
  const int lane = tid & 63;

  u64* lst    = (u64*)(arena + OFF_LST);
  u32* cImgW  = (u32*)(arena + OFF_CIMG);
  u32* hO     = (u32*)(arena + OFF_HO);
  u32* hist   = (u32*)(arena + OFF_HIST);
  u32* eqA    = (u32*)(arena + OFF_EQ);
  float* w1s  = (float*)(arena + OFF_W1S);
  float* s1s  = (float*)(arena + OFF_S1S);
  u64* amax   = (u64*)(arena + OFF_AMAX);
  u32* scal   = (u32*)(arena + OFF_SCAL);
  u32* ws     = scal + 10;                  // 16 slots
  u32* sc     = scal + 2;
  u64* rows   = (u64*)(arena + OFF_ROWS);
  u64* hrows  = (u64*)(arena + OFF_HROWS);
  u64* fgList = (u64*)(arena + OFF_FGL);
  u64* seedB  = (u64*)(arena + OFF_SEEDB);
  u64* seedF  = (u64*)(arena + OFF_SEEDF);

  const u32 BND = __float_as_uint(0.110f);
  const float4* img4 = (const float4*)(x + (size_t)b * HWN);
  const float* img = x + (size_t)b * HWN;

  // ---- phase 0: zero
  if (tid < 256) hO[tid] = 0;
  if (tid < 28) scal[tid] = 0;
  if (tid == 28) *amax = 0ull;
  __syncthreads();

  // ---- phase 1: single scan. cb = (int)(v*255) ≡ clip(floor(v*255)) for v in [0,1).
  //      packed cImg, otsu hist, candidate push (1 same-address atomic per group).
#pragma unroll
  for (int half = 0; half < 2; ++half) {
    float4 v[8];
#pragma unroll
    for (int k = 0; k < 8; k++) v[k] = img4[((half * 8 + k) << 10) + tid];
#pragma unroll
    for (int k = 0; k < 8; k++) {
      u32 c0 = (u32)(int)(v[k].x * 255.0f);
      u32 c1 = (u32)(int)(v[k].y * 255.0f);
      u32 c2 = (u32)(int)(v[k].z * 255.0f);
      u32 c3 = (u32)(int)(v[k].w * 255.0f);
      atomicAdd(&hO[c0], 1u); atomicAdd(&hO[c1], 1u);
      atomicAdd(&hO[c2], 1u); atomicAdd(&hO[c3], 1u);
      cImgW[((half * 8 + k) << 10) + tid] = c0 | (c1 << 8) | (c2 << 16) | (c3 << 24);
    }
#pragma unroll
    for (int k = 0; k < 8; k++) {
      u32 q0 = __float_as_uint(v[k].x), q1 = __float_as_uint(v[k].y);
      u32 q2 = __float_as_uint(v[k].z), q3 = __float_as_uint(v[k].w);
      bool s0 = q0 < BND, s1 = q1 < BND, s2 = q2 < BND, s3 = q3 < BND;
      u64 b0 = __ballot(s0), b1 = __ballot(s1), b2 = __ballot(s2), b3 = __ballot(s3);
      u32 tot = (u32)(__popcll(b0) + __popcll(b1) + __popcll(b2) + __popcll(b3));
      u32 base = 0;
      if (lane == 0 && tot) base = atomicAdd(&scal[0], tot);
      base = __shfl(base, 0, 64);
      u64 below = (1ull << lane) - 1ull;
      u32 pix = (u32)((((half * 8 + k) << 10) + tid) * 4);
      if (s0) { u32 p = base + (u32)__popcll(b0 & below); if (p < CAP) lst[p] = ((u64)q0 << 16) | pix; }
      base += (u32)__popcll(b0);
      if (s1) { u32 p = base + (u32)__popcll(b1 & below); if (p < CAP) lst[p] = ((u64)q1 << 16) | (pix + 1); }
      base += (u32)__popcll(b1);
      if (s2) { u32 p = base + (u32)__popcll(b2 & below); if (p < CAP) lst[p] = ((u64)q2 << 16) | (pix + 2); }
      base += (u32)__popcll(b2);
      if (s3) { u32 p = base + (u32)__popcll(b3 & below); if (p < CAP) lst[p] = ((u64)q3 << 16) | (pix + 3); }
    }
  }
  __syncthreads();
  u32 cntBelow = scal[0];

  // ---- phase 2: Otsu — parallel u32 cumsums (exact), variance, first-max argmax
  {
    u32 h = 0, incW = 0, incS = 0;
    if (tid < 256) {
      h = hO[tid];
      incW = h; incS = h * tid;
#pragma unroll
      for (int d = 1; d < 64; d <<= 1) {
        u32 tw = __shfl_up(incW, d, 64);
        u32 ts = __shfl_up(incS, d, 64);
        if (lane >= d) { incW += tw; incS += ts; }
      }
      if (lane == 63) { scal[10 + (tid >> 6)] = incW; scal[14 + (tid >> 6)] = incS; }
      u64 nb = __ballot(h != 0);
      if (lane == 0) atomicAdd(&scal[4], (u32)__popcll(nb));
    }
    __syncthreads();
    if (tid < 256) {
      int wv = tid >> 6;
      u32 offW = 0, offS = 0;
      for (int k = 0; k < wv; k++) { offW += scal[10 + k]; offS += scal[14 + k]; }
      w1s[tid] = (float)(incW + offW);
      s1s[tid] = (float)(incS + offS);
    }
    __syncthreads();
    if (tid < 255) {
      int t = tid;
      float total = w1s[255], stot = s1s[255];
      float h1 = (float)hO[t + 1];
      float w1 = w1s[t];
      float w2 = total - w1s[t + 1] + h1;
      float s1 = s1s[t];
      float s2 = stot - s1s[t + 1] + h1 * (float)(t + 1);
      float m1 = s1 / fmaxf(w1, 1.0f);
      float m2 = s2 / fmaxf(w2, 1.0f);
      float d = m1 - m2;
      float v = (w1 * w2) * (d * d);
      u64 key = ((u64)__float_as_uint(v) << 32) | (u32)(255 - t);
      atomicMax((unsigned long long*)amax, (unsigned long long)key);
    }
    __syncthreads();
    if (tid == 0) {
      int bi = 255 - (int)(*amax & 0xFFFFFFFFu);
      float th = (float)bi;
      th = (th <= 0.0f) ? 1.0f : ((th >= 255.0f) ? 254.0f : th);
      scal[8] = (u32)(int)th;
      scal[5] = (scal[4] <= 1u) ? 1u : 0u;
    }
    __syncthreads();
  }
  u32 thiU = scal[8];
  bool dead = scal[5] != 0u;

  // ---- phase 3: cam rank-K_BG select (keys 30-bit; stages 11+11+8)
  bool fastOK = (cntBelow >= K_BG && cntBelow <= CAP);
  hist[tid] = 0; hist[tid + 1024] = 0;
  __syncthreads();
  u32 listN = 0;
  if (fastOK) {
    listN = cntBelow;
    for (u32 e = tid; e < listN; e += 1024) atomicAdd(&hist[(u32)(lst[e] >> 16) >> 19], 1u);
  } else {
    for (int c = 0; c < 64; c++) atomicAdd(&hist[__float_as_uint(img[(c << 10) + tid]) >> 19], 1u);
  }
  __syncthreads();
  pselT<2>(hist, K_BG, false, ws, sc, 2048, tid);
  u32 cb0 = sc[0], K1 = sc[1];
  if (!fastOK) {
    // collect bin-cb0 pixels into lst (fallback; essentially never taken)
    if (tid == 0) scal[0] = 0;
    __syncthreads();
    for (int c = 0; c < 64; c++) {
      int i = (c << 10) + tid;
      u32 q = __float_as_uint(img[i]);
      bool sel = (q >> 19) == cb0;
      u64 bal = __ballot(sel);
      u32 tot = (u32)__popcll(bal);
      u32 base2 = 0;
      if (lane == 0 && tot) base2 = atomicAdd(&scal[0], tot);
      base2 = __shfl(base2, 0, 64);
      if (sel) { u32 p = base2 + (u32)__popcll(bal & ((1ull << lane) - 1ull)); if (p < CAP) lst[p] = ((u64)q << 16) | (u32)i; }
    }
    __syncthreads();
    listN = scal[0] < CAP ? scal[0] : CAP;
  }
  for (u32 e = tid; e < listN; e += 1024) { u32 key = (u32)(lst[e] >> 16); if ((key >> 19) == cb0) atomicAdd(&hist[(key >> 8) & 0x7FFu], 1u); }
  __syncthreads();
  pselT<2>(hist, K1, false, ws, sc, 256, tid);
  u32 cb1 = sc[0], K2 = sc[1];
  u32 hi22 = (cb0 << 11) | cb1;
  for (u32 e = tid; e < listN; e += 1024) { u32 key = (u32)(lst[e] >> 16); if ((key >> 8) == hi22) atomicAdd(&hist[key & 0xFFu], 1u); }
  __syncthreads();
  psel256(hist, K2, false, ws, sc, 0, tid);
  u32 T = (hi22 << 8) | sc[0];
  u32 ties = sc[1];

  // tie collection + index sort
  if (tid == 0) scal[1] = 0;
  __syncthreads();
  for (u32 e = tid; e < listN; e += 1024) {
    u64 le = lst[e];
    if ((u32)(le >> 16) == T) { u32 p = atomicAdd(&scal[1], 1u); if (p < 256) eqA[p] = (u32)(le & 0xFFFFu); }
  }
  __syncthreads();
  if (tid == 0) {
    u32 ne = scal[1] < 256u ? scal[1] : 256u;
    for (u32 i2 = 1; i2 < ne; i2++) { u32 v = eqA[i2]; int j = (int)i2 - 1; while (j >= 0 && eqA[j] > v) { eqA[j + 1] = eqA[j]; j--; } eqA[j + 1] = v; }
    scal[9] = (ties > 0) ? eqA[ties - 1] : 0xFFFFFFFFu;
  }
  __syncthreads();
  int tmax = (scal[9] == 0xFFFFFFFFu) ? -1 : (int)scal[9];
  __syncthreads();

  // ---- phase 4: compact candidates into lst head (order-free; block scan)
  if (fastOK) {
    u64 mine[8]; int nm = 0;
    for (u32 e = tid; e < listN; e += 1024) {
      u64 le = lst[e];
      u32 key = (u32)(le >> 16); int idx = (int)(le & 0xFFFFu);
      if (key < T || (key == T && idx <= tmax)) mine[nm++] = le;
    }
    __syncthreads();
    u32 nmU = (u32)nm, incl = nmU;
#pragma unroll
    for (int d = 1; d < 64; d <<= 1) { u32 t2 = __shfl_up(incl, d, 64); if (lane >= d) incl += t2; }
    u32 wtot = __shfl(incl, 63, 64);
    u32 base = 0;
    if (lane == 0) base = atomicAdd(&scal[6], wtot);
    base = __shfl(base, 0, 64);
    u32 my = base + incl - nmU;
    for (int k = 0; k < nm; k++) if (my + (u32)k < CAP) lst[my + k] = mine[k];
    __syncthreads();
  } else {
    __syncthreads();
    for (int c = 0; c < 64; c++) {
      int i = (c << 10) + tid;
      u32 q = __float_as_uint(img[i]);
      bool sel = (q < T) || (q == T && i <= tmax);
      if (sel) { u32 p = atomicAdd(&scal[6], 1u); if (p < CAP) lst[p] = ((u64)q << 16) | (u32)i; }
    }
    __syncthreads();
  }
  u32 candN = scal[6] < CAP ? scal[6] : CAP;

  // ---- phase 6: ROI bits from packed cImg (one 64-px word per thread)
  {
    u64 bits = 0;
#pragma unroll
    for (int k2 = 0; k2 < 16; k2++) {
      int k = (k2 + (tid >> 1)) & 15;
      u32 v4 = cImgW[tid * 16 + k];
      u32 m = 0;
      if ((v4 & 0xFFu) > thiU)         m |= 1u;
      if (((v4 >> 8) & 0xFFu) > thiU)  m |= 2u;
      if (((v4 >> 16) & 0xFFu) > thiU) m |= 4u;
      if ((v4 >> 24) > thiU)           m |= 8u;
      bits |= (u64)m << (4 * k);
    }
    rows[tid] = bits;
  }
  __syncthreads();

  // ---- phase 7: 11x11 erosion (OOB = 1)
  if (tid < 256) {
    int r = tid;
    u64 wv[4], h0[4];
    for (int j = 0; j < 4; j++) { wv[j] = rows[r * 4 + j]; h0[j] = wv[j]; }
    for (int s = 1; s <= 5; s++) {
      for (int j = 0; j < 4; j++) {
        u64 hi = (j < 3) ? wv[j + 1] : ~0ull;
        u64 lo = (j > 0) ? wv[j - 1] : ~0ull;
        u64 A  = (wv[j] >> s) | (hi << (64 - s));
        u64 Bv = (wv[j] << s) | (lo >> (64 - s));
        h0[j] &= A & Bv;
      }
    }
    for (int j = 0; j < 4; j++) hrows[r * 4 + j] = h0[j];
  }
  __syncthreads();
  if (tid < 256) {
    int r = tid;
    u64 res[4] = {hrows[r * 4], hrows[r * 4 + 1], hrows[r * 4 + 2], hrows[r * 4 + 3]};
    for (int dr = -5; dr <= 5; dr++) {
      if (dr == 0) continue;
      int rr = r + dr;
      if (rr < 0 || rr >= HH) continue;
      for (int j = 0; j < 4; j++) res[j] &= hrows[rr * 4 + j];
    }
    for (int j = 0; j < 4; j++) rows[r * 4 + j] = res[j];
  }
  __syncthreads();

  // ---- phase 8: extract fg (roi) indices (almost surely none)
  {
    u64 wv = rows[tid];
    while (wv) {
      int bit = __ffsll((long long)wv) - 1; wv &= wv - 1;
      u32 p = atomicAdd(&scal[7], 1u);
      if (p < FG_CAP) fgList[p] = (u64)(u32)(tid * 64 + bit);
    }
  }
  __syncthreads();
  u32 fgN = scal[7] < FG_CAP ? scal[7] : FG_CAP;

  // ---- phase 9: bg seeds (candidates) then fg seeds (roi)
  seed_from_idx(lst, candN, kb0, kb1, (u32)b, seedB, hist, eqA, scal, ws, dead, tid);
  seed_from_idx(fgList, fgN, kf0, kf1, (u32)b, seedF, hist, eqA, scal, ws, dead, tid);

  // ---- phase 10: 3x3 dilation + conflict resolve + int4 emit
  u64* fvL = (u64*)(arena + OFF_FVL);
  u64* bvL = (u64*)(arena + OFF_BVL);
  u64* fhL = (u64*)(arena + OFF_FHL);
  u64* bhL = (u64*)(arena + OFF_BHL);
  {
    int r = tid >> 2;
    u64 vf = seedF[tid], vb = seedB[tid];
    if (r > 0)   { vf |= seedF[tid - 4]; vb |= seedB[tid - 4]; }
    if (r < 255) { vf |= seedF[tid + 4]; vb |= seedB[tid + 4]; }
    fvL[tid] = vf; bvL[tid] = vb;
  }
  __syncthreads();
  {
    int j = tid & 3;
    u64 v = fvL[tid];
    u64 L = (j > 0) ? fvL[tid - 1] : 0ull;
    u64 R = (j < 3) ? fvL[tid + 1] : 0ull;
    fhL[tid] = v | (v << 1) | (L >> 63) | (v >> 1) | (R << 63);
    v = bvL[tid];
    L = (j > 0) ? bvL[tid - 1] : 0ull;
    R = (j < 3) ? bvL[tid + 1] : 0ull;
    bhL[tid] = v | (v << 1) | (L >> 63) | (v >> 1) | (R << 63);
  }
  __syncthreads();
  int4* out4 = (int4*)(out + (size_t)b * HWN);
  for (int it = 0; it < 16; it++) {
    int idx4 = it * 1024 + tid;
    int word = idx4 >> 4;
    int sh = (idx4 & 15) * 4;
    u32 fb = (u32)(fhL[word] >> sh) & 0xFu;
    u32 gb = (u32)(bhL[word] >> sh) & 0xFu;
    u32 e = fb ^ gb;
    int4 o;
    o.x = (e & 1u)        ? (int)(fb & 1u)        : -255;
    o.y = ((e >> 1) & 1u) ? (int)((fb >> 1) & 1u) : -255;
    o.z = ((e >> 2) & 1u) ? (int)((fb >> 2) & 1u) : -255;
    o.w = ((e >> 3) & 1u) ? (int)((fb >> 3) & 1u) : -255;
    out4[idx4] = o;
  }
}

extern "C" void kernel_launch(void* const* d_in, const int* in_sizes, int n_in,
                              void* d_out, int out_size, void* d_ws, size_t ws_size,
                              hipStream_t stream) {
  const float* x = (const float*)d_in[0];
  int* out = (int*)d_out;

  u32 kf0, kf1, kb0, kb1;
#if PARTITIONABLE
  threefry2x32(0u, 42u, 0u, 0u, kf0, kf1);
  threefry2x32(0u, 42u, 0u, 1u, kb0, kb1);
#else
  u32 a0, a1, c0, c1;
  threefry2x32(0u, 42u, 0u, 2u, a0, a1);
  threefry2x32(0u, 42u, 1u, 3u, c0, c1);
  kf0 = a0; kf1 = c0; kb0 = a1; kb1 = c1;
#endif

  k_all<<<BB, 1024, 0, stream>>>(x, kf0, kf1, kb0, kb1, out);
}

// Round 7
// 58.155 us; speedup vs baseline: 10.0469x; 1.0653x over previous
//
#include <hip/hip_runtime.h>
#include <stdint.h>

// MBSeederSLFCAMS — exact JAX replication; fused kernel, shortened barrier ladder.
#define PARTITIONABLE 1

typedef unsigned int u32;
typedef unsigned long long u64;

static constexpr int BB  = 256;
static constexpr int HWN = 65536;
static constexpr u32 K_BG = 6553;
static constexpr u32 TOPK = 100;
static constexpr u32 CAP  = 7936;
static constexpr u32 FG_CAP = 1024;

// ---- arena (bytes); live ranges audited per barrier interval
static constexpr int OFF_LST   = 0;        // u64[7936]  62KB  ph1..bg-mark
static constexpr int OFF_FVL   = 0;        // u64[1024]  dilate (lst dead)
static constexpr int OFF_BVL   = 8192;
static constexpr int OFF_FHL   = 16384;
static constexpr int OFF_BHL   = 24576;
static constexpr int OFF_CIMG  = 63488;    // u32[16384] 64KB  ph1..ROI
static constexpr int OFF_FGL   = 63488;    // u64[1024]  fg list (cImg dead)
static constexpr int OFF_SEEDB = 71680;    // u64[1024]
static constexpr int OFF_SEEDF = 79872;    // u64[1024]
static constexpr int OFF_HIST  = 129024;   // u32[4096]  16KB
static constexpr int OFF_HROWS = 137216;   // u64[1024]  = hist[2048..4095]
static constexpr int OFF_ROWS  = 145408;   // u64[1024]  8KB
static constexpr int OFF_HO    = 153600;   // u32[256]
static constexpr int OFF_EQ    = 154624;   // u32[256]
static constexpr int OFF_SCAL  = 155648;   // u32[32]
static constexpr int ARENA_BYTES = 155776; // < 160 KiB

__host__ __device__ inline u32 rotl32(u32 x, int d) { return (x << d) | (x >> (32 - d)); }

#define TF_ROUND(r) do { x0 += x1; x1 = rotl32(x1, r); x1 ^= x0; } while (0)

__host__ __device__ inline void threefry2x32(u32 k0, u32 k1, u32 x0, u32 x1, u32& o0, u32& o1) {
  u32 ks2 = k0 ^ k1 ^ 0x1BD11BDAu;
  x0 += k0; x1 += k1;
  TF_ROUND(13); TF_ROUND(15); TF_ROUND(26); TF_ROUND(6);
  x0 += k1;  x1 += ks2 + 1u;
  TF_ROUND(17); TF_ROUND(29); TF_ROUND(16); TF_ROUND(24);
  x0 += ks2; x1 += k0 + 2u;
  TF_ROUND(13); TF_ROUND(15); TF_ROUND(26); TF_ROUND(6);
  x0 += k0;  x1 += k1 + 3u;
  TF_ROUND(17); TF_ROUND(29); TF_ROUND(16); TF_ROUND(24);
  x0 += k1;  x1 += ks2 + 4u;
  TF_ROUND(13); TF_ROUND(15); TF_ROUND(26); TF_ROUND(6);
  x0 += ks2; x1 += k0 + 5u;
  o0 = x0; o1 = x1;
}

__device__ inline u32 score_bits(u32 k0, u32 k1, u32 i) {
#if PARTITIONABLE
  u32 a, b;
  threefry2x32(k0, k1, 0u, i, a, b);
  return a ^ b;
#else
  const u32 HALF = 1u << 23;
  u32 a, b;
  if (i < HALF) { threefry2x32(k0, k1, i, i + HALF, a, b); return a; }
  threefry2x32(k0, k1, i - HALF, i, a, b); return b;
#endif
}

__device__ __forceinline__ u32 wscan_incl(u32 v, int lane) {
#pragma unroll
  for (int d = 1; d < 64; d <<= 1) { u32 t = __shfl_up(v, d, 64); if (lane >= d) v += t; }
  return v;
}

// ---- parallel rank-select split in two halves around a barrier.
// NT participating threads (local index t in [0,NT)), BPT bins each.
template<int BPT, int NT>
__device__ __forceinline__ void pselA(const u32* hist, u32* ws, int t, u32* h, u32& loc, u32& inc) {
  int lane = t & 63;
  loc = 0;
#pragma unroll
  for (int j = 0; j < BPT; j++) { h[j] = hist[BPT * t + j]; loc += h[j]; }
  inc = wscan_incl(loc, lane);
  if (lane == 63) ws[t >> 6] = inc;
}
template<int BPT, int NT>
__device__ __forceinline__ void pselB(u32 K, bool desc, const u32* ws, u32* sc, int t, const u32* h, u32 loc, u32 inc) {
  const int NW = NT / 64;
  int wid = t >> 6;
  u32 off = 0, total = 0;
#pragma unroll
  for (int k = 0; k < NW; k++) { u32 wv = ws[k]; total += wv; if (k < wid) off += wv; }
  inc += off;
  if (!desc) {
    u32 ex = inc - loc;
#pragma unroll
    for (int j = 0; j < BPT; j++) { if (ex < K && K <= ex + h[j]) { sc[0] = BPT * t + j; sc[1] = K - ex; } ex += h[j]; }
  } else {
    u32 ex = total - inc;
#pragma unroll
    for (int j = BPT - 1; j >= 0; j--) { if (ex < K && K <= ex + h[j]) { sc[0] = BPT * t + j; sc[1] = K - ex; } ex += h[j]; }
  }
}

// ---- full psel with internal barriers (cold paths); zeroes hist[0..zeroN)
template<int BPT, int NT>
__device__ void psel_full(u32* hist, u32 K, bool desc, u32* ws, u32* sc, int zeroN, int tid) {
  u32 h[BPT], loc = 0, inc = 0;
  bool act = tid < NT;
  if (act) pselA<BPT, NT>(hist, ws, tid, h, loc, inc);
  __syncthreads();
  if (act) pselB<BPT, NT>(K, desc, ws, sc, tid, h, loc, inc);
  for (int k = tid; k < zeroN; k += 1024) hist[k] = 0;
  __syncthreads();
}

// ---- register-only Otsu on wave 0 (no barriers). Writes scal[8]=thi, scal[5]=bad.
__device__ __forceinline__ void otsu_wave0(const u32* hO, u32* scal, int lane) {
  u32 base = (u32)lane * 4;
  u32 h[4], cw[4], cs[4];
#pragma unroll
  for (int j = 0; j < 4; j++) h[j] = hO[base + j];
  cw[0] = h[0]; cs[0] = h[0] * base;
#pragma unroll
  for (int j = 1; j < 4; j++) { cw[j] = cw[j-1] + h[j]; cs[j] = cs[j-1] + h[j] * (base + j); }
  u32 incW = wscan_incl(cw[3], lane);
  u32 incS = wscan_incl(cs[3], lane);
  u32 offW = incW - cw[3], offS = incS - cs[3];
  u32 totW = __shfl(incW, 63, 64), totS = __shfl(incS, 63, 64);
  int nz = 0;
#pragma unroll
  for (int j = 0; j < 4; j++) nz += (h[j] != 0);
#pragma unroll
  for (int d = 1; d < 64; d <<= 1) nz += __shfl_xor(nz, d, 64);
  u32 selfW0 = cw[0] + offW, selfS0 = cs[0] + offS;
  u32 nxtW = __shfl_down(selfW0, 1, 64);
  u32 nxtS = __shfl_down(selfS0, 1, 64);
  u32 nxtH = __shfl_down(h[0], 1, 64);
  float total = (float)totW, stot = (float)totS;
  unsigned long long best = 0ull;
#pragma unroll
  for (int j = 0; j < 4; j++) {
    int t = (int)base + j;
    if (t < 255) {
      float h1 = (float)((j < 3) ? h[j+1] : nxtH);
      float w1 = (float)(cw[j] + offW);
      float w1n = (j < 3) ? (float)(cw[j+1] + offW) : (float)nxtW;
      float s1 = (float)(cs[j] + offS);
      float s1n = (j < 3) ? (float)(cs[j+1] + offS) : (float)nxtS;
      float w2 = total - w1n + h1;
      float s2 = stot - s1n + h1 * (float)(t + 1);
      float m1 = s1 / fmaxf(w1, 1.0f);
      float m2 = s2 / fmaxf(w2, 1.0f);
      float d = m1 - m2;
      float v = (w1 * w2) * (d * d);
      unsigned long long key = ((unsigned long long)__float_as_uint(v) << 32) | (u32)(255 - t);
      if (key > best) best = key;
    }
  }
#pragma unroll
  for (int d = 1; d < 64; d <<= 1) { unsigned long long o = __shfl_xor(best, d, 64); if (o > best) best = o; }
  if (lane == 0) {
    int bi = 255 - (int)(best & 0xFFFFFFFFu);
    float th = (float)bi;
    th = (th <= 0.0f) ? 1.0f : ((th >= 255.0f) ? 254.0f : th);
    scal[8] = (u32)(int)th;
    scal[5] = (nz <= 1) ? 1u : 0u;
  }
}

__device__ __forceinline__ void roi_bits(const u32* cImgW, u64* rows, u32 thiU, int tid) {
  u64 bits = 0;
#pragma unroll
  for (int k2 = 0; k2 < 16; k2++) {
    int k = (k2 + (tid >> 1)) & 15;
    u32 v4 = cImgW[tid * 16 + k];
    u32 m = 0;
    if ((v4 & 0xFFu) > thiU)         m |= 1u;
    if (((v4 >> 8) & 0xFFu) > thiU)  m |= 2u;
    if (((v4 >> 16) & 0xFFu) > thiU) m |= 4u;
    if ((v4 >> 24) > thiU)           m |= 8u;
    bits |= (u64)m << (4 * k);
  }
  rows[tid] = bits;
}

__device__ __forceinline__ void erode_h(const u64* rows, u64* hrows, int r) {
  u64 wv[4], h0[4];
  for (int j = 0; j < 4; j++) { wv[j] = rows[r * 4 + j]; h0[j] = wv[j]; }
  for (int s = 1; s <= 5; s++)
    for (int j = 0; j < 4; j++) {
      u64 hi = (j < 3) ? wv[j + 1] : ~0ull;
      u64 lo = (j > 0) ? wv[j - 1] : ~0ull;
      h0[j] &= ((wv[j] >> s) | (hi << (64 - s))) & ((wv[j] << s) | (lo >> (64 - s)));
    }
  for (int j = 0; j < 4; j++) hrows[r * 4 + j] = h0[j];
}

__device__ __forceinline__ void erode_v(const u64* hrows, u64* rows, int r) {
  u64 res[4] = {hrows[r * 4], hrows[r * 4 + 1], hrows[r * 4 + 2], hrows[r * 4 + 3]};
  for (int dr = -5; dr <= 5; dr++) {
    if (dr == 0) continue;
    int rr = r + dr;
    if (rr < 0 || rr >= 256) continue;
    for (int j = 0; j < 4; j++) res[j] &= hrows[rr * 4 + j];
  }
  for (int j = 0; j < 4; j++) rows[r * 4 + j] = res[j];
}

// ---- generic top-100 seeding from an idx list (cold fg path).
// Entry: hist[0..2047]==0. Exit: hist[0..2047]==0.
__device__ void seed_generic(u64* lst2, u32 n, u32 k0, u32 k1, u32 bimg, u64* seedRows,
                             u32* hist, u32* eqA, u32* scal, u32* ws, bool dead, int tid) {
  u32* sc = scal + 2;
  seedRows[tid] = 0;
  for (u32 e = tid; e < n; e += 1024) {
    u32 idx = (u32)(lst2[e] & 0xFFFFu);
    u32 m = score_bits(k0, k1, (bimg << 16) | idx) >> 9;
    lst2[e] = ((u64)m << 16) | idx;
    atomicAdd(&hist[m >> 12], 1u);
  }
  if (tid == 0) scal[1] = 0;
  __syncthreads();
  u32 keff = n < TOPK ? n : TOPK;
  psel_full<2, 1024>(hist, keff, true, ws, sc, 4096, tid);
  u32 s0 = sc[0], Kr = sc[1];
  for (u32 e = tid; e < n; e += 1024) { u32 m = (u32)(lst2[e] >> 16); if ((m >> 12) == s0) atomicAdd(&hist[m & 0xFFFu], 1u); }
  __syncthreads();
  psel_full<4, 1024>(hist, Kr, true, ws, sc, 2048, tid);
  u32 S = (s0 << 12) | sc[0]; u32 tiesS = sc[1];
  for (u32 e = tid; e < n; e += 1024) {
    u64 le = lst2[e]; u32 m = (u32)(le >> 16); u32 idx = (u32)(le & 0xFFFFu);
    if (m > S) { if (!dead) atomicOr(&seedRows[idx >> 6], 1ull << (idx & 63)); }
    else if (m == S) { u32 p = atomicAdd(&scal[1], 1u); if (p < 256) eqA[p] = idx; }
  }
  __syncthreads();
  if (tid == 0) {
    u32 ne = scal[1] < 256u ? scal[1] : 256u;
    for (u32 i2 = 1; i2 < ne; i2++) { u32 v = eqA[i2]; int j = (int)i2 - 1; while (j >= 0 && eqA[j] > v) { eqA[j + 1] = eqA[j]; j--; } eqA[j + 1] = v; }
    scal[4] = ne;
  }
  __syncthreads();
  { u32 ne = scal[4]; u32 tk = tiesS < ne ? tiesS : ne;
    if (!dead && (u32)tid < tk) { u32 idx = eqA[tid]; atomicOr(&seedRows[idx >> 6], 1ull << (idx & 63)); } }
  __syncthreads();
}

__global__ __launch_bounds__(1024, 4) void k_all(const float* __restrict__ x,
                                                 u32 kf0, u32 kf1, u32 kb0, u32 kb1,
                                                 int* __restrict__ out) {
  __shared__ __align__(16) char arena[ARENA_BYTES];
  const int b = blockIdx.x, tid = threadIdx.x;
  const int lane = tid & 63;

  u64* lst    = (u64*)(arena + OFF_LST);
  u32* cImgW  = (u32*)(arena + OFF_CIMG);
  u32* hO     = (u32*)(arena + OFF_HO);
  u32* hist   = (u32*)(arena + OFF_HIST);
  u32* eqA    = (u32*)(arena + OFF_EQ);
  u32* scal   = (u32*)(arena + OFF_SCAL);
  u32* ws     = scal + 10;
  u32* sc     = scal + 2;
  u64* rows   = (u64*)(arena + OFF_ROWS);
  u64* hrows  = (u64*)(arena + OFF_HROWS);
  u64* fgList = (u64*)(arena + OFF_FGL);
  u64* seedB  = (u64*)(arena + OFF_SEEDB);
  u64* seedF  = (u64*)(arena + OFF_SEEDF);

  const u32 BND = __float_as_uint(0.110f);
  const float4* img4 = (const float4*)(x + (size_t)b * HWN);
  const float* img = x + (size_t)b * HWN;

  // ---- I0: zero
  if (tid < 256) hO[tid] = 0;
  hist[tid] = 0; hist[tid + 1024] = 0;
  if (tid < 10) scal[tid] = 0;
  __syncthreads();

  // ---- I1: single scan: cImg pack, otsu hist, candidate push + cam-stage1 count
#pragma unroll
  for (int half = 0; half < 2; ++half) {
    float4 v[8];
#pragma unroll
    for (int k = 0; k < 8; k++) v[k] = img4[((half * 8 + k) << 10) + tid];
#pragma unroll
    for (int k = 0; k < 8; k++) {
      u32 c0 = (u32)(int)(v[k].x * 255.0f);
      u32 c1 = (u32)(int)(v[k].y * 255.0f);
      u32 c2 = (u32)(int)(v[k].z * 255.0f);
      u32 c3 = (u32)(int)(v[k].w * 255.0f);
      atomicAdd(&hO[c0], 1u); atomicAdd(&hO[c1], 1u);
      atomicAdd(&hO[c2], 1u); atomicAdd(&hO[c3], 1u);
      cImgW[((half * 8 + k) << 10) + tid] = c0 | (c1 << 8) | (c2 << 16) | (c3 << 24);
    }
#pragma unroll
    for (int k = 0; k < 8; k++) {
      u32 q0 = __float_as_uint(v[k].x), q1 = __float_as_uint(v[k].y);
      u32 q2 = __float_as_uint(v[k].z), q3 = __float_as_uint(v[k].w);
      bool s0 = q0 < BND, s1 = q1 < BND, s2 = q2 < BND, s3 = q3 < BND;
      if (s0) atomicAdd(&hist[q0 >> 19], 1u);
      if (s1) atomicAdd(&hist[q1 >> 19], 1u);
      if (s2) atomicAdd(&hist[q2 >> 19], 1u);
      if (s3) atomicAdd(&hist[q3 >> 19], 1u);
      u64 b0 = __ballot(s0), b1 = __ballot(s1), b2 = __ballot(s2), b3 = __ballot(s3);
      u32 tot = (u32)(__popcll(b0) + __popcll(b1) + __popcll(b2) + __popcll(b3));
      u32 base = 0;
      if (lane == 0 && tot) base = atomicAdd(&scal[0], tot);
      base = __shfl(base, 0, 64);
      u64 below = (1ull << lane) - 1ull;
      u32 pix = (u32)((((half * 8 + k) << 10) + tid) * 4);
      if (s0) { u32 p = base + (u32)__popcll(b0 & below); if (p < CAP) lst[p] = ((u64)q0 << 16) | pix; }
      base += (u32)__popcll(b0);
      if (s1) { u32 p = base + (u32)__popcll(b1 & below); if (p < CAP) lst[p] = ((u64)q1 << 16) | (pix + 1); }
      base += (u32)__popcll(b1);
      if (s2) { u32 p = base + (u32)__popcll(b2 & below); if (p < CAP) lst[p] = ((u64)q2 << 16) | (pix + 2); }
      base += (u32)__popcll(b2);
      if (s3) { u32 p = base + (u32)__popcll(b3 & below); if (p < CAP) lst[p] = ((u64)q3 << 16) | (pix + 3); }
    }
  }
  __syncthreads();
  u32 cntBelow = scal[0];
  bool fastOK = (cntBelow >= K_BG && cntBelow <= CAP);

  // ---- I2a: Otsu (wave 0, registers) ∥ cam psel stage1 scan (tid>=512)
  {
    u32 h1v[4], loc1 = 0, inc1 = 0;
    if (tid < 64) otsu_wave0(hO, scal, lane);
    if (tid >= 512) pselA<4, 512>(hist, ws, tid - 512, h1v, loc1, inc1);
    __syncthreads();
    // ---- I2b: psel stage1 finish ∥ zero hist[0..2047] (tid<512)
    if (tid >= 512) pselB<4, 512>(K_BG, false, ws, sc, tid - 512, h1v, loc1, inc1);
    else { hist[tid*4] = 0; hist[tid*4+1] = 0; hist[tid*4+2] = 0; hist[tid*4+3] = 0; }
    __syncthreads();
  }
  u32 thiU = scal[8];
  bool dead = scal[5] != 0u;

  u32 T, listN;
  if (fastOK) {
    listN = cntBelow;
    u32 cb0 = sc[0], Kb = sc[1];
    // ---- I4: stage2 count ∥ ROI bits
    for (u32 e = tid; e < listN; e += 1024) { u32 q = (u32)(lst[e] >> 16); if ((q >> 19) == cb0) atomicAdd(&hist[(q >> 8) & 0x7FFu], 1u); }
    roi_bits(cImgW, rows, thiU, tid);
    __syncthreads();
    // ---- I5a: psel stage2 scan (tid<512)
    u32 h2v[4], loc2 = 0, inc2 = 0;
    if (tid < 512) pselA<4, 512>(hist, ws, tid, h2v, loc2, inc2);
    __syncthreads();
    // ---- I5b: psel stage2 finish ∥ erosion-h (512..767) ∥ zero hist[0..255] (768..1023)
    if (tid < 512) pselB<4, 512>(Kb, false, ws, sc, tid, h2v, loc2, inc2);
    else if (tid < 768) erode_h(rows, hrows, tid - 512);
    else hist[tid - 768] = 0;
    __syncthreads();
    u32 cb1 = sc[0], Kc = sc[1];
    u32 hi22 = (cb0 << 11) | cb1;
    // ---- I6: stage3 count
    for (u32 e = tid; e < listN; e += 1024) { u32 q = (u32)(lst[e] >> 16); if ((q >> 8) == hi22) atomicAdd(&hist[q & 0xFFu], 1u); }
    __syncthreads();
    // ---- I7a: psel stage3 scan (tid<256) ∥ erosion-v (256..511)
    u32 h3v[1], loc3 = 0, inc3 = 0;
    if (tid < 256) pselA<1, 256>(hist, ws, tid, h3v, loc3, inc3);
    else if (tid < 512) erode_v(hrows, rows, tid - 256);
    __syncthreads();
    // ---- I7b: psel stage3 finish ∥ zero hist[0..2047] (tid>=512; preps bg stage1)
    if (tid < 256) pselB<1, 256>(Kc, false, ws, sc, tid, h3v, loc3, inc3);
    else if (tid >= 512) { int t0 = tid - 512; hist[t0*4] = 0; hist[t0*4+1] = 0; hist[t0*4+2] = 0; hist[t0*4+3] = 0; }
    __syncthreads();
    T = (hi22 << 8) | sc[0];
    u32 tiesCam = sc[1];
    // ---- I8: cam tie-collect ∥ fg extract
    for (u32 e = tid; e < listN; e += 1024) {
      u64 le = lst[e];
      if ((u32)(le >> 16) == T) { u32 p = atomicAdd(&scal[1], 1u); if (p < 256) eqA[p] = (u32)(le & 0xFFFFu); }
    }
    { u64 wv = rows[tid];
      while (wv) { int bit = __ffsll((long long)wv) - 1; wv &= wv - 1; u32 p = atomicAdd(&scal[7], 1u); if (p < FG_CAP) fgList[p] = (u64)(u32)(tid * 64 + bit); } }
    __syncthreads();
    // ---- I9: cam tie sort
    if (tid == 0) {
      u32 ne = scal[1] < 256u ? scal[1] : 256u;
      for (u32 i2 = 1; i2 < ne; i2++) { u32 v = eqA[i2]; int j = (int)i2 - 1; while (j >= 0 && eqA[j] > v) { eqA[j + 1] = eqA[j]; j--; } eqA[j + 1] = v; }
      scal[9] = (tiesCam > 0 && tiesCam <= ne) ? eqA[tiesCam - 1] : ((tiesCam > 0) ? 0xFFFFFFFEu : 0xFFFFFFFFu);
    }
    __syncthreads();
  } else {
    // ======== cold exact fallback: full-range recount from global ========
    for (int k2 = tid; k2 < 4096; k2 += 1024) hist[k2] = 0;
    __syncthreads();
    for (int c = 0; c < 64; c++) atomicAdd(&hist[__float_as_uint(img[(c << 10) + tid]) >> 19], 1u);
    __syncthreads();
    psel_full<2, 1024>(hist, K_BG, false, ws, sc, 2048, tid);
    u32 cb0 = sc[0], Kb = sc[1];
    if (tid == 0) scal[0] = 0;
    __syncthreads();
    for (int c = 0; c < 64; c++) {
      int i = (c << 10) + tid; u32 q = __float_as_uint(img[i]);
      if ((q >> 19) == cb0) { u32 p = atomicAdd(&scal[0], 1u); if (p < CAP) lst[p] = ((u64)q << 16) | (u32)i; }
    }
    __syncthreads();
    u32 ln = scal[0] < CAP ? scal[0] : CAP;
    for (u32 e = tid; e < ln; e += 1024) { u32 q = (u32)(lst[e] >> 16); atomicAdd(&hist[(q >> 8) & 0x7FFu], 1u); }
    __syncthreads();
    psel_full<2, 1024>(hist, Kb, false, ws, sc, 256, tid);
    u32 cb1 = sc[0], Kc = sc[1];
    u32 hi22 = (cb0 << 11) | cb1;
    for (u32 e = tid; e < ln; e += 1024) { u32 q = (u32)(lst[e] >> 16); if ((q >> 8) == hi22) atomicAdd(&hist[q & 0xFFu], 1u); }
    __syncthreads();
    psel_full<1, 256>(hist, Kc, false, ws, sc, 2048, tid);
    T = (hi22 << 8) | sc[0];
    u32 tiesCam = sc[1];
    if (tid == 0) scal[1] = 0;
    __syncthreads();
    for (u32 e = tid; e < ln; e += 1024) {
      u64 le = lst[e];
      if ((u32)(le >> 16) == T) { u32 p = atomicAdd(&scal[1], 1u); if (p < 256) eqA[p] = (u32)(le & 0xFFFFu); }
    }
    __syncthreads();
    if (tid == 0) {
      u32 ne = scal[1] < 256u ? scal[1] : 256u;
      for (u32 i2 = 1; i2 < ne; i2++) { u32 v = eqA[i2]; int j = (int)i2 - 1; while (j >= 0 && eqA[j] > v) { eqA[j + 1] = eqA[j]; j--; } eqA[j + 1] = v; }
      scal[9] = (tiesCam > 0 && tiesCam <= ne) ? eqA[tiesCam - 1] : ((tiesCam > 0) ? 0xFFFFFFFEu : 0xFFFFFFFFu);
      scal[0] = 0;
    }
    __syncthreads();
    // rebuild full candidate list (keys+idx) from global
    u32 tmaxF = scal[9];
    for (int c = 0; c < 64; c++) {
      int i = (c << 10) + tid; u32 q = __float_as_uint(img[i]);
      bool sel = (q < T) || (q == T && tmaxF != 0xFFFFFFFFu && (u32)i <= tmaxF);
      if (sel) { u32 p = atomicAdd(&scal[0], 1u); if (p < CAP) lst[p] = ((u64)q << 16) | (u32)i; }
    }
    // plain ROI / erosion / fg
    roi_bits(cImgW, rows, thiU, tid);
    __syncthreads();
    if (tid < 256) erode_h(rows, hrows, tid);
    __syncthreads();
    if (tid < 256) erode_v(hrows, rows, tid);
    __syncthreads();
    { u64 wv = rows[tid];
      while (wv) { int bit = __ffsll((long long)wv) - 1; wv &= wv - 1; u32 p = atomicAdd(&scal[7], 1u); if (p < FG_CAP) fgList[p] = (u64)(u32)(tid * 64 + bit); } }
    __syncthreads();
    listN = scal[0] < CAP ? scal[0] : CAP;
    // hist[0..2047] is zeroed (psel_full<1,256> zeroN=2048) — ready for bg stage1
  }

  u32 camTmaxU = scal[9];
  u32 fgN = scal[7] < FG_CAP ? scal[7] : FG_CAP;
  if (fgN > 0) seed_generic(fgList, fgN, kf0, kf1, (u32)b, seedF, hist, eqA, scal, ws, dead, tid);

  // ---- I10a: read+filter candidates into registers
  u64 mine[8]; int nm = 0;
  for (u32 e = tid; e < listN; e += 1024) {
    u64 le = lst[e]; u32 q = (u32)(le >> 16); u32 idx = (u32)(le & 0xFFFFu);
    if (q < T || (q == T && camTmaxU != 0xFFFFFFFFu && idx <= camTmaxU)) { if (nm < 8) mine[nm++] = le; }
  }
  if (tid == 0) { scal[1] = 0; scal[6] = 0; }
  __syncthreads();
  // ---- I10b: compact + threefry score + bg stage1 count; init seeds
  {
    u32 nmU = (u32)nm;
    u32 incl = wscan_incl(nmU, lane);
    u32 wtot = __shfl(incl, 63, 64);
    u32 base2 = 0;
    if (lane == 0) base2 = atomicAdd(&scal[6], wtot);
    base2 = __shfl(base2, 0, 64);
    u32 my = base2 + incl - nmU;
    for (int k2 = 0; k2 < nm; k2++) {
      u32 idx = (u32)(mine[k2] & 0xFFFFu);
      u32 m = score_bits(kb0, kb1, ((u32)b << 16) | idx) >> 9;
      if (my + (u32)k2 < CAP) lst[my + k2] = ((u64)m << 16) | idx;
      atomicAdd(&hist[m >> 12], 1u);
    }
    seedB[tid] = 0;
    if (fgN == 0) seedF[tid] = 0;
  }
  __syncthreads();
  u32 candN = scal[6] < CAP ? scal[6] : CAP;
  u32 keff = candN < TOPK ? candN : TOPK;

  if (keff > 0) {
    // ---- I11: bg psel stage1 (desc)
    u32 hb1[2], locb1 = 0, incb1 = 0;
    pselA<2, 1024>(hist, ws, tid, hb1, locb1, incb1);
    __syncthreads();
    pselB<2, 1024>(keff, true, ws, sc, tid, hb1, locb1, incb1);
    for (int k2 = tid; k2 < 4096; k2 += 1024) hist[k2] = 0;
    __syncthreads();
    u32 s0b = sc[0], Krb = sc[1];
    // ---- I12: stage2 count
    for (u32 e = tid; e < candN; e += 1024) { u32 m = (u32)(lst[e] >> 16); if ((m >> 12) == s0b) atomicAdd(&hist[m & 0xFFFu], 1u); }
    __syncthreads();
    // ---- I13: bg psel stage2 (desc)
    u32 hb2[4], locb2 = 0, incb2 = 0;
    pselA<4, 1024>(hist, ws, tid, hb2, locb2, incb2);
    __syncthreads();
    pselB<4, 1024>(Krb, true, ws, sc, tid, hb2, locb2, incb2);
    __syncthreads();
    u32 S = (s0b << 12) | sc[0]; u32 tiesS = sc[1];
    // ---- I14: mark m>S ∥ collect m==S
    for (u32 e = tid; e < candN; e += 1024) {
      u64 le = lst[e]; u32 m = (u32)(le >> 16); u32 idx = (u32)(le & 0xFFFFu);
      if (m > S) { if (!dead) atomicOr(&seedB[idx >> 6], 1ull << (idx & 63)); }
      else if (m == S) { u32 p = atomicAdd(&scal[1], 1u); if (p < 256) eqA[p] = idx; }
    }
    __syncthreads();
    // ---- I15: tie sort
    if (tid == 0) {
      u32 ne = scal[1] < 256u ? scal[1] : 256u;
      for (u32 i2 = 1; i2 < ne; i2++) { u32 v = eqA[i2]; int j = (int)i2 - 1; while (j >= 0 && eqA[j] > v) { eqA[j + 1] = eqA[j]; j--; } eqA[j + 1] = v; }
      scal[4] = ne;
    }
    __syncthreads();
    // ---- I16: tie mark
    { u32 ne = scal[4]; u32 tk = tiesS < ne ? tiesS : ne;
      if (!dead && (u32)tid < tk) { u32 idx = eqA[tid]; atomicOr(&seedB[idx >> 6], 1ull << (idx & 63)); } }
    __syncthreads();
  }

  // ---- I17/I18/I19: 3x3 dilation + conflict resolve + int4 emit
  u64* fvL = (u64*)(arena + OFF_FVL);
  u64* bvL = (u64*)(arena + OFF_BVL);
  u64* fhL = (u64*)(arena + OFF_FHL);
  u64* bhL = (u64*)(arena + OFF_BHL);
  {
    int r = tid >> 2;
    u64 vf = seedF[tid], vb = seedB[tid];
    if (r > 0)   { vf |= seedF[tid - 4]; vb |= seedB[tid - 4]; }
    if (r < 255) { vf |= seedF[tid + 4]; vb |= seedB[tid + 4]; }
    fvL[tid] = vf; bvL[tid] = vb;
  }
  __syncthreads();
  {
    int j = tid & 3;
    u64 v = fvL[tid];
    u64 L = (j > 0) ? fvL[tid - 1] : 0ull;
    u64 R = (j < 3) ? fvL[tid + 1] : 0ull;
    fhL[tid] = v | (v << 1) | (L >> 63) | (v >> 1) | (R << 63);
    v = bvL[tid];
    L = (j > 0) ? bvL[tid - 1] : 0ull;
    R = (j < 3) ? bvL[tid + 1] : 0ull;
    bhL[tid] = v | (v << 1) | (L >> 63) | (v >> 1) | (R << 63);
  }
  __syncthreads();
  int4* out4 = (int4*)(out + (size_t)b * HWN);
  for (int it = 0; it < 16; it++) {
    int idx4 = it * 1024 + tid;
    int word = idx4 >> 4;
    int sh = (idx4 & 15) * 4;
    u32 fb = (u32)(fhL[word] >> sh) & 0xFu;
    u32 gb = (u32)(bhL[word] >> sh) & 0xFu;
    u32 e = fb ^ gb;
    int4 o;
    o.x = (e & 1u)        ? (int)(fb & 1u)        : -255;
    o.y = ((e >> 1) & 1u) ? (int)((fb >> 1) & 1u) : -255;
    o.z = ((e >> 2) & 1u) ? (int)((fb >> 2) & 1u) : -255;
    o.w = ((e >> 3) & 1u) ? (int)((fb >> 3) & 1u) : -255;
    out4[idx4] = o;
  }
}

extern "C" void kernel_launch(void* const* d_in, const int* in_sizes, int n_in,
                              void* d_out, int out_size, void* d_ws, size_t ws_size,
                              hipStream_t stream) {
  const float* x = (const float*)d_in[0];
  int* out = (int*)d_out;

  u32 kf0, kf1, kb0, kb1;
#if PARTITIONABLE
  threefry2x32(0u, 42u, 0u, 0u, kf0, kf1);
  threefry2x32(0u, 42u, 0u, 1u, kb0, kb1);
#else
  u32 a0, a1, c0, c1;
  threefry2x32(0u, 42u, 0u, 2u, a0, a1);
  threefry2x32(0u, 42u, 1u, 3u, c0, c1);
  kf0 = a0; kf1 = c0; kb0 = a1; kb1 = c1;
#endif

  k_all<<<BB, 1024, 0, stream>>>(x, kf0, kf1, kb0, kb1, out);
}

// Round 8
// 54.936 us; speedup vs baseline: 10.6356x; 1.0586x over previous
//
#include <hip/hip_runtime.h>
#include <stdint.h>

// MBSeederSLFCAMS — exact JAX replication; fused kernel, lean phase-1 + nt stores.
#define PARTITIONABLE 1

typedef unsigned int u32;
typedef unsigned long long u64;
typedef __attribute__((ext_vector_type(4))) int int4v;

static constexpr int BB  = 256;
static constexpr int HWN = 65536;
static constexpr u32 K_BG = 6553;
static constexpr u32 TOPK = 100;
static constexpr u32 CAP  = 7936;
static constexpr u32 FG_CAP = 1024;

// ---- arena (bytes); live ranges audited per barrier interval
static constexpr int OFF_LST   = 0;        // u64[7936]  62KB  ph1..bg-mark
static constexpr int OFF_FVL   = 0;        // u64[1024]  dilate (lst dead)
static constexpr int OFF_BVL   = 8192;
static constexpr int OFF_FHL   = 16384;
static constexpr int OFF_BHL   = 24576;
static constexpr int OFF_CIMG  = 63488;    // u32[16384] 64KB  ph1..ROI
static constexpr int OFF_FGL   = 63488;    // u64[1024]  fg list (cImg dead)
static constexpr int OFF_SEEDB = 71680;    // u64[1024]
static constexpr int OFF_SEEDF = 79872;    // u64[1024]
static constexpr int OFF_HIST  = 129024;   // u32[4096]  16KB
static constexpr int OFF_HROWS = 137216;   // u64[1024]
static constexpr int OFF_ROWS  = 145408;   // u64[1024]
static constexpr int OFF_HO    = 153600;   // u32[256]
static constexpr int OFF_EQ    = 154624;   // u32[256]
static constexpr int OFF_SCAL  = 155648;   // u32[32]
static constexpr int ARENA_BYTES = 155776; // < 160 KiB

__host__ __device__ inline u32 rotl32(u32 x, int d) { return (x << d) | (x >> (32 - d)); }

#define TF_ROUND(r) do { x0 += x1; x1 = rotl32(x1, r); x1 ^= x0; } while (0)

__host__ __device__ inline void threefry2x32(u32 k0, u32 k1, u32 x0, u32 x1, u32& o0, u32& o1) {
  u32 ks2 = k0 ^ k1 ^ 0x1BD11BDAu;
  x0 += k0; x1 += k1;
  TF_ROUND(13); TF_ROUND(15); TF_ROUND(26); TF_ROUND(6);
  x0 += k1;  x1 += ks2 + 1u;
  TF_ROUND(17); TF_ROUND(29); TF_ROUND(16); TF_ROUND(24);
  x0 += ks2; x1 += k0 + 2u;
  TF_ROUND(13); TF_ROUND(15); TF_ROUND(26); TF_ROUND(6);
  x0 += k0;  x1 += k1 + 3u;
  TF_ROUND(17); TF_ROUND(29); TF_ROUND(16); TF_ROUND(24);
  x0 += k1;  x1 += ks2 + 4u;
  TF_ROUND(13); TF_ROUND(15); TF_ROUND(26); TF_ROUND(6);
  x0 += ks2; x1 += k0 + 5u;
  o0 = x0; o1 = x1;
}

__device__ inline u32 score_bits(u32 k0, u32 k1, u32 i) {
#if PARTITIONABLE
  u32 a, b;
  threefry2x32(k0, k1, 0u, i, a, b);
  return a ^ b;
#else
  const u32 HALF = 1u << 23;
  u32 a, b;
  if (i < HALF) { threefry2x32(k0, k1, i, i + HALF, a, b); return a; }
  threefry2x32(k0, k1, i - HALF, i, a, b); return b;
#endif
}

__device__ __forceinline__ u32 wscan_incl(u32 v, int lane) {
#pragma unroll
  for (int d = 1; d < 64; d <<= 1) { u32 t = __shfl_up(v, d, 64); if (lane >= d) v += t; }
  return v;
}

// ---- parallel rank-select split in two halves around a barrier.
template<int BPT, int NT>
__device__ __forceinline__ void pselA(const u32* hist, u32* ws, int t, u32* h, u32& loc, u32& inc) {
  int lane = t & 63;
  loc = 0;
#pragma unroll
  for (int j = 0; j < BPT; j++) { h[j] = hist[BPT * t + j]; loc += h[j]; }
  inc = wscan_incl(loc, lane);
  if (lane == 63) ws[t >> 6] = inc;
}
template<int BPT, int NT>
__device__ __forceinline__ void pselB(u32 K, bool desc, const u32* ws, u32* sc, int t, const u32* h, u32 loc, u32 inc) {
  const int NW = NT / 64;
  int wid = t >> 6;
  u32 off = 0, total = 0;
#pragma unroll
  for (int k = 0; k < NW; k++) { u32 wv = ws[k]; total += wv; if (k < wid) off += wv; }
  inc += off;
  if (!desc) {
    u32 ex = inc - loc;
#pragma unroll
    for (int j = 0; j < BPT; j++) { if (ex < K && K <= ex + h[j]) { sc[0] = BPT * t + j; sc[1] = K - ex; } ex += h[j]; }
  } else {
    u32 ex = total - inc;
#pragma unroll
    for (int j = BPT - 1; j >= 0; j--) { if (ex < K && K <= ex + h[j]) { sc[0] = BPT * t + j; sc[1] = K - ex; } ex += h[j]; }
  }
}

// ---- full psel with internal barriers (cold paths); zeroes hist[0..zeroN)
template<int BPT, int NT>
__device__ void psel_full(u32* hist, u32 K, bool desc, u32* ws, u32* sc, int zeroN, int tid) {
  u32 h[BPT], loc = 0, inc = 0;
  bool act = tid < NT;
  if (act) pselA<BPT, NT>(hist, ws, tid, h, loc, inc);
  __syncthreads();
  if (act) pselB<BPT, NT>(K, desc, ws, sc, tid, h, loc, inc);
  for (int k = tid; k < zeroN; k += 1024) hist[k] = 0;
  __syncthreads();
}

// ---- register-only Otsu on wave 0 (no barriers). Writes scal[8]=thi, scal[5]=bad.
__device__ __forceinline__ void otsu_wave0(const u32* hO, u32* scal, int lane) {
  u32 base = (u32)lane * 4;
  u32 h[4], cw[4], cs[4];
#pragma unroll
  for (int j = 0; j < 4; j++) h[j] = hO[base + j];
  cw[0] = h[0]; cs[0] = h[0] * base;
#pragma unroll
  for (int j = 1; j < 4; j++) { cw[j] = cw[j-1] + h[j]; cs[j] = cs[j-1] + h[j] * (base + j); }
  u32 incW = wscan_incl(cw[3], lane);
  u32 incS = wscan_incl(cs[3], lane);
  u32 offW = incW - cw[3], offS = incS - cs[3];
  u32 totW = __shfl(incW, 63, 64), totS = __shfl(incS, 63, 64);
  int nz = 0;
#pragma unroll
  for (int j = 0; j < 4; j++) nz += (h[j] != 0);
#pragma unroll
  for (int d = 1; d < 64; d <<= 1) nz += __shfl_xor(nz, d, 64);
  u32 selfW0 = cw[0] + offW, selfS0 = cs[0] + offS;
  u32 nxtW = __shfl_down(selfW0, 1, 64);
  u32 nxtS = __shfl_down(selfS0, 1, 64);
  u32 nxtH = __shfl_down(h[0], 1, 64);
  float total = (float)totW, stot = (float)totS;
  unsigned long long best = 0ull;
#pragma unroll
  for (int j = 0; j < 4; j++) {
    int t = (int)base + j;
    if (t < 255) {
      float h1 = (float)((j < 3) ? h[j+1] : nxtH);
      float w1 = (float)(cw[j] + offW);
      float w1n = (j < 3) ? (float)(cw[j+1] + offW) : (float)nxtW;
      float s1 = (float)(cs[j] + offS);
      float s1n = (j < 3) ? (float)(cs[j+1] + offS) : (float)nxtS;
      float w2 = total - w1n + h1;
      float s2 = stot - s1n + h1 * (float)(t + 1);
      float m1 = s1 / fmaxf(w1, 1.0f);
      float m2 = s2 / fmaxf(w2, 1.0f);
      float d = m1 - m2;
      float v = (w1 * w2) * (d * d);
      unsigned long long key = ((unsigned long long)__float_as_uint(v) << 32) | (u32)(255 - t);
      if (key > best) best = key;
    }
  }
#pragma unroll
  for (int d = 1; d < 64; d <<= 1) { unsigned long long o = __shfl_xor(best, d, 64); if (o > best) best = o; }
  if (lane == 0) {
    int bi = 255 - (int)(best & 0xFFFFFFFFu);
    float th = (float)bi;
    th = (th <= 0.0f) ? 1.0f : ((th >= 255.0f) ? 254.0f : th);
    scal[8] = (u32)(int)th;
    scal[5] = (nz <= 1) ? 1u : 0u;
  }
}

__device__ __forceinline__ void roi_bits(const u32* cImgW, u64* rows, u32 thiU, int tid) {
  u64 bits = 0;
#pragma unroll
  for (int k2 = 0; k2 < 16; k2++) {
    int k = (k2 + (tid >> 1)) & 15;
    u32 v4 = cImgW[tid * 16 + k];
    u32 m = 0;
    if ((v4 & 0xFFu) > thiU)         m |= 1u;
    if (((v4 >> 8) & 0xFFu) > thiU)  m |= 2u;
    if (((v4 >> 16) & 0xFFu) > thiU) m |= 4u;
    if ((v4 >> 24) > thiU)           m |= 8u;
    bits |= (u64)m << (4 * k);
  }
  rows[tid] = bits;
}

__device__ __forceinline__ void erode_h(const u64* rows, u64* hrows, int r) {
  u64 wv[4], h0[4];
  for (int j = 0; j < 4; j++) { wv[j] = rows[r * 4 + j]; h0[j] = wv[j]; }
  for (int s = 1; s <= 5; s++)
    for (int j = 0; j < 4; j++) {
      u64 hi = (j < 3) ? wv[j + 1] : ~0ull;
      u64 lo = (j > 0) ? wv[j - 1] : ~0ull;
      h0[j] &= ((wv[j] >> s) | (hi << (64 - s))) & ((wv[j] << s) | (lo >> (64 - s)));
    }
  for (int j = 0; j < 4; j++) hrows[r * 4 + j] = h0[j];
}

__device__ __forceinline__ void erode_v(const u64* hrows, u64* rows, int r) {
  u64 res[4] = {hrows[r * 4], hrows[r * 4 + 1], hrows[r * 4 + 2], hrows[r * 4 + 3]};
  for (int dr = -5; dr <= 5; dr++) {
    if (dr == 0) continue;
    int rr = r + dr;
    if (rr < 0 || rr >= 256) continue;
    for (int j = 0; j < 4; j++) res[j] &= hrows[rr * 4 + j];
  }
  for (int j = 0; j < 4; j++) rows[r * 4 + j] = res[j];
}

// ---- generic top-100 seeding from an idx list (cold fg path).
__device__ void seed_generic(u64* lst2, u32 n, u32 k0, u32 k1, u32 bimg, u64* seedRows,
                             u32* hist, u32* eqA, u32* scal, u32* ws, bool dead, int tid) {
  u32* sc = scal + 2;
  seedRows[tid] = 0;
  for (u32 e = tid; e < n; e += 1024) {
    u32 idx = (u32)(lst2[e] & 0xFFFFu);
    u32 m = score_bits(k0, k1, (bimg << 16) | idx) >> 9;
    lst2[e] = ((u64)m << 16) | idx;
    atomicAdd(&hist[m >> 12], 1u);
  }
  if (tid == 0) scal[1] = 0;
  __syncthreads();
  u32 keff = n < TOPK ? n : TOPK;
  psel_full<2, 1024>(hist, keff, true, ws, sc, 4096, tid);
  u32 s0 = sc[0], Kr = sc[1];
  for (u32 e = tid; e < n; e += 1024) { u32 m = (u32)(lst2[e] >> 16); if ((m >> 12) == s0) atomicAdd(&hist[m & 0xFFFu], 1u); }
  __syncthreads();
  psel_full<4, 1024>(hist, Kr, true, ws, sc, 2048, tid);
  u32 S = (s0 << 12) | sc[0]; u32 tiesS = sc[1];
  for (u32 e = tid; e < n; e += 1024) {
    u64 le = lst2[e]; u32 m = (u32)(le >> 16); u32 idx = (u32)(le & 0xFFFFu);
    if (m > S) { if (!dead) atomicOr(&seedRows[idx >> 6], 1ull << (idx & 63)); }
    else if (m == S) { u32 p = atomicAdd(&scal[1], 1u); if (p < 256) eqA[p] = idx; }
  }
  __syncthreads();
  if (tid == 0) {
    u32 ne = scal[1] < 256u ? scal[1] : 256u;
    for (u32 i2 = 1; i2 < ne; i2++) { u32 v = eqA[i2]; int j = (int)i2 - 1; while (j >= 0 && eqA[j] > v) { eqA[j + 1] = eqA[j]; j--; } eqA[j + 1] = v; }
    scal[4] = ne;
  }
  __syncthreads();
  { u32 ne = scal[4]; u32 tk = tiesS < ne ? tiesS : ne;
    if (!dead && (u32)tid < tk) { u32 idx = eqA[tid]; atomicOr(&seedRows[idx >> 6], 1ull << (idx & 63)); } }
  __syncthreads();
}

__global__ __launch_bounds__(1024, 4) void k_all(const float* __restrict__ x,
                                                 u32 kf0, u32 kf1, u32 kb0, u32 kb1,
                                                 int* __restrict__ out) {
  __shared__ __align__(16) char arena[ARENA_BYTES];
  const int b = blockIdx.x, tid = threadIdx.x;
  const int lane = tid & 63;

  u64* lst    = (u64*)(arena + OFF_LST);
  u32* cImgW  = (u32*)(arena + OFF_CIMG);
  u32* hO     = (u32*)(arena + OFF_HO);
  u32* hist   = (u32*)(arena + OFF_HIST);
  u32* eqA    = (u32*)(arena + OFF_EQ);
  u32* scal   = (u32*)(arena + OFF_SCAL);
  u32* ws     = scal + 10;
  u32* sc     = scal + 2;
  u64* rows   = (u64*)(arena + OFF_ROWS);
  u64* hrows  = (u64*)(arena + OFF_HROWS);
  u64* fgList = (u64*)(arena + OFF_FGL);
  u64* seedB  = (u64*)(arena + OFF_SEEDB);
  u64* seedF  = (u64*)(arena + OFF_SEEDF);

  const u32 BND = __float_as_uint(0.110f);
  const float4* img4 = (const float4*)(x + (size_t)b * HWN);
  const float* img = x + (size_t)b * HWN;

  // ---- I0: zero
  if (tid < 256) hO[tid] = 0;
  hist[tid] = 0; hist[tid + 1024] = 0;
  if (tid < 10) scal[tid] = 0;
  __syncthreads();

  // ---- I1: single scan: cImg pack, otsu hist, cam-stage1 count, scan-based push
#pragma unroll
  for (int half = 0; half < 2; ++half) {
    float4 v[8];
#pragma unroll
    for (int k = 0; k < 8; k++) v[k] = img4[((half * 8 + k) << 10) + tid];
    u32 nq = 0;
#pragma unroll
    for (int k = 0; k < 8; k++) {
      u32 c0 = (u32)(int)(v[k].x * 255.0f);
      u32 c1 = (u32)(int)(v[k].y * 255.0f);
      u32 c2 = (u32)(int)(v[k].z * 255.0f);
      u32 c3 = (u32)(int)(v[k].w * 255.0f);
      atomicAdd(&hO[c0], 1u); atomicAdd(&hO[c1], 1u);
      atomicAdd(&hO[c2], 1u); atomicAdd(&hO[c3], 1u);
      cImgW[((half * 8 + k) << 10) + tid] = c0 | (c1 << 8) | (c2 << 16) | (c3 << 24);
      u32 q0 = __float_as_uint(v[k].x), q1 = __float_as_uint(v[k].y);
      u32 q2 = __float_as_uint(v[k].z), q3 = __float_as_uint(v[k].w);
      if (q0 < BND) { nq++; atomicAdd(&hist[q0 >> 19], 1u); }
      if (q1 < BND) { nq++; atomicAdd(&hist[q1 >> 19], 1u); }
      if (q2 < BND) { nq++; atomicAdd(&hist[q2 >> 19], 1u); }
      if (q3 < BND) { nq++; atomicAdd(&hist[q3 >> 19], 1u); }
    }
    // order-free push: one wave scan + one atomic per half
    u32 incl = wscan_incl(nq, lane);
    u32 wtot = __shfl(incl, 63, 64);
    u32 base = 0;
    if (lane == 0) base = atomicAdd(&scal[0], wtot);
    base = __shfl(base, 0, 64);
    u32 pos = base + incl - nq;
#pragma unroll
    for (int k = 0; k < 8; k++) {
      u32 q0 = __float_as_uint(v[k].x), q1 = __float_as_uint(v[k].y);
      u32 q2 = __float_as_uint(v[k].z), q3 = __float_as_uint(v[k].w);
      u32 pix = (u32)((((half * 8 + k) << 10) + tid) * 4);
      if (q0 < BND) { if (pos < CAP) lst[pos] = ((u64)q0 << 16) | pix; pos++; }
      if (q1 < BND) { if (pos < CAP) lst[pos] = ((u64)q1 << 16) | (pix + 1); pos++; }
      if (q2 < BND) { if (pos < CAP) lst[pos] = ((u64)q2 << 16) | (pix + 2); pos++; }
      if (q3 < BND) { if (pos < CAP) lst[pos] = ((u64)q3 << 16) | (pix + 3); pos++; }
    }
  }
  __syncthreads();
  u32 cntBelow = scal[0];
  bool fastOK = (cntBelow >= K_BG && cntBelow <= CAP);

  // ---- I2a: Otsu (wave 0, registers) ∥ cam psel stage1 scan (tid>=512)
  {
    u32 h1v[4], loc1 = 0, inc1 = 0;
    if (tid < 64) otsu_wave0(hO, scal, lane);
    if (tid >= 512) pselA<4, 512>(hist, ws, tid - 512, h1v, loc1, inc1);
    __syncthreads();
    // ---- I2b: psel stage1 finish ∥ zero hist[0..2047] (tid<512)
    if (tid >= 512) pselB<4, 512>(K_BG, false, ws, sc, tid - 512, h1v, loc1, inc1);
    else { hist[tid*4] = 0; hist[tid*4+1] = 0; hist[tid*4+2] = 0; hist[tid*4+3] = 0; }
    __syncthreads();
  }
  u32 thiU = scal[8];
  bool dead = scal[5] != 0u;

  u32 T, listN;
  if (fastOK) {
    listN = cntBelow;
    u32 cb0 = sc[0], Kb = sc[1];
    // ---- I4: stage2 count ∥ ROI bits
    for (u32 e = tid; e < listN; e += 1024) { u32 q = (u32)(lst[e] >> 16); if ((q >> 19) == cb0) atomicAdd(&hist[(q >> 8) & 0x7FFu], 1u); }
    roi_bits(cImgW, rows, thiU, tid);
    __syncthreads();
    // ---- I5a: psel stage2 scan (tid<512)
    u32 h2v[4], loc2 = 0, inc2 = 0;
    if (tid < 512) pselA<4, 512>(hist, ws, tid, h2v, loc2, inc2);
    __syncthreads();
    // ---- I5b: psel stage2 finish ∥ erosion-h ∥ zero hist[0..255]
    if (tid < 512) pselB<4, 512>(Kb, false, ws, sc, tid, h2v, loc2, inc2);
    else if (tid < 768) erode_h(rows, hrows, tid - 512);
    else hist[tid - 768] = 0;
    __syncthreads();
    u32 cb1 = sc[0], Kc = sc[1];
    u32 hi22 = (cb0 << 11) | cb1;
    // ---- I6: stage3 count
    for (u32 e = tid; e < listN; e += 1024) { u32 q = (u32)(lst[e] >> 16); if ((q >> 8) == hi22) atomicAdd(&hist[q & 0xFFu], 1u); }
    __syncthreads();
    // ---- I7a: psel stage3 scan (tid<256) ∥ erosion-v (256..511)
    u32 h3v[1], loc3 = 0, inc3 = 0;
    if (tid < 256) pselA<1, 256>(hist, ws, tid, h3v, loc3, inc3);
    else if (tid < 512) erode_v(hrows, rows, tid - 256);
    __syncthreads();
    // ---- I7b: psel stage3 finish ∥ zero hist[0..2047] (preps bg stage1)
    if (tid < 256) pselB<1, 256>(Kc, false, ws, sc, tid, h3v, loc3, inc3);
    else if (tid >= 512) { int t0 = tid - 512; hist[t0*4] = 0; hist[t0*4+1] = 0; hist[t0*4+2] = 0; hist[t0*4+3] = 0; }
    __syncthreads();
    T = (hi22 << 8) | sc[0];
    u32 tiesCam = sc[1];
    // ---- I8: cam tie-collect ∥ fg extract
    for (u32 e = tid; e < listN; e += 1024) {
      u64 le = lst[e];
      if ((u32)(le >> 16) == T) { u32 p = atomicAdd(&scal[1], 1u); if (p < 256) eqA[p] = (u32)(le & 0xFFFFu); }
    }
    { u64 wv = rows[tid];
      while (wv) { int bit = __ffsll((long long)wv) - 1; wv &= wv - 1; u32 p = atomicAdd(&scal[7], 1u); if (p < FG_CAP) fgList[p] = (u64)(u32)(tid * 64 + bit); } }
    __syncthreads();
    // ---- I9: cam tie sort
    if (tid == 0) {
      u32 ne = scal[1] < 256u ? scal[1] : 256u;
      for (u32 i2 = 1; i2 < ne; i2++) { u32 v = eqA[i2]; int j = (int)i2 - 1; while (j >= 0 && eqA[j] > v) { eqA[j + 1] = eqA[j]; j--; } eqA[j + 1] = v; }
      scal[9] = (tiesCam > 0 && tiesCam <= ne) ? eqA[tiesCam - 1] : ((tiesCam > 0) ? 0xFFFFFFFEu : 0xFFFFFFFFu);
    }
    __syncthreads();
  } else {
    // ======== cold exact fallback: full-range recount from global ========
    for (int k2 = tid; k2 < 4096; k2 += 1024) hist[k2] = 0;
    __syncthreads();
    for (int c = 0; c < 64; c++) atomicAdd(&hist[__float_as_uint(img[(c << 10) + tid]) >> 19], 1u);
    __syncthreads();
    psel_full<2, 1024>(hist, K_BG, false, ws, sc, 2048, tid);
    u32 cb0 = sc[0], Kb = sc[1];
    if (tid == 0) scal[0] = 0;
    __syncthreads();
    for (int c = 0; c < 64; c++) {
      int i = (c << 10) + tid; u32 q = __float_as_uint(img[i]);
      if ((q >> 19) == cb0) { u32 p = atomicAdd(&scal[0], 1u); if (p < CAP) lst[p] = ((u64)q << 16) | (u32)i; }
    }
    __syncthreads();
    u32 ln = scal[0] < CAP ? scal[0] : CAP;
    for (u32 e = tid; e < ln; e += 1024) { u32 q = (u32)(lst[e] >> 16); atomicAdd(&hist[(q >> 8) & 0x7FFu], 1u); }
    __syncthreads();
    psel_full<2, 1024>(hist, Kb, false, ws, sc, 256, tid);
    u32 cb1 = sc[0], Kc = sc[1];
    u32 hi22 = (cb0 << 11) | cb1;
    for (u32 e = tid; e < ln; e += 1024) { u32 q = (u32)(lst[e] >> 16); if ((q >> 8) == hi22) atomicAdd(&hist[q & 0xFFu], 1u); }
    __syncthreads();
    psel_full<1, 256>(hist, Kc, false, ws, sc, 2048, tid);
    T = (hi22 << 8) | sc[0];
    u32 tiesCam = sc[1];
    if (tid == 0) scal[1] = 0;
    __syncthreads();
    for (u32 e = tid; e < ln; e += 1024) {
      u64 le = lst[e];
      if ((u32)(le >> 16) == T) { u32 p = atomicAdd(&scal[1], 1u); if (p < 256) eqA[p] = (u32)(le & 0xFFFFu); }
    }
    __syncthreads();
    if (tid == 0) {
      u32 ne = scal[1] < 256u ? scal[1] : 256u;
      for (u32 i2 = 1; i2 < ne; i2++) { u32 v = eqA[i2]; int j = (int)i2 - 1; while (j >= 0 && eqA[j] > v) { eqA[j + 1] = eqA[j]; j--; } eqA[j + 1] = v; }
      scal[9] = (tiesCam > 0 && tiesCam <= ne) ? eqA[tiesCam - 1] : ((tiesCam > 0) ? 0xFFFFFFFEu : 0xFFFFFFFFu);
      scal[0] = 0;
    }
    __syncthreads();
    u32 tmaxF = scal[9];
    for (int c = 0; c < 64; c++) {
      int i = (c << 10) + tid; u32 q = __float_as_uint(img[i]);
      bool sel = (q < T) || (q == T && tmaxF != 0xFFFFFFFFu && (u32)i <= tmaxF);
      if (sel) { u32 p = atomicAdd(&scal[0], 1u); if (p < CAP) lst[p] = ((u64)q << 16) | (u32)i; }
    }
    roi_bits(cImgW, rows, thiU, tid);
    __syncthreads();
    if (tid < 256) erode_h(rows, hrows, tid);
    __syncthreads();
    if (tid < 256) erode_v(hrows, rows, tid);
    __syncthreads();
    { u64 wv = rows[tid];
      while (wv) { int bit = __ffsll((long long)wv) - 1; wv &= wv - 1; u32 p = atomicAdd(&scal[7], 1u); if (p < FG_CAP) fgList[p] = (u64)(u32)(tid * 64 + bit); } }
    __syncthreads();
    listN = scal[0] < CAP ? scal[0] : CAP;
  }

  u32 camTmaxU = scal[9];
  u32 fgN = scal[7] < FG_CAP ? scal[7] : FG_CAP;
  if (fgN > 0) seed_generic(fgList, fgN, kf0, kf1, (u32)b, seedF, hist, eqA, scal, ws, dead, tid);

  // ---- I10a: read+filter candidates into registers
  u64 mine[8]; int nm = 0;
  for (u32 e = tid; e < listN; e += 1024) {
    u64 le = lst[e]; u32 q = (u32)(le >> 16); u32 idx = (u32)(le & 0xFFFFu);
    if (q < T || (q == T && camTmaxU != 0xFFFFFFFFu && idx <= camTmaxU)) { if (nm < 8) mine[nm++] = le; }
  }
  if (tid == 0) { scal[1] = 0; scal[6] = 0; }
  __syncthreads();
  // ---- I10b: compact + threefry score + bg stage1 count; init seeds
  {
    u32 nmU = (u32)nm;
    u32 incl = wscan_incl(nmU, lane);
    u32 wtot = __shfl(incl, 63, 64);
    u32 base2 = 0;
    if (lane == 0) base2 = atomicAdd(&scal[6], wtot);
    base2 = __shfl(base2, 0, 64);
    u32 my = base2 + incl - nmU;
    for (int k2 = 0; k2 < nm; k2++) {
      u32 idx = (u32)(mine[k2] & 0xFFFFu);
      u32 m = score_bits(kb0, kb1, ((u32)b << 16) | idx) >> 9;
      if (my + (u32)k2 < CAP) lst[my + k2] = ((u64)m << 16) | idx;
      atomicAdd(&hist[m >> 12], 1u);
    }
    seedB[tid] = 0;
    if (fgN == 0) seedF[tid] = 0;
  }
  __syncthreads();
  u32 candN = scal[6] < CAP ? scal[6] : CAP;
  u32 keff = candN < TOPK ? candN : TOPK;

  if (keff > 0) {
    // ---- I11: bg psel stage1 (desc)
    u32 hb1[2], locb1 = 0, incb1 = 0;
    pselA<2, 1024>(hist, ws, tid, hb1, locb1, incb1);
    __syncthreads();
    pselB<2, 1024>(keff, true, ws, sc, tid, hb1, locb1, incb1);
    for (int k2 = tid; k2 < 4096; k2 += 1024) hist[k2] = 0;
    __syncthreads();
    u32 s0b = sc[0], Krb = sc[1];
    // ---- I12: stage2 count
    for (u32 e = tid; e < candN; e += 1024) { u32 m = (u32)(lst[e] >> 16); if ((m >> 12) == s0b) atomicAdd(&hist[m & 0xFFFu], 1u); }
    __syncthreads();
    // ---- I13: bg psel stage2 (desc)
    u32 hb2[4], locb2 = 0, incb2 = 0;
    pselA<4, 1024>(hist, ws, tid, hb2, locb2, incb2);
    __syncthreads();
    pselB<4, 1024>(Krb, true, ws, sc, tid, hb2, locb2, incb2);
    __syncthreads();
    u32 S = (s0b << 12) | sc[0]; u32 tiesS = sc[1];
    // ---- I14: mark m>S ∥ collect m==S
    for (u32 e = tid; e < candN; e += 1024) {
      u64 le = lst[e]; u32 m = (u32)(le >> 16); u32 idx = (u32)(le & 0xFFFFu);
      if (m > S) { if (!dead) atomicOr(&seedB[idx >> 6], 1ull << (idx & 63)); }
      else if (m == S) { u32 p = atomicAdd(&scal[1], 1u); if (p < 256) eqA[p] = idx; }
    }
    __syncthreads();
    // ---- I15: tie sort
    if (tid == 0) {
      u32 ne = scal[1] < 256u ? scal[1] : 256u;
      for (u32 i2 = 1; i2 < ne; i2++) { u32 v = eqA[i2]; int j = (int)i2 - 1; while (j >= 0 && eqA[j] > v) { eqA[j + 1] = eqA[j]; j--; } eqA[j + 1] = v; }
      scal[4] = ne;
    }
    __syncthreads();
    // ---- I16: tie mark
    { u32 ne = scal[4]; u32 tk = tiesS < ne ? tiesS : ne;
      if (!dead && (u32)tid < tk) { u32 idx = eqA[tid]; atomicOr(&seedB[idx >> 6], 1ull << (idx & 63)); } }
    __syncthreads();
  }

  // ---- I17/I18/I19: 3x3 dilation + conflict resolve + nt int4 emit
  u64* fvL = (u64*)(arena + OFF_FVL);
  u64* bvL = (u64*)(arena + OFF_BVL);
  u64* fhL = (u64*)(arena + OFF_FHL);
  u64* bhL = (u64*)(arena + OFF_BHL);
  {
    int r = tid >> 2;
    u64 vf = seedF[tid], vb = seedB[tid];
    if (r > 0)   { vf |= seedF[tid - 4]; vb |= seedB[tid - 4]; }
    if (r < 255) { vf |= seedF[tid + 4]; vb |= seedB[tid + 4]; }
    fvL[tid] = vf; bvL[tid] = vb;
  }
  __syncthreads();
  {
    int j = tid & 3;
    u64 v = fvL[tid];
    u64 L = (j > 0) ? fvL[tid - 1] : 0ull;
    u64 R = (j < 3) ? fvL[tid + 1] : 0ull;
    fhL[tid] = v | (v << 1) | (L >> 63) | (v >> 1) | (R << 63);
    v = bvL[tid];
    L = (j > 0) ? bvL[tid - 1] : 0ull;
    R = (j < 3) ? bvL[tid + 1] : 0ull;
    bhL[tid] = v | (v << 1) | (L >> 63) | (v >> 1) | (R << 63);
  }
  __syncthreads();
  int4v* out4 = (int4v*)(out + (size_t)b * HWN);
  for (int it = 0; it < 16; it++) {
    int idx4 = it * 1024 + tid;
    int word = idx4 >> 4;
    int sh = (idx4 & 15) * 4;
    u32 fb = (u32)(fhL[word] >> sh) & 0xFu;
    u32 gb = (u32)(bhL[word] >> sh) & 0xFu;
    u32 e = fb ^ gb;
    int4v o;
    o.x = (e & 1u)        ? (int)(fb & 1u)        : -255;
    o.y = ((e >> 1) & 1u) ? (int)((fb >> 1) & 1u) : -255;
    o.z = ((e >> 2) & 1u) ? (int)((fb >> 2) & 1u) : -255;
    o.w = ((e >> 3) & 1u) ? (int)((fb >> 3) & 1u) : -255;
    __builtin_nontemporal_store(o, out4 + idx4);
  }
}

extern "C" void kernel_launch(void* const* d_in, const int* in_sizes, int n_in,
                              void* d_out, int out_size, void* d_ws, size_t ws_size,
                              hipStream_t stream) {
  const float* x = (const float*)d_in[0];
  int* out = (int*)d_out;

  u32 kf0, kf1, kb0, kb1;
#if PARTITIONABLE
  threefry2x32(0u, 42u, 0u, 0u, kf0, kf1);
  threefry2x32(0u, 42u, 0u, 1u, kb0, kb1);
#else
  u32 a0, a1, c0, c1;
  threefry2x32(0u, 42u, 0u, 2u, a0, a1);
  threefry2x32(0u, 42u, 1u, 3u, c0, c1);
  kf0 = a0; kf1 = c0; kb0 = a1; kb1 = c1;
#endif

  k_all<<<BB, 1024, 0, stream>>>(x, kf0, kf1, kb0, kb1, out);
}

// Round 9
// 48.681 us; speedup vs baseline: 12.0022x; 1.1285x over previous
//
#include <hip/hip_runtime.h>
#include <stdint.h>

// MBSeederSLFCAMS — exact JAX replication; fused kernel, exact-finish selects.
#define PARTITIONABLE 1

typedef unsigned int u32;
typedef unsigned long long u64;
typedef __attribute__((ext_vector_type(4))) int int4v;

static constexpr int BB  = 256;
static constexpr int HWN = 65536;
static constexpr u32 K_BG = 6553;
static constexpr u32 TOPK = 100;
static constexpr u32 CAP  = 7936;
static constexpr u32 FG_CAP = 1024;

// ---- arena (bytes); live ranges audited per barrier interval
static constexpr int OFF_LST   = 0;        // u64[7936]  62KB  ph1..bg-mark
static constexpr int OFF_FVL   = 0;        // u64[1024]  dilate (lst dead)
static constexpr int OFF_BVL   = 8192;
static constexpr int OFF_FHL   = 16384;
static constexpr int OFF_BHL   = 24576;
static constexpr int OFF_CIMG  = 63488;    // u32[16384] 64KB  ph1..ROI
static constexpr int OFF_FGL   = 63488;    // u64[1024]  fg list (cImg dead)
static constexpr int OFF_SEEDB = 71680;    // u64[1024]
static constexpr int OFF_SEEDF = 79872;    // u64[1024]
static constexpr int OFF_HIST  = 129024;   // u32[4096]  16KB
static constexpr int OFF_HROWS = 137216;   // u64[1024]  = hist[2048..4095]
static constexpr int OFF_ROWS  = 145408;   // u64[1024]
static constexpr int OFF_HO    = 153600;   // u32[256]
static constexpr int OFF_EQ    = 154624;   // u32[256]
static constexpr int OFF_SCAL  = 155648;   // u32[32]
static constexpr int ARENA_BYTES = 155776; // < 160 KiB

__host__ __device__ inline u32 rotl32(u32 x, int d) { return (x << d) | (x >> (32 - d)); }

#define TF_ROUND(r) do { x0 += x1; x1 = rotl32(x1, r); x1 ^= x0; } while (0)

__host__ __device__ inline void threefry2x32(u32 k0, u32 k1, u32 x0, u32 x1, u32& o0, u32& o1) {
  u32 ks2 = k0 ^ k1 ^ 0x1BD11BDAu;
  x0 += k0; x1 += k1;
  TF_ROUND(13); TF_ROUND(15); TF_ROUND(26); TF_ROUND(6);
  x0 += k1;  x1 += ks2 + 1u;
  TF_ROUND(17); TF_ROUND(29); TF_ROUND(16); TF_ROUND(24);
  x0 += ks2; x1 += k0 + 2u;
  TF_ROUND(13); TF_ROUND(15); TF_ROUND(26); TF_ROUND(6);
  x0 += k0;  x1 += k1 + 3u;
  TF_ROUND(17); TF_ROUND(29); TF_ROUND(16); TF_ROUND(24);
  x0 += k1;  x1 += ks2 + 4u;
  TF_ROUND(13); TF_ROUND(15); TF_ROUND(26); TF_ROUND(6);
  x0 += ks2; x1 += k0 + 5u;
  o0 = x0; o1 = x1;
}

__device__ inline u32 score_bits(u32 k0, u32 k1, u32 i) {
#if PARTITIONABLE
  u32 a, b;
  threefry2x32(k0, k1, 0u, i, a, b);
  return a ^ b;
#else
  const u32 HALF = 1u << 23;
  u32 a, b;
  if (i < HALF) { threefry2x32(k0, k1, i, i + HALF, a, b); return a; }
  threefry2x32(k0, k1, i - HALF, i, a, b); return b;
#endif
}

__device__ __forceinline__ u32 wscan_incl(u32 v, int lane) {
#pragma unroll
  for (int d = 1; d < 64; d <<= 1) { u32 t = __shfl_up(v, d, 64); if (lane >= d) v += t; }
  return v;
}

// ---- parallel rank-select split in two halves around a barrier.
template<int BPT, int NT>
__device__ __forceinline__ void pselA(const u32* hist, u32* ws, int t, u32* h, u32& loc, u32& inc) {
  int lane = t & 63;
  loc = 0;
#pragma unroll
  for (int j = 0; j < BPT; j++) { h[j] = hist[BPT * t + j]; loc += h[j]; }
  inc = wscan_incl(loc, lane);
  if (lane == 63) ws[t >> 6] = inc;
}
template<int BPT, int NT>
__device__ __forceinline__ void pselB(u32 K, bool desc, const u32* ws, u32* sc, int t, const u32* h, u32 loc, u32 inc) {
  const int NW = NT / 64;
  int wid = t >> 6;
  u32 off = 0, total = 0;
#pragma unroll
  for (int k = 0; k < NW; k++) { u32 wv = ws[k]; total += wv; if (k < wid) off += wv; }
  inc += off;
  if (!desc) {
    u32 ex = inc - loc;
#pragma unroll
    for (int j = 0; j < BPT; j++) { if (ex < K && K <= ex + h[j]) { sc[0] = BPT * t + j; sc[1] = K - ex; } ex += h[j]; }
  } else {
    u32 ex = total - inc;
#pragma unroll
    for (int j = BPT - 1; j >= 0; j--) { if (ex < K && K <= ex + h[j]) { sc[0] = BPT * t + j; sc[1] = K - ex; } ex += h[j]; }
  }
}

// ---- full psel with internal barriers (cold paths); zeroes hist[0..zeroN)
template<int BPT, int NT>
__device__ void psel_full(u32* hist, u32 K, bool desc, u32* ws, u32* sc, int zeroN, int tid) {
  u32 h[BPT], loc = 0, inc = 0;
  bool act = tid < NT;
  if (act) pselA<BPT, NT>(hist, ws, tid, h, loc, inc);
  __syncthreads();
  if (act) pselB<BPT, NT>(K, desc, ws, sc, tid, h, loc, inc);
  for (int k = tid; k < zeroN; k += 1024) hist[k] = 0;
  __syncthreads();
}

// ---- register-only Otsu on wave 0 (no barriers). Writes scal[8]=thi, scal[5]=bad.
__device__ __forceinline__ void otsu_wave0(const u32* hO, u32* scal, int lane) {
  u32 base = (u32)lane * 4;
  u32 h[4], cw[4], cs[4];
#pragma unroll
  for (int j = 0; j < 4; j++) h[j] = hO[base + j];
  cw[0] = h[0]; cs[0] = h[0] * base;
#pragma unroll
  for (int j = 1; j < 4; j++) { cw[j] = cw[j-1] + h[j]; cs[j] = cs[j-1] + h[j] * (base + j); }
  u32 incW = wscan_incl(cw[3], lane);
  u32 incS = wscan_incl(cs[3], lane);
  u32 offW = incW - cw[3], offS = incS - cs[3];
  u32 totW = __shfl(incW, 63, 64), totS = __shfl(incS, 63, 64);
  int nz = 0;
#pragma unroll
  for (int j = 0; j < 4; j++) nz += (h[j] != 0);
#pragma unroll
  for (int d = 1; d < 64; d <<= 1) nz += __shfl_xor(nz, d, 64);
  u32 selfW0 = cw[0] + offW, selfS0 = cs[0] + offS;
  u32 nxtW = __shfl_down(selfW0, 1, 64);
  u32 nxtS = __shfl_down(selfS0, 1, 64);
  u32 nxtH = __shfl_down(h[0], 1, 64);
  float total = (float)totW, stot = (float)totS;
  unsigned long long best = 0ull;
#pragma unroll
  for (int j = 0; j < 4; j++) {
    int t = (int)base + j;
    if (t < 255) {
      float h1 = (float)((j < 3) ? h[j+1] : nxtH);
      float w1 = (float)(cw[j] + offW);
      float w1n = (j < 3) ? (float)(cw[j+1] + offW) : (float)nxtW;
      float s1 = (float)(cs[j] + offS);
      float s1n = (j < 3) ? (float)(cs[j+1] + offS) : (float)nxtS;
      float w2 = total - w1n + h1;
      float s2 = stot - s1n + h1 * (float)(t + 1);
      float m1 = s1 / fmaxf(w1, 1.0f);
      float m2 = s2 / fmaxf(w2, 1.0f);
      float d = m1 - m2;
      float v = (w1 * w2) * (d * d);
      unsigned long long key = ((unsigned long long)__float_as_uint(v) << 32) | (u32)(255 - t);
      if (key > best) best = key;
    }
  }
#pragma unroll
  for (int d = 1; d < 64; d <<= 1) { unsigned long long o = __shfl_xor(best, d, 64); if (o > best) best = o; }
  if (lane == 0) {
    int bi = 255 - (int)(best & 0xFFFFFFFFu);
    float th = (float)bi;
    th = (th <= 0.0f) ? 1.0f : ((th >= 255.0f) ? 254.0f : th);
    scal[8] = (u32)(int)th;
    scal[5] = (nz <= 1) ? 1u : 0u;
  }
}

__device__ __forceinline__ void roi_bits(const u32* cImgW, u64* rows, u32 thiU, int tid) {
  u64 bits = 0;
#pragma unroll
  for (int k2 = 0; k2 < 16; k2++) {
    int k = (k2 + (tid >> 1)) & 15;
    u32 v4 = cImgW[tid * 16 + k];
    u32 m = 0;
    if ((v4 & 0xFFu) > thiU)         m |= 1u;
    if (((v4 >> 8) & 0xFFu) > thiU)  m |= 2u;
    if (((v4 >> 16) & 0xFFu) > thiU) m |= 4u;
    if ((v4 >> 24) > thiU)           m |= 8u;
    bits |= (u64)m << (4 * k);
  }
  rows[tid] = bits;
}

__device__ __forceinline__ void erode_h(const u64* rows, u64* hrows, int r) {
  u64 wv[4], h0[4];
  for (int j = 0; j < 4; j++) { wv[j] = rows[r * 4 + j]; h0[j] = wv[j]; }
  for (int s = 1; s <= 5; s++)
    for (int j = 0; j < 4; j++) {
      u64 hi = (j < 3) ? wv[j + 1] : ~0ull;
      u64 lo = (j > 0) ? wv[j - 1] : ~0ull;
      h0[j] &= ((wv[j] >> s) | (hi << (64 - s))) & ((wv[j] << s) | (lo >> (64 - s)));
    }
  for (int j = 0; j < 4; j++) hrows[r * 4 + j] = h0[j];
}

__device__ __forceinline__ void erode_v(const u64* hrows, u64* rows, int r) {
  u64 res[4] = {hrows[r * 4], hrows[r * 4 + 1], hrows[r * 4 + 2], hrows[r * 4 + 3]};
  for (int dr = -5; dr <= 5; dr++) {
    if (dr == 0) continue;
    int rr = r + dr;
    if (rr < 0 || rr >= 256) continue;
    for (int j = 0; j < 4; j++) res[j] &= hrows[rr * 4 + j];
  }
  for (int j = 0; j < 4; j++) rows[r * 4 + j] = res[j];
}

// ---- generic top-100 seeding from an idx list (cold fg path).
// Entry: hist[0..4095]==0. Exit: hist[0..4095]==0.
__device__ void seed_generic(u64* lst2, u32 n, u32 k0, u32 k1, u32 bimg, u64* seedRows,
                             u32* hist, u32* eqA, u32* scal, u32* ws, bool dead, int tid) {
  u32* sc = scal + 2;
  seedRows[tid] = 0;
  for (u32 e = tid; e < n; e += 1024) {
    u32 idx = (u32)(lst2[e] & 0xFFFFu);
    u32 m = score_bits(k0, k1, (bimg << 16) | idx) >> 9;
    lst2[e] = ((u64)m << 16) | idx;
    atomicAdd(&hist[m >> 12], 1u);
  }
  if (tid == 0) scal[1] = 0;
  __syncthreads();
  u32 keff = n < TOPK ? n : TOPK;
  psel_full<2, 1024>(hist, keff, true, ws, sc, 4096, tid);
  u32 s0 = sc[0], Kr = sc[1];
  for (u32 e = tid; e < n; e += 1024) { u32 m = (u32)(lst2[e] >> 16); if ((m >> 12) == s0) atomicAdd(&hist[m & 0xFFFu], 1u); }
  __syncthreads();
  psel_full<4, 1024>(hist, Kr, true, ws, sc, 4096, tid);
  u32 S = (s0 << 12) | sc[0]; u32 tiesS = sc[1];
  for (u32 e = tid; e < n; e += 1024) {
    u64 le = lst2[e]; u32 m = (u32)(le >> 16); u32 idx = (u32)(le & 0xFFFFu);
    if (m > S) { if (!dead) atomicOr(&seedRows[idx >> 6], 1ull << (idx & 63)); }
    else if (m == S) { u32 p = atomicAdd(&scal[1], 1u); if (p < 256) eqA[p] = idx; }
  }
  __syncthreads();
  if (tid == 0) {
    u32 ne = scal[1] < 256u ? scal[1] : 256u;
    for (u32 i2 = 1; i2 < ne; i2++) { u32 v = eqA[i2]; int j = (int)i2 - 1; while (j >= 0 && eqA[j] > v) { eqA[j + 1] = eqA[j]; j--; } eqA[j + 1] = v; }
    scal[4] = ne;
  }
  __syncthreads();
  { u32 ne = scal[4]; u32 tk = tiesS < ne ? tiesS : ne;
    if (!dead && (u32)tid < tk) { u32 idx = eqA[tid]; atomicOr(&seedRows[idx >> 6], 1ull << (idx & 63)); } }
  __syncthreads();
}

__global__ __launch_bounds__(1024, 4) void k_all(const float* __restrict__ x,
                                                 u32 kf0, u32 kf1, u32 kb0, u32 kb1,
                                                 int* __restrict__ out) {
  __shared__ __align__(16) char arena[ARENA_BYTES];
  const int b = blockIdx.x, tid = threadIdx.x;
  const int lane = tid & 63;

  u64* lst    = (u64*)(arena + OFF_LST);
  u32* cImgW  = (u32*)(arena + OFF_CIMG);
  u32* hO     = (u32*)(arena + OFF_HO);
  u32* hist   = (u32*)(arena + OFF_HIST);
  u32* eqA    = (u32*)(arena + OFF_EQ);
  u32* scal   = (u32*)(arena + OFF_SCAL);
  u32* ws     = scal + 10;
  u32* sc     = scal + 2;
  u64* rows   = (u64*)(arena + OFF_ROWS);
  u64* hrows  = (u64*)(arena + OFF_HROWS);
  u64* fgList = (u64*)(arena + OFF_FGL);
  u64* seedB  = (u64*)(arena + OFF_SEEDB);
  u64* seedF  = (u64*)(arena + OFF_SEEDF);

  const u32 BND = __float_as_uint(0.110f);
  const float4* img4 = (const float4*)(x + (size_t)b * HWN);
  const float* img = x + (size_t)b * HWN;

  // ---- I0: zero
  if (tid < 256) hO[tid] = 0;
  hist[tid] = 0; hist[tid + 1024] = 0;
  if (tid < 10) scal[tid] = 0;
  __syncthreads();

  // ---- I1: single scan: cImg pack, otsu hist, cam-stage1 count, scan-based push
#pragma unroll
  for (int half = 0; half < 2; ++half) {
    float4 v[8];
#pragma unroll
    for (int k = 0; k < 8; k++) v[k] = img4[((half * 8 + k) << 10) + tid];
    u32 nq = 0;
#pragma unroll
    for (int k = 0; k < 8; k++) {
      u32 c0 = (u32)(int)(v[k].x * 255.0f);
      u32 c1 = (u32)(int)(v[k].y * 255.0f);
      u32 c2 = (u32)(int)(v[k].z * 255.0f);
      u32 c3 = (u32)(int)(v[k].w * 255.0f);
      atomicAdd(&hO[c0], 1u); atomicAdd(&hO[c1], 1u);
      atomicAdd(&hO[c2], 1u); atomicAdd(&hO[c3], 1u);
      cImgW[((half * 8 + k) << 10) + tid] = c0 | (c1 << 8) | (c2 << 16) | (c3 << 24);
      u32 q0 = __float_as_uint(v[k].x), q1 = __float_as_uint(v[k].y);
      u32 q2 = __float_as_uint(v[k].z), q3 = __float_as_uint(v[k].w);
      if (q0 < BND) { nq++; atomicAdd(&hist[q0 >> 19], 1u); }
      if (q1 < BND) { nq++; atomicAdd(&hist[q1 >> 19], 1u); }
      if (q2 < BND) { nq++; atomicAdd(&hist[q2 >> 19], 1u); }
      if (q3 < BND) { nq++; atomicAdd(&hist[q3 >> 19], 1u); }
    }
    u32 incl = wscan_incl(nq, lane);
    u32 wtot = __shfl(incl, 63, 64);
    u32 base = 0;
    if (lane == 0) base = atomicAdd(&scal[0], wtot);
    base = __shfl(base, 0, 64);
    u32 pos = base + incl - nq;
#pragma unroll
    for (int k = 0; k < 8; k++) {
      u32 q0 = __float_as_uint(v[k].x), q1 = __float_as_uint(v[k].y);
      u32 q2 = __float_as_uint(v[k].z), q3 = __float_as_uint(v[k].w);
      u32 pix = (u32)((((half * 8 + k) << 10) + tid) * 4);
      if (q0 < BND) { if (pos < CAP) lst[pos] = ((u64)q0 << 16) | pix; pos++; }
      if (q1 < BND) { if (pos < CAP) lst[pos] = ((u64)q1 << 16) | (pix + 1); pos++; }
      if (q2 < BND) { if (pos < CAP) lst[pos] = ((u64)q2 << 16) | (pix + 2); pos++; }
      if (q3 < BND) { if (pos < CAP) lst[pos] = ((u64)q3 << 16) | (pix + 3); pos++; }
    }
  }
  __syncthreads();
  u32 cntBelow = scal[0];
  bool fastOK = (cntBelow >= K_BG && cntBelow <= CAP);

  // ---- I2a: Otsu (wave 0) ∥ cam psel stage1 scan (tid>=512)
  {
    u32 h1v[4], loc1 = 0, inc1 = 0;
    if (tid < 64) otsu_wave0(hO, scal, lane);
    if (tid >= 512) pselA<4, 512>(hist, ws, tid - 512, h1v, loc1, inc1);
    __syncthreads();
    // ---- I2b: psel stage1 finish ∥ zero hist[0..2047] (tid<512)
    if (tid >= 512) pselB<4, 512>(K_BG, false, ws, sc, tid - 512, h1v, loc1, inc1);
    else { hist[tid*4] = 0; hist[tid*4+1] = 0; hist[tid*4+2] = 0; hist[tid*4+3] = 0; }
    __syncthreads();
  }
  u32 thiU = scal[8];
  bool dead = scal[5] != 0u;

  u32 listN;
  if (fastOK) {
    listN = cntBelow;
    u32 cb0 = sc[0], Kb = sc[1];
    // ---- I4: stage2 count ∥ ROI bits
    for (u32 e = tid; e < listN; e += 1024) { u32 q = (u32)(lst[e] >> 16); if ((q >> 19) == cb0) atomicAdd(&hist[(q >> 8) & 0x7FFu], 1u); }
    roi_bits(cImgW, rows, thiU, tid);
    __syncthreads();
    // ---- I5a: psel stage2 scan (tid<512) ∥ erosion-h (512..767)
    u32 h2v[4], loc2 = 0, inc2 = 0;
    if (tid < 512) pselA<4, 512>(hist, ws, tid, h2v, loc2, inc2);
    else if (tid < 768) erode_h(rows, hrows, tid - 512);
    __syncthreads();
    // ---- I5b: psel stage2 finish ∥ erosion-v (512..767)
    if (tid < 512) pselB<4, 512>(Kb, false, ws, sc, tid, h2v, loc2, inc2);
    else if (tid < 768) erode_v(hrows, rows, tid - 512);
    __syncthreads();
    u32 cb1 = sc[0], Kc = sc[1];
    u32 hi22 = (cb0 << 11) | cb1;
    // ---- I6: collect stage3-bin entries ∥ fg extract ∥ zero hist[0..4095]
    for (u32 e = tid; e < listN; e += 1024) {
      u64 le = lst[e]; u32 q = (u32)(le >> 16);
      if ((q >> 8) == hi22) { u32 p = atomicAdd(&scal[1], 1u); if (p < 256) eqA[p] = ((q & 0xFFu) << 16) | (u32)(le & 0xFFFFu); }
    }
    { u64 wv = rows[tid];
      while (wv) { int bit = __ffsll((long long)wv) - 1; wv &= wv - 1; u32 p = atomicAdd(&scal[7], 1u); if (p < FG_CAP) fgList[p] = (u64)(u32)(tid * 64 + bit); } }
    hist[tid] = 0; hist[tid + 1024] = 0; hist[tid + 2048] = 0; hist[tid + 3072] = 0;
    __syncthreads();
    // ---- I7: exact finish — sort bin entries asc by (low8, idx); rank-Kc element
    if (tid == 0) {
      u32 ne = scal[1] < 256u ? scal[1] : 256u;
      for (u32 i2 = 1; i2 < ne; i2++) { u32 v = eqA[i2]; int j = (int)i2 - 1; while (j >= 0 && eqA[j] > v) { eqA[j + 1] = eqA[j]; j--; } eqA[j + 1] = v; }
      u32 ent = eqA[Kc - 1];
      scal[26] = (hi22 << 8) | (ent >> 16);   // T (full float bits)
      scal[27] = ent & 0xFFFFu;               // tie-max idx at T
    }
    __syncthreads();
  } else {
    // ======== cold exact fallback: full-range recount from global ========
    for (int k2 = tid; k2 < 4096; k2 += 1024) hist[k2] = 0;
    __syncthreads();
    for (int c = 0; c < 64; c++) atomicAdd(&hist[__float_as_uint(img[(c << 10) + tid]) >> 19], 1u);
    __syncthreads();
    psel_full<2, 1024>(hist, K_BG, false, ws, sc, 2048, tid);
    u32 cb0 = sc[0], Kb = sc[1];
    if (tid == 0) scal[0] = 0;
    __syncthreads();
    for (int c = 0; c < 64; c++) {
      int i = (c << 10) + tid; u32 q = __float_as_uint(img[i]);
      if ((q >> 19) == cb0) { u32 p = atomicAdd(&scal[0], 1u); if (p < CAP) lst[p] = ((u64)q << 16) | (u32)i; }
    }
    __syncthreads();
    u32 ln = scal[0] < CAP ? scal[0] : CAP;
    for (u32 e = tid; e < ln; e += 1024) { u32 q = (u32)(lst[e] >> 16); atomicAdd(&hist[(q >> 8) & 0x7FFu], 1u); }
    __syncthreads();
    psel_full<2, 1024>(hist, Kb, false, ws, sc, 256, tid);
    u32 cb1 = sc[0], Kc = sc[1];
    u32 hi22 = (cb0 << 11) | cb1;
    for (u32 e = tid; e < ln; e += 1024) { u32 q = (u32)(lst[e] >> 16); if ((q >> 8) == hi22) atomicAdd(&hist[q & 0xFFu], 1u); }
    __syncthreads();
    psel_full<1, 256>(hist, Kc, false, ws, sc, 2048, tid);
    u32 T0 = (hi22 << 8) | sc[0];
    u32 tiesCam = sc[1];
    if (tid == 0) scal[1] = 0;
    __syncthreads();
    for (u32 e = tid; e < ln; e += 1024) {
      u64 le = lst[e];
      if ((u32)(le >> 16) == T0) { u32 p = atomicAdd(&scal[1], 1u); if (p < 256) eqA[p] = (u32)(le & 0xFFFFu); }
    }
    __syncthreads();
    if (tid == 0) {
      u32 ne = scal[1] < 256u ? scal[1] : 256u;
      for (u32 i2 = 1; i2 < ne; i2++) { u32 v = eqA[i2]; int j = (int)i2 - 1; while (j >= 0 && eqA[j] > v) { eqA[j + 1] = eqA[j]; j--; } eqA[j + 1] = v; }
      u32 tmF = (tiesCam > 0 && tiesCam <= ne) ? eqA[tiesCam - 1] : ((tiesCam > 0) ? 0xFFFFFFFEu : 0xFFFFFFFFu);
      scal[9] = tmF;
      scal[26] = T0;
      scal[27] = tmF;
      scal[0] = 0;
    }
    __syncthreads();
    u32 tmaxF = scal[9];
    for (int c = 0; c < 64; c++) {
      int i = (c << 10) + tid; u32 q = __float_as_uint(img[i]);
      bool sel = (q < T0) || (q == T0 && tmaxF != 0xFFFFFFFFu && (u32)i <= tmaxF);
      if (sel) { u32 p = atomicAdd(&scal[0], 1u); if (p < CAP) lst[p] = ((u64)q << 16) | (u32)i; }
    }
    roi_bits(cImgW, rows, thiU, tid);
    __syncthreads();
    if (tid < 256) erode_h(rows, hrows, tid);
    __syncthreads();
    if (tid < 256) erode_v(hrows, rows, tid);
    __syncthreads();
    { u64 wv = rows[tid];
      while (wv) { int bit = __ffsll((long long)wv) - 1; wv &= wv - 1; u32 p = atomicAdd(&scal[7], 1u); if (p < FG_CAP) fgList[p] = (u64)(u32)(tid * 64 + bit); } }
    hist[tid + 2048] = 0; hist[tid + 3072] = 0;    // upper half (hrows now dead)
    __syncthreads();
    listN = scal[0] < CAP ? scal[0] : CAP;
    // hist[0..2047] zeroed by psel_full<1,256>; upper half zeroed above.
  }

  u32 T = scal[26];
  u32 camTmax = scal[27];
  u32 fgN = scal[7] < FG_CAP ? scal[7] : FG_CAP;
  if (fgN > 0) seed_generic(fgList, fgN, kf0, kf1, (u32)b, seedF, hist, eqA, scal, ws, dead, tid);

  // ---- I8a: read+filter candidates into registers
  u64 mine[8]; int nm = 0;
  for (u32 e = tid; e < listN; e += 1024) {
    u64 le = lst[e]; u32 q = (u32)(le >> 16); u32 idx = (u32)(le & 0xFFFFu);
    if (q < T || (q == T && idx <= camTmax)) { if (nm < 8) mine[nm++] = le; }
  }
  if (tid == 0) { scal[1] = 0; scal[6] = 0; }
  __syncthreads();
  // ---- I8b: compact + threefry score + bg stage1 count (4096 bins); init seeds
  {
    u32 nmU = (u32)nm;
    u32 incl = wscan_incl(nmU, lane);
    u32 wtot = __shfl(incl, 63, 64);
    u32 base2 = 0;
    if (lane == 0) base2 = atomicAdd(&scal[6], wtot);
    base2 = __shfl(base2, 0, 64);
    u32 my = base2 + incl - nmU;
    for (int k2 = 0; k2 < nm; k2++) {
      u32 idx = (u32)(mine[k2] & 0xFFFFu);
      u32 m = score_bits(kb0, kb1, ((u32)b << 16) | idx) >> 9;
      if (my + (u32)k2 < CAP) lst[my + k2] = ((u64)m << 16) | idx;
      atomicAdd(&hist[m >> 11], 1u);
    }
    seedB[tid] = 0;
    if (fgN == 0) seedF[tid] = 0;
  }
  __syncthreads();
  u32 candN = scal[6] < CAP ? scal[6] : CAP;
  u32 keff = candN < TOPK ? candN : TOPK;

  if (keff > 0) {
    // ---- I9: bg psel over 4096 bins (desc)
    u32 hb1[4], locb1 = 0, incb1 = 0;
    pselA<4, 1024>(hist, ws, tid, hb1, locb1, incb1);
    __syncthreads();
    pselB<4, 1024>(keff, true, ws, sc, tid, hb1, locb1, incb1);
    __syncthreads();
    u32 binB = sc[0], Krb = sc[1];
    // ---- I10: collect bin entries packed (invLow11<<16)|idx  (asc == m desc, idx asc)
    for (u32 e = tid; e < candN; e += 1024) {
      u64 le = lst[e]; u32 m = (u32)(le >> 16);
      if ((m >> 11) == binB) {
        u32 k2 = ((0x7FFu - (m & 0x7FFu)) << 16) | (u32)(le & 0xFFFFu);
        u32 p = atomicAdd(&scal[1], 1u); if (p < 256) eqA[p] = k2;
      }
    }
    __syncthreads();
    // ---- I11: tiny sort; rank-Krb element
    if (tid == 0) {
      u32 ne = scal[1] < 256u ? scal[1] : 256u;
      for (u32 i2 = 1; i2 < ne; i2++) { u32 v = eqA[i2]; int j = (int)i2 - 1; while (j >= 0 && eqA[j] > v) { eqA[j + 1] = eqA[j]; j--; } eqA[j + 1] = v; }
      scal[26] = eqA[Krb - 1];
    }
    __syncthreads();
    u32 key2K = scal[26];
    // ---- I12: mark
    if (!dead) {
      for (u32 e = tid; e < candN; e += 1024) {
        u64 le = lst[e]; u32 m = (u32)(le >> 16); u32 idx = (u32)(le & 0xFFFFu);
        u32 hb = m >> 11;
        u32 k2 = ((0x7FFu - (m & 0x7FFu)) << 16) | idx;
        bool sel = (hb > binB) || (hb == binB && k2 <= key2K);
        if (sel) atomicOr(&seedB[idx >> 6], 1ull << (idx & 63));
      }
    }
    __syncthreads();
  }

  // ---- dilation + conflict resolve + nt int4 emit
  u64* fvL = (u64*)(arena + OFF_FVL);
  u64* bvL = (u64*)(arena + OFF_BVL);
  u64* fhL = (u64*)(arena + OFF_FHL);
  u64* bhL = (u64*)(arena + OFF_BHL);
  {
    int r = tid >> 2;
    u64 vf = seedF[tid], vb = seedB[tid];
    if (r > 0)   { vf |= seedF[tid - 4]; vb |= seedB[tid - 4]; }
    if (r < 255) { vf |= seedF[tid + 4]; vb |= seedB[tid + 4]; }
    fvL[tid] = vf; bvL[tid] = vb;
  }
  __syncthreads();
  {
    int j = tid & 3;
    u64 v = fvL[tid];
    u64 L = (j > 0) ? fvL[tid - 1] : 0ull;
    u64 R = (j < 3) ? fvL[tid + 1] : 0ull;
    fhL[tid] = v | (v << 1) | (L >> 63) | (v >> 1) | (R << 63);
    v = bvL[tid];
    L = (j > 0) ? bvL[tid - 1] : 0ull;
    R = (j < 3) ? bvL[tid + 1] : 0ull;
    bhL[tid] = v | (v << 1) | (L >> 63) | (v >> 1) | (R << 63);
  }
  __syncthreads();
  int4v* out4 = (int4v*)(out + (size_t)b * HWN);
  for (int it = 0; it < 16; it++) {
    int idx4 = it * 1024 + tid;
    int word = idx4 >> 4;
    int sh = (idx4 & 15) * 4;
    u32 fb = (u32)(fhL[word] >> sh) & 0xFu;
    u32 gb = (u32)(bhL[word] >> sh) & 0xFu;
    u32 e = fb ^ gb;
    int4v o;
    o.x = (e & 1u)        ? (int)(fb & 1u)        : -255;
    o.y = ((e >> 1) & 1u) ? (int)((fb >> 1) & 1u) : -255;
    o.z = ((e >> 2) & 1u) ? (int)((fb >> 2) & 1u) : -255;
    o.w = ((e >> 3) & 1u) ? (int)((fb >> 3) & 1u) : -255;
    __builtin_nontemporal_store(o, out4 + idx4);
  }
}

extern "C" void kernel_launch(void* const* d_in, const int* in_sizes, int n_in,
                              void* d_out, int out_size, void* d_ws, size_t ws_size,
                              hipStream_t stream) {
  const float* x = (const float*)d_in[0];
  int* out = (int*)d_out;

  u32 kf0, kf1, kb0, kb1;
#if PARTITIONABLE
  threefry2x32(0u, 42u, 0u, 0u, kf0, kf1);
  threefry2x32(0u, 42u, 0u, 1u, kb0, kb1);
#else
  u32 a0, a1, c0, c1;
  threefry2x32(0u, 42u, 0u, 2u, a0, a1);
  threefry2x32(0u, 42u, 1u, 3u, c0, c1);
  kf0 = a0; kf1 = c0; kb0 = a1; kb1 = c1;
#endif

  k_all<<<BB, 1024, 0, stream>>>(x, kf0, kf1, kb0, kb1, out);
}